// Round 1
// baseline (7809.211 us; speedup 1.0000x reference)
//
#include <hip/hip_runtime.h>
#include <math.h>

#define BATCH 2
#define NN 50000
#define NE 400000
#define C_IN 5
#define CC 128
#define SS 32
#define NH 8
#define NL 4
#define FFN 512
#define COORD_F 8
#define TIME_F 4
#define HD 16
#define BETA 1.0f
#define TWO_PI 6.283185307179586476925287f

#define SL_NODES 256
#define BC_NODES 32
#define FF_NODES 32

// ---------------- CSR build ----------------
__global__ void count_deg(const int* rows, int* deg) {
    int e = blockIdx.x * blockDim.x + threadIdx.x;
    if (e < NE) atomicAdd(&deg[rows[e]], 1);
}

__global__ __launch_bounds__(512) void scan_deg(const int* deg, int* rowptr) {
    __shared__ int part[512];
    int t = threadIdx.x;
    const int CH = (NN + 511) / 512;  // 98
    int begin = t * CH, end = min(begin + CH, NN);
    int s = 0;
    for (int i = begin; i < end; i++) s += deg[i];
    part[t] = s;
    __syncthreads();
    for (int off = 1; off < 512; off <<= 1) {
        int v = (t >= off) ? part[t - off] : 0;
        __syncthreads();
        part[t] += v;
        __syncthreads();
    }
    int base = (t == 0) ? 0 : part[t - 1];
    for (int i = begin; i < end; i++) { rowptr[i] = base; base += deg[i]; }
    if (t == 511) rowptr[NN] = part[511];
}

__global__ void fill_csr(const int* rows, const int* cols, const float* vals,
                         int* cursor, int* csr_col, float* csr_val) {
    int e = blockIdx.x * blockDim.x + threadIdx.x;
    if (e < NE) {
        int p = atomicAdd(&cursor[rows[e]], 1);
        csr_col[p] = cols[e];
        csr_val[p] = vals[e];
    }
}

// ---------------- embed ----------------
__global__ __launch_bounds__(128) void embed_kernel(const float* inputs, const float* coords,
                                                    const float* t_norm, const float* freq,
                                                    const float* W, const float* bias, float* x) {
    int node = blockIdx.x;  // 0..BATCH*NN
    int b = node / NN;
    int t = threadIdx.x;
    __shared__ float feat[32];
    if (t < 8) {
        float c0 = coords[node * 2 + 0], c1 = coords[node * 2 + 1];
        float p = TWO_PI * (c0 * freq[t] + c1 * freq[8 + t]);
        feat[5 + t] = sinf(p);
        feat[13 + t] = cosf(p);
    } else if (t < 12) {
        int j = t - 8;
        float omega = powf(1000.0f, -(float)j * 0.25f);
        float ang = omega * t_norm[b] * 1000.0f;
        feat[21 + j] = sinf(ang);
        feat[25 + j] = cosf(ang);
    } else if (t >= 16 && t < 21) {
        feat[t - 16] = inputs[node * 5 + (t - 16)];
    }
    __syncthreads();
    float acc = bias[t];
    #pragma unroll
    for (int k = 0; k < 29; k++) acc += feat[k] * W[k * CC + t];
    x[(size_t)node * CC + t] = acc;
}

// ---------------- layernorm ----------------
__global__ __launch_bounds__(128) void ln_kernel(const float* xin, const float* g, const float* bb,
                                                 float* outp) {
    int node = blockIdx.x;
    int t = threadIdx.x;
    __shared__ float red[128];
    float v = xin[(size_t)node * CC + t];
    red[t] = v;
    __syncthreads();
    for (int off = 64; off > 0; off >>= 1) { if (t < off) red[t] += red[t + off]; __syncthreads(); }
    float mean = red[0] * (1.0f / 128.0f);
    __syncthreads();
    float d = v - mean;
    red[t] = d * d;
    __syncthreads();
    for (int off = 64; off > 0; off >>= 1) { if (t < off) red[t] += red[t + off]; __syncthreads(); }
    float var = red[0] * (1.0f / 128.0f);
    outp[(size_t)node * CC + t] = d * rsqrtf(var + 1e-5f) * g[t] + bb[t];
}

// ---------------- sparse aggregation (gather via CSR) ----------------
__global__ __launch_bounds__(128) void agg_kernel(const float* h, const int* rowptr,
                                                  const int* csr_col, const float* csr_val,
                                                  float* hl) {
    int blk = blockIdx.x;         // 0..BATCH*NN
    int b = blk / NN, r = blk % NN;
    int t = threadIdx.x;
    int s0 = rowptr[r], s1 = rowptr[r + 1];
    const float* hb = h + (size_t)b * NN * CC;
    float acc = 0.0f;
    for (int e = s0; e < s1; e++) acc += csr_val[e] * hb[(size_t)csr_col[e] * CC + t];
    hl[(size_t)blk * CC + t] = acc;
}

// ---------------- logits + softmax -> w ----------------
__global__ __launch_bounds__(128) void logits_kernel(const float* h, const float* hl,
                                                     const float* Ws, const float* bs,
                                                     const float* Wf, const float* bf,
                                                     float* wout) {
    int node = blockIdx.x;
    int t = threadIdx.x;
    __shared__ float hsh[128], hfsh[128];
    __shared__ float part[4][32];
    float hv = h[(size_t)node * CC + t];
    float hlv = hl[(size_t)node * CC + t];
    hsh[t] = hv;
    hfsh[t] = hv - hlv;
    __syncthreads();
    int s = t & 31, chunk = t >> 5;
    float p = 0.0f;
    #pragma unroll 8
    for (int i = 0; i < 32; i++) {
        int c = chunk * 32 + i;
        p += hsh[c] * Ws[c * SS + s] + BETA * hfsh[c] * Wf[c * SS + s];
    }
    part[chunk][s] = p;
    __syncthreads();
    if (t < 32) {
        float logit = part[0][t] + part[1][t] + part[2][t] + part[3][t] + bs[t] + BETA * bf[t];
        float m = logit;
        for (int off = 16; off > 0; off >>= 1) m = fmaxf(m, __shfl_xor(m, off, 32));
        float e = expf(logit - m);
        float sum = e;
        for (int off = 16; off > 0; off >>= 1) sum += __shfl_xor(sum, off, 32);
        wout[(size_t)node * SS + t] = e / sum;
    }
}

// ---------------- slice pooling: slices_acc[b,s,c] = sum_n w*h ; wsum ----------------
__global__ __launch_bounds__(256) void slices_acc_kernel(const float* w, const float* h,
                                                         float* slices_acc, float* wsum) {
    int b = blockIdx.y, t = threadIdx.x;
    int n0 = blockIdx.x * SL_NODES;
    __shared__ float wsh[32];
    __shared__ float hsh[128];
    int c = t & 127, sg = t >> 7;
    float acc[16];
    #pragma unroll
    for (int k = 0; k < 16; k++) acc[k] = 0.0f;
    float wsum_loc = 0.0f;
    for (int i = 0; i < SL_NODES; i++) {
        int n = n0 + i;
        __syncthreads();
        if (n < NN) {
            if (t < 32) wsh[t] = w[((size_t)b * NN + n) * SS + t];
            else if (t >= 64 && t < 192) hsh[t - 64] = h[((size_t)b * NN + n) * CC + (t - 64)];
        } else {
            if (t < 32) wsh[t] = 0.0f;
            else if (t >= 64 && t < 192) hsh[t - 64] = 0.0f;
        }
        __syncthreads();
        float hv = hsh[c];
        #pragma unroll
        for (int k = 0; k < 16; k++) acc[k] += wsh[sg * 16 + k] * hv;
        if (t < 32) wsum_loc += wsh[t];
    }
    #pragma unroll
    for (int k = 0; k < 16; k++)
        atomicAdd(&slices_acc[(size_t)b * SS * CC + (sg * 16 + k) * CC + c], acc[k]);
    if (t < 32) atomicAdd(&wsum[b * SS + t], wsum_loc);
}

// ---------------- slice MHA (one block per batch) ----------------
__global__ __launch_bounds__(256) void mha_kernel(const float* slices_acc, const float* wsum,
                                                  const float* Win, const float* b_in_p,
                                                  const float* Wout, const float* bout,
                                                  float* slices_out) {
    int b = blockIdx.x, t = threadIdx.x;
    __shared__ float qkv[32 * 384];  // 48KB; q-section reused for o
    __shared__ float inv[32];
    if (t < 32) inv[t] = 1.0f / fmaxf(wsum[b * SS + t], 1e-8f);
    __syncthreads();
    for (int idx = t; idx < 32 * 384; idx += 256) {
        int s = idx / 384, j = idx - s * 384;
        float a = b_in_p[j];
        const float* sr = &slices_acc[(size_t)b * SS * CC + s * CC];
        float iv = inv[s];
        for (int c = 0; c < 128; c++) a += sr[c] * iv * Win[c * 384 + j];
        qkv[idx] = a;
    }
    __syncthreads();
    int head = t >> 5, q = t & 31;
    const float* qr = &qkv[q * 384 + head * HD];
    float sc[32];
    float m = -1e30f;
    for (int k = 0; k < 32; k++) {
        const float* kr = &qkv[k * 384 + 128 + head * HD];
        float a = 0.0f;
        #pragma unroll
        for (int d = 0; d < HD; d++) a += qr[d] * kr[d];
        a *= 0.25f;  // 1/sqrt(16)
        sc[k] = a;
        if (a > m) m = a;
    }
    float ssum = 0.0f;
    for (int k = 0; k < 32; k++) { float e = expf(sc[k] - m); sc[k] = e; ssum += e; }
    float isum = 1.0f / ssum;
    float o[HD];
    #pragma unroll
    for (int d = 0; d < HD; d++) o[d] = 0.0f;
    for (int k = 0; k < 32; k++) {
        const float* vr = &qkv[k * 384 + 256 + head * HD];
        float a = sc[k] * isum;
        #pragma unroll
        for (int d = 0; d < HD; d++) o[d] += a * vr[d];
    }
    __syncthreads();
    #pragma unroll
    for (int d = 0; d < HD; d++) qkv[q * 384 + head * HD + d] = o[d];
    __syncthreads();
    for (int idx = t; idx < 32 * 128; idx += 256) {
        int s = idx >> 7, c = idx & 127;
        float a = bout[c];
        const float* orow = &qkv[s * 384];
        for (int cc = 0; cc < 128; cc++) a += orow[cc] * Wout[cc * CC + c];
        slices_out[(size_t)b * SS * CC + idx] = a;
    }
}

// ---------------- broadcast back: x += w @ slices_out ----------------
__global__ __launch_bounds__(256) void broadcast_kernel(const float* w, const float* slices_out,
                                                        float* x) {
    int b = blockIdx.y, t = threadIdx.x;
    int n0 = blockIdx.x * BC_NODES;
    __shared__ float so[32 * 128];
    __shared__ float wt[BC_NODES * 32];
    for (int idx = t; idx < 32 * 128; idx += 256) so[idx] = slices_out[(size_t)b * SS * CC + idx];
    for (int idx = t; idx < BC_NODES * 32; idx += 256) {
        int n = n0 + (idx >> 5);
        wt[idx] = (n < NN) ? w[((size_t)b * NN + n) * SS + (idx & 31)] : 0.0f;
    }
    __syncthreads();
    #pragma unroll
    for (int k = 0; k < 16; k++) {
        int idx = t + k * 256;
        int ln = idx >> 7, c = idx & 127;
        int n = n0 + ln;
        if (n < NN) {
            float a = 0.0f;
            const float* wr = &wt[ln * 32];
            #pragma unroll 8
            for (int s = 0; s < 32; s++) a += wr[s] * so[s * 128 + c];
            x[((size_t)b * NN + n) * CC + c] += a;
        }
    }
}

// ---------------- fused FFN: x += gelu(h2@Wff1+b1)@Wff2 + b2 ----------------
__global__ __launch_bounds__(256) void ffn_kernel(const float* h2, const float* Wff1,
                                                  const float* bff1, const float* Wff2,
                                                  const float* bff2, float* x) {
    int t = threadIdx.x;
    size_t n0 = (size_t)blockIdx.x * FF_NODES;
    __shared__ float h2t[FF_NODES * 128];
    __shared__ float hid[FF_NODES * 128];
    const size_t NTOT = (size_t)BATCH * NN;
    for (int idx = t; idx < FF_NODES * 128; idx += 256) {
        size_t n = n0 + (idx >> 7);
        h2t[idx] = (n < NTOT) ? h2[n * CC + (idx & 127)] : 0.0f;
    }
    __syncthreads();
    int c = t & 127, g = t >> 7;
    float acc[16];
    #pragma unroll
    for (int k = 0; k < 16; k++) acc[k] = 0.0f;
    for (int jc = 0; jc < 4; jc++) {
        for (int idx = t; idx < FF_NODES * 128; idx += 256) {
            int n = idx >> 7, jj = idx & 127, j = jc * 128 + jj;
            float a = bff1[j];
            const float* hr = &h2t[n * 128];
            #pragma unroll 8
            for (int cc = 0; cc < 128; cc++) a += hr[cc] * Wff1[cc * FFN + j];
            hid[idx] = 0.5f * a * (1.0f + erff(a * 0.7071067811865475f));
        }
        __syncthreads();
        for (int jj = 0; jj < 128; jj++) {
            float wv = Wff2[(jc * 128 + jj) * CC + c];
            #pragma unroll
            for (int k = 0; k < 16; k++) acc[k] += hid[(g * 16 + k) * 128 + jj] * wv;
        }
        __syncthreads();
    }
    #pragma unroll
    for (int k = 0; k < 16; k++) {
        size_t n = n0 + g * 16 + k;
        if (n < NTOT) x[n * CC + c] += acc[k] + bff2[c];
    }
}

// ---------------- final projection ----------------
__global__ __launch_bounds__(128) void proj_kernel(const float* x, const float* W,
                                                   const float* bias, float* outp) {
    int node = blockIdx.x;
    int t = threadIdx.x;
    __shared__ float xr[128];
    __shared__ float pr[40];
    xr[t] = x[(size_t)node * CC + t];
    __syncthreads();
    if (t < 40) {
        int k = t / 8, part = t % 8;
        float a = 0.0f;
        #pragma unroll
        for (int i = 0; i < 16; i++) {
            int c = part * 16 + i;
            a += xr[c] * W[c * C_IN + k];
        }
        pr[t] = a;
    }
    __syncthreads();
    if (t < 5) {
        float a = bias[t];
        #pragma unroll
        for (int p = 0; p < 8; p++) a += pr[t * 8 + p];
        outp[(size_t)node * C_IN + t] = a;
    }
}

extern "C" void kernel_launch(void* const* d_in, const int* in_sizes, int n_in,
                              void* d_out, int out_size, void* d_ws, size_t ws_size,
                              hipStream_t stream) {
    const float* inputs  = (const float*)d_in[0];
    const float* coords  = (const float*)d_in[1];
    const float* t_norm  = (const float*)d_in[2];
    const int*   adj     = (const int*)d_in[3];   // rows = adj[0:E], cols = adj[E:2E]
    const float* adj_v   = (const float*)d_in[4];
    const float* freq    = (const float*)d_in[5];
    const float* embed_W = (const float*)d_in[6];
    const float* embed_b = (const float*)d_in[7];
    const float* ln1_g   = (const float*)d_in[8];
    const float* ln1_b   = (const float*)d_in[9];
    const float* Wslice  = (const float*)d_in[10];
    const float* bslice  = (const float*)d_in[11];
    const float* Wfront  = (const float*)d_in[12];
    const float* bfront  = (const float*)d_in[13];
    const float* Win     = (const float*)d_in[14];
    const float* b_in    = (const float*)d_in[15];
    const float* Wout    = (const float*)d_in[16];
    const float* bout    = (const float*)d_in[17];
    const float* ln2_g   = (const float*)d_in[18];
    const float* ln2_b   = (const float*)d_in[19];
    const float* Wff1    = (const float*)d_in[20];
    const float* bff1    = (const float*)d_in[21];
    const float* Wff2    = (const float*)d_in[22];
    const float* bff2    = (const float*)d_in[23];
    const float* proj_W  = (const float*)d_in[24];
    const float* proj_b  = (const float*)d_in[25];

    float* out = (float*)d_out;
    float* wout_base = out + (size_t)BATCH * NN * C_IN;  // weights region (L,B,N,S)

    // workspace layout (floats)
    float* x          = (float*)d_ws;
    float* h          = x + (size_t)BATCH * NN * CC;
    float* hl         = h + (size_t)BATCH * NN * CC;   // also reused as h2
    float* slices_acc = hl + (size_t)BATCH * NN * CC;
    float* wsum       = slices_acc + BATCH * SS * CC;
    float* slices_out = wsum + BATCH * SS;
    float* csr_val    = slices_out + BATCH * SS * CC;
    int*   rowptr     = (int*)(csr_val + NE);
    int*   cursor     = rowptr + (NN + 1);
    int*   deg        = cursor + NN;
    int*   csr_col    = deg + NN;

    // ---- CSR build (adjacency shared across batch & layers) ----
    hipMemsetAsync(deg, 0, NN * sizeof(int), stream);
    count_deg<<<(NE + 255) / 256, 256, 0, stream>>>(adj, deg);
    scan_deg<<<1, 512, 0, stream>>>(deg, rowptr);
    hipMemcpyAsync(cursor, rowptr, NN * sizeof(int), hipMemcpyDeviceToDevice, stream);
    fill_csr<<<(NE + 255) / 256, 256, 0, stream>>>(adj, adj + NE, adj_v, cursor, csr_col, csr_val);

    // ---- embed ----
    embed_kernel<<<BATCH * NN, 128, 0, stream>>>(inputs, coords, t_norm, freq, embed_W, embed_b, x);

    for (int l = 0; l < NL; l++) {
        float* wl = wout_base + (size_t)l * BATCH * NN * SS;
        ln_kernel<<<BATCH * NN, 128, 0, stream>>>(x, ln1_g + l * CC, ln1_b + l * CC, h);
        agg_kernel<<<BATCH * NN, 128, 0, stream>>>(h, rowptr, csr_col, csr_val, hl);
        logits_kernel<<<BATCH * NN, 128, 0, stream>>>(h, hl, Wslice + (size_t)l * CC * SS,
                                                      bslice + l * SS, Wfront + (size_t)l * CC * SS,
                                                      bfront + l * SS, wl);
        hipMemsetAsync(slices_acc, 0, (BATCH * SS * CC + BATCH * SS) * sizeof(float), stream);
        dim3 g1((NN + SL_NODES - 1) / SL_NODES, BATCH);
        slices_acc_kernel<<<g1, 256, 0, stream>>>(wl, h, slices_acc, wsum);
        mha_kernel<<<BATCH, 256, 0, stream>>>(slices_acc, wsum, Win + (size_t)l * CC * 3 * CC,
                                              b_in + l * 3 * CC, Wout + (size_t)l * CC * CC,
                                              bout + l * CC, slices_out);
        dim3 g2((NN + BC_NODES - 1) / BC_NODES, BATCH);
        broadcast_kernel<<<g2, 256, 0, stream>>>(wl, slices_out, x);
        ln_kernel<<<BATCH * NN, 128, 0, stream>>>(x, ln2_g + l * CC, ln2_b + l * CC, hl);
        ffn_kernel<<<(BATCH * NN + FF_NODES - 1) / FF_NODES, 256, 0, stream>>>(
            hl, Wff1 + (size_t)l * CC * FFN, bff1 + l * FFN,
            Wff2 + (size_t)l * FFN * CC, bff2 + l * CC, x);
    }

    proj_kernel<<<BATCH * NN, 128, 0, stream>>>(x, proj_W, proj_b, out);
}

// Round 2
// 3917.493 us; speedup vs baseline: 1.9934x; 1.9934x over previous
//
#include <hip/hip_runtime.h>
#include <math.h>

#define BATCH 2
#define NN 50000
#define NE 400000
#define C_IN 5
#define CC 128
#define SS 32
#define NH 8
#define NL 4
#define FFN 512
#define COORD_F 8
#define TIME_F 4
#define HD 16
#define BETA 1.0f
#define TWO_PI 6.283185307179586476925287f

#define SL_NODES 256
#define BC_NODES 32
#define NTOT (BATCH * NN)
#define FF_MT 128
#define FF_BLOCKS ((NTOT + FF_MT - 1) / FF_MT)   // 782
#define MPAD (FF_BLOCKS * FF_MT)                  // 100096

typedef unsigned short u16;
typedef unsigned int u32;
typedef __attribute__((ext_vector_type(8))) __bf16 bf16x8;
typedef __attribute__((ext_vector_type(4))) float f32x4;

__device__ __forceinline__ u16 f2bf(float f) {
    union { float f; u32 u; } v; v.f = f;
    u32 u = v.u;
    u32 r = (u + 0x7fffu + ((u >> 16) & 1u)) >> 16;
    return (u16)r;
}

// ---------------- CSR build ----------------
__global__ void count_deg(const int* rows, int* deg) {
    int e = blockIdx.x * blockDim.x + threadIdx.x;
    if (e < NE) atomicAdd(&deg[rows[e]], 1);
}

__global__ __launch_bounds__(512) void scan_deg(const int* deg, int* rowptr) {
    __shared__ int part[512];
    int t = threadIdx.x;
    const int CH = (NN + 511) / 512;  // 98
    int begin = t * CH, end = min(begin + CH, NN);
    int s = 0;
    for (int i = begin; i < end; i++) s += deg[i];
    part[t] = s;
    __syncthreads();
    for (int off = 1; off < 512; off <<= 1) {
        int v = (t >= off) ? part[t - off] : 0;
        __syncthreads();
        part[t] += v;
        __syncthreads();
    }
    int base = (t == 0) ? 0 : part[t - 1];
    for (int i = begin; i < end; i++) { rowptr[i] = base; base += deg[i]; }
    if (t == 511) rowptr[NN] = part[511];
}

__global__ void fill_csr(const int* rows, const int* cols, const float* vals,
                         int* cursor, int* csr_col, float* csr_val) {
    int e = blockIdx.x * blockDim.x + threadIdx.x;
    if (e < NE) {
        int p = atomicAdd(&cursor[rows[e]], 1);
        csr_col[p] = cols[e];
        csr_val[p] = vals[e];
    }
}

// ---------------- embed ----------------
__global__ __launch_bounds__(128) void embed_kernel(const float* inputs, const float* coords,
                                                    const float* t_norm, const float* freq,
                                                    const float* W, const float* bias, float* x) {
    int node = blockIdx.x;  // 0..BATCH*NN
    int b = node / NN;
    int t = threadIdx.x;
    __shared__ float feat[32];
    if (t < 8) {
        float c0 = coords[node * 2 + 0], c1 = coords[node * 2 + 1];
        float p = TWO_PI * (c0 * freq[t] + c1 * freq[8 + t]);
        feat[5 + t] = sinf(p);
        feat[13 + t] = cosf(p);
    } else if (t < 12) {
        int j = t - 8;
        float omega = powf(1000.0f, -(float)j * 0.25f);
        float ang = omega * t_norm[b] * 1000.0f;
        feat[21 + j] = sinf(ang);
        feat[25 + j] = cosf(ang);
    } else if (t >= 16 && t < 21) {
        feat[t - 16] = inputs[node * 5 + (t - 16)];
    }
    __syncthreads();
    float acc = bias[t];
    #pragma unroll
    for (int k = 0; k < 29; k++) acc += feat[k] * W[k * CC + t];
    x[(size_t)node * CC + t] = acc;
}

// ---------------- layernorm (fp32 out) ----------------
__global__ __launch_bounds__(128) void ln_kernel(const float* xin, const float* g, const float* bb,
                                                 float* outp) {
    int node = blockIdx.x;
    int t = threadIdx.x;
    __shared__ float red[128];
    float v = xin[(size_t)node * CC + t];
    red[t] = v;
    __syncthreads();
    for (int off = 64; off > 0; off >>= 1) { if (t < off) red[t] += red[t + off]; __syncthreads(); }
    float mean = red[0] * (1.0f / 128.0f);
    __syncthreads();
    float d = v - mean;
    red[t] = d * d;
    __syncthreads();
    for (int off = 64; off > 0; off >>= 1) { if (t < off) red[t] += red[t + off]; __syncthreads(); }
    float var = red[0] * (1.0f / 128.0f);
    outp[(size_t)node * CC + t] = d * rsqrtf(var + 1e-5f) * g[t] + bb[t];
}

// ---------------- layernorm (bf16 out, zero-padded to MPAD) ----------------
__global__ __launch_bounds__(128) void ln_bf16_kernel(const float* xin, const float* g,
                                                      const float* bb, u16* outp) {
    int node = blockIdx.x;
    int t = threadIdx.x;
    if (node >= NTOT) { outp[(size_t)node * CC + t] = 0; return; }
    __shared__ float red[128];
    float v = xin[(size_t)node * CC + t];
    red[t] = v;
    __syncthreads();
    for (int off = 64; off > 0; off >>= 1) { if (t < off) red[t] += red[t + off]; __syncthreads(); }
    float mean = red[0] * (1.0f / 128.0f);
    __syncthreads();
    float d = v - mean;
    red[t] = d * d;
    __syncthreads();
    for (int off = 64; off > 0; off >>= 1) { if (t < off) red[t] += red[t + off]; __syncthreads(); }
    float var = red[0] * (1.0f / 128.0f);
    outp[(size_t)node * CC + t] = f2bf(d * rsqrtf(var + 1e-5f) * g[t] + bb[t]);
}

// ---------------- sparse aggregation (gather via CSR) ----------------
__global__ __launch_bounds__(128) void agg_kernel(const float* h, const int* rowptr,
                                                  const int* csr_col, const float* csr_val,
                                                  float* hl) {
    int blk = blockIdx.x;         // 0..BATCH*NN
    int b = blk / NN, r = blk % NN;
    int t = threadIdx.x;
    int s0 = rowptr[r], s1 = rowptr[r + 1];
    const float* hb = h + (size_t)b * NN * CC;
    float acc = 0.0f;
    for (int e = s0; e < s1; e++) acc += csr_val[e] * hb[(size_t)csr_col[e] * CC + t];
    hl[(size_t)blk * CC + t] = acc;
}

// ---------------- logits + softmax -> w ----------------
__global__ __launch_bounds__(128) void logits_kernel(const float* h, const float* hl,
                                                     const float* Ws, const float* bs,
                                                     const float* Wf, const float* bf,
                                                     float* wout) {
    int node = blockIdx.x;
    int t = threadIdx.x;
    __shared__ float hsh[128], hfsh[128];
    __shared__ float part[4][32];
    float hv = h[(size_t)node * CC + t];
    float hlv = hl[(size_t)node * CC + t];
    hsh[t] = hv;
    hfsh[t] = hv - hlv;
    __syncthreads();
    int s = t & 31, chunk = t >> 5;
    float p = 0.0f;
    #pragma unroll 8
    for (int i = 0; i < 32; i++) {
        int c = chunk * 32 + i;
        p += hsh[c] * Ws[c * SS + s] + BETA * hfsh[c] * Wf[c * SS + s];
    }
    part[chunk][s] = p;
    __syncthreads();
    if (t < 32) {
        float logit = part[0][t] + part[1][t] + part[2][t] + part[3][t] + bs[t] + BETA * bf[t];
        float m = logit;
        for (int off = 16; off > 0; off >>= 1) m = fmaxf(m, __shfl_xor(m, off, 32));
        float e = expf(logit - m);
        float sum = e;
        for (int off = 16; off > 0; off >>= 1) sum += __shfl_xor(sum, off, 32);
        wout[(size_t)node * SS + t] = e / sum;
    }
}

// ---------------- slice pooling ----------------
__global__ __launch_bounds__(256) void slices_acc_kernel(const float* w, const float* h,
                                                         float* slices_acc, float* wsum) {
    int b = blockIdx.y, t = threadIdx.x;
    int n0 = blockIdx.x * SL_NODES;
    __shared__ float wsh[32];
    __shared__ float hsh[128];
    int c = t & 127, sg = t >> 7;
    float acc[16];
    #pragma unroll
    for (int k = 0; k < 16; k++) acc[k] = 0.0f;
    float wsum_loc = 0.0f;
    for (int i = 0; i < SL_NODES; i++) {
        int n = n0 + i;
        __syncthreads();
        if (n < NN) {
            if (t < 32) wsh[t] = w[((size_t)b * NN + n) * SS + t];
            else if (t >= 64 && t < 192) hsh[t - 64] = h[((size_t)b * NN + n) * CC + (t - 64)];
        } else {
            if (t < 32) wsh[t] = 0.0f;
            else if (t >= 64 && t < 192) hsh[t - 64] = 0.0f;
        }
        __syncthreads();
        float hv = hsh[c];
        #pragma unroll
        for (int k = 0; k < 16; k++) acc[k] += wsh[sg * 16 + k] * hv;
        if (t < 32) wsum_loc += wsh[t];
    }
    #pragma unroll
    for (int k = 0; k < 16; k++)
        atomicAdd(&slices_acc[(size_t)b * SS * CC + (sg * 16 + k) * CC + c], acc[k]);
    if (t < 32) atomicAdd(&wsum[b * SS + t], wsum_loc);
}

// ---------------- slice MHA ----------------
__global__ __launch_bounds__(256) void mha_kernel(const float* slices_acc, const float* wsum,
                                                  const float* Win, const float* b_in_p,
                                                  const float* Wout, const float* bout,
                                                  float* slices_out) {
    int b = blockIdx.x, t = threadIdx.x;
    __shared__ float qkv[32 * 384];
    __shared__ float inv[32];
    if (t < 32) inv[t] = 1.0f / fmaxf(wsum[b * SS + t], 1e-8f);
    __syncthreads();
    for (int idx = t; idx < 32 * 384; idx += 256) {
        int s = idx / 384, j = idx - s * 384;
        float a = b_in_p[j];
        const float* sr = &slices_acc[(size_t)b * SS * CC + s * CC];
        float iv = inv[s];
        for (int c = 0; c < 128; c++) a += sr[c] * iv * Win[c * 384 + j];
        qkv[idx] = a;
    }
    __syncthreads();
    int head = t >> 5, q = t & 31;
    const float* qr = &qkv[q * 384 + head * HD];
    float sc[32];
    float m = -1e30f;
    for (int k = 0; k < 32; k++) {
        const float* kr = &qkv[k * 384 + 128 + head * HD];
        float a = 0.0f;
        #pragma unroll
        for (int d = 0; d < HD; d++) a += qr[d] * kr[d];
        a *= 0.25f;
        sc[k] = a;
        if (a > m) m = a;
    }
    float ssum = 0.0f;
    for (int k = 0; k < 32; k++) { float e = expf(sc[k] - m); sc[k] = e; ssum += e; }
    float isum = 1.0f / ssum;
    float o[HD];
    #pragma unroll
    for (int d = 0; d < HD; d++) o[d] = 0.0f;
    for (int k = 0; k < 32; k++) {
        const float* vr = &qkv[k * 384 + 256 + head * HD];
        float a = sc[k] * isum;
        #pragma unroll
        for (int d = 0; d < HD; d++) o[d] += a * vr[d];
    }
    __syncthreads();
    #pragma unroll
    for (int d = 0; d < HD; d++) qkv[q * 384 + head * HD + d] = o[d];
    __syncthreads();
    for (int idx = t; idx < 32 * 128; idx += 256) {
        int s = idx >> 7, c = idx & 127;
        float a = bout[c];
        const float* orow = &qkv[s * 384];
        for (int cc = 0; cc < 128; cc++) a += orow[cc] * Wout[cc * CC + c];
        slices_out[(size_t)b * SS * CC + idx] = a;
    }
}

// ---------------- broadcast back: x += w @ slices_out ----------------
__global__ __launch_bounds__(256) void broadcast_kernel(const float* w, const float* slices_out,
                                                        float* x) {
    int b = blockIdx.y, t = threadIdx.x;
    int n0 = blockIdx.x * BC_NODES;
    __shared__ float so[32 * 128];
    __shared__ float wt[BC_NODES * 32];
    for (int idx = t; idx < 32 * 128; idx += 256) so[idx] = slices_out[(size_t)b * SS * CC + idx];
    for (int idx = t; idx < BC_NODES * 32; idx += 256) {
        int n = n0 + (idx >> 5);
        wt[idx] = (n < NN) ? w[((size_t)b * NN + n) * SS + (idx & 31)] : 0.0f;
    }
    __syncthreads();
    #pragma unroll
    for (int k = 0; k < 16; k++) {
        int idx = t + k * 256;
        int ln = idx >> 7, c = idx & 127;
        int n = n0 + ln;
        if (n < NN) {
            float a = 0.0f;
            const float* wr = &wt[ln * 32];
            #pragma unroll 8
            for (int s = 0; s < 32; s++) a += wr[s] * so[s * 128 + c];
            x[((size_t)b * NN + n) * CC + c] += a;
        }
    }
}

// ---------------- pack FFN weights to bf16 fragment-friendly layouts ----------------
// W1p[l][j][c]  (512x128 per layer) = bf16(Wff1[l][c][j])   -- B of GEMM1, k=c contiguous
// W2p[l][c][j]  (128x512 per layer) = bf16(Wff2[l][j][c])   -- B of GEMM2, k=j contiguous
__global__ __launch_bounds__(256) void pack_ffn_weights(const float* Wff1, const float* Wff2,
                                                        u16* W1p, u16* W2p) {
    int idx = blockIdx.x * 256 + threadIdx.x;
    if (idx >= NL * FFN * CC) return;
    int l = idx / (FFN * CC);
    int r = idx - l * (FFN * CC);
    int j = r >> 7, c = r & 127;          // W1p flat index [l][j][c]
    W1p[idx] = f2bf(Wff1[(size_t)l * CC * FFN + (size_t)c * FFN + j]);
    int c2 = r >> 9, j2 = r & 511;        // W2p flat index [l][c2][j2]
    W2p[idx] = f2bf(Wff2[(size_t)l * FFN * CC + (size_t)j2 * CC + c2]);
}

// ---------------- fused FFN via MFMA: x += gelu(h2@Wff1+b1)@Wff2 + b2 ----------------
// block = 256 threads = 4 waves; tile = 128 nodes x 128 cols; wave quadrant 64x64.
__global__ __launch_bounds__(256, 2) void ffn_mfma(const u16* __restrict__ h2bf,
                                                   const u16* __restrict__ W1p,
                                                   const float* __restrict__ bff1,
                                                   const u16* __restrict__ W2p,
                                                   const float* __restrict__ bff2,
                                                   float* __restrict__ x) {
    __shared__ u16 lds_h[128 * 136];  // hidden chunk, bf16, +8 pad
    int t = threadIdx.x;
    int wave = t >> 6, lane = t & 63;
    int wm = wave >> 1, wn = wave & 1;
    int q = lane >> 4, ln16 = lane & 15;
    size_t m_blk = (size_t)blockIdx.x * FF_MT;

    f32x4 acc2[4][4];
    #pragma unroll
    for (int mi = 0; mi < 4; mi++)
        #pragma unroll
        for (int ni = 0; ni < 4; ni++) acc2[mi][ni] = (f32x4){0.f, 0.f, 0.f, 0.f};

    float b2[4];
    #pragma unroll
    for (int ni = 0; ni < 4; ni++) b2[ni] = bff2[wn * 64 + ni * 16 + ln16];

    for (int jc = 0; jc < 4; jc++) {
        // ---- GEMM1 chunk: hidden[:, jc*128 .. +128] = h2 @ Wff1 ----
        f32x4 acc1[4][4];
        #pragma unroll
        for (int mi = 0; mi < 4; mi++)
            #pragma unroll
            for (int ni = 0; ni < 4; ni++) acc1[mi][ni] = (f32x4){0.f, 0.f, 0.f, 0.f};

        #pragma unroll
        for (int ks = 0; ks < 4; ks++) {
            bf16x8 af[4], bfr[4];
            #pragma unroll
            for (int mi = 0; mi < 4; mi++)
                af[mi] = *(const bf16x8*)&h2bf[(m_blk + wm * 64 + mi * 16 + ln16) * CC + ks * 32 + q * 8];
            #pragma unroll
            for (int ni = 0; ni < 4; ni++)
                bfr[ni] = *(const bf16x8*)&W1p[(size_t)(jc * 128 + wn * 64 + ni * 16 + ln16) * CC + ks * 32 + q * 8];
            #pragma unroll
            for (int mi = 0; mi < 4; mi++)
                #pragma unroll
                for (int ni = 0; ni < 4; ni++)
                    acc1[mi][ni] = __builtin_amdgcn_mfma_f32_16x16x32_bf16(af[mi], bfr[ni], acc1[mi][ni], 0, 0, 0);
        }

        // ---- bias + gelu, pack to LDS as bf16 row-major [m][j] ----
        #pragma unroll
        for (int ni = 0; ni < 4; ni++) {
            float b1 = bff1[jc * 128 + wn * 64 + ni * 16 + ln16];
            #pragma unroll
            for (int mi = 0; mi < 4; mi++)
                #pragma unroll
                for (int r = 0; r < 4; r++) {
                    float a = acc1[mi][ni][r] + b1;
                    float gv = 0.5f * a * (1.0f + erff(a * 0.7071067811865475f));
                    lds_h[(wm * 64 + mi * 16 + q * 4 + r) * 136 + wn * 64 + ni * 16 + ln16] = f2bf(gv);
                }
        }
        __syncthreads();

        // ---- GEMM2 partial: acc2 += hidden_chunk @ Wff2[jc*128.. , :] ----
        #pragma unroll
        for (int ks2 = 0; ks2 < 4; ks2++) {
            bf16x8 af[4], bfr[4];
            #pragma unroll
            for (int mi = 0; mi < 4; mi++)
                af[mi] = *(const bf16x8*)&lds_h[(wm * 64 + mi * 16 + ln16) * 136 + ks2 * 32 + q * 8];
            #pragma unroll
            for (int ni = 0; ni < 4; ni++)
                bfr[ni] = *(const bf16x8*)&W2p[(size_t)(wn * 64 + ni * 16 + ln16) * FFN + jc * 128 + ks2 * 32 + q * 8];
            #pragma unroll
            for (int mi = 0; mi < 4; mi++)
                #pragma unroll
                for (int ni = 0; ni < 4; ni++)
                    acc2[mi][ni] = __builtin_amdgcn_mfma_f32_16x16x32_bf16(af[mi], bfr[ni], acc2[mi][ni], 0, 0, 0);
        }
        __syncthreads();
    }

    // ---- epilogue: x += acc2 + bff2 ----
    #pragma unroll
    for (int mi = 0; mi < 4; mi++)
        #pragma unroll
        for (int r = 0; r < 4; r++) {
            size_t node = m_blk + wm * 64 + mi * 16 + q * 4 + r;
            if (node < NTOT) {
                #pragma unroll
                for (int ni = 0; ni < 4; ni++) {
                    size_t off = node * CC + wn * 64 + ni * 16 + ln16;
                    x[off] += acc2[mi][ni][r] + b2[ni];
                }
            }
        }
}

// ---------------- final projection ----------------
__global__ __launch_bounds__(128) void proj_kernel(const float* x, const float* W,
                                                   const float* bias, float* outp) {
    int node = blockIdx.x;
    int t = threadIdx.x;
    __shared__ float xr[128];
    __shared__ float pr[40];
    xr[t] = x[(size_t)node * CC + t];
    __syncthreads();
    if (t < 40) {
        int k = t / 8, part = t % 8;
        float a = 0.0f;
        #pragma unroll
        for (int i = 0; i < 16; i++) {
            int c = part * 16 + i;
            a += xr[c] * W[c * C_IN + k];
        }
        pr[t] = a;
    }
    __syncthreads();
    if (t < 5) {
        float a = bias[t];
        #pragma unroll
        for (int p = 0; p < 8; p++) a += pr[t * 8 + p];
        outp[(size_t)node * C_IN + t] = a;
    }
}

extern "C" void kernel_launch(void* const* d_in, const int* in_sizes, int n_in,
                              void* d_out, int out_size, void* d_ws, size_t ws_size,
                              hipStream_t stream) {
    const float* inputs  = (const float*)d_in[0];
    const float* coords  = (const float*)d_in[1];
    const float* t_norm  = (const float*)d_in[2];
    const int*   adj     = (const int*)d_in[3];
    const float* adj_v   = (const float*)d_in[4];
    const float* freq    = (const float*)d_in[5];
    const float* embed_W = (const float*)d_in[6];
    const float* embed_b = (const float*)d_in[7];
    const float* ln1_g   = (const float*)d_in[8];
    const float* ln1_b   = (const float*)d_in[9];
    const float* Wslice  = (const float*)d_in[10];
    const float* bslice  = (const float*)d_in[11];
    const float* Wfront  = (const float*)d_in[12];
    const float* bfront  = (const float*)d_in[13];
    const float* Win     = (const float*)d_in[14];
    const float* b_in    = (const float*)d_in[15];
    const float* Wout    = (const float*)d_in[16];
    const float* bout    = (const float*)d_in[17];
    const float* ln2_g   = (const float*)d_in[18];
    const float* ln2_b   = (const float*)d_in[19];
    const float* Wff1    = (const float*)d_in[20];
    const float* bff1    = (const float*)d_in[21];
    const float* Wff2    = (const float*)d_in[22];
    const float* bff2    = (const float*)d_in[23];
    const float* proj_W  = (const float*)d_in[24];
    const float* proj_b  = (const float*)d_in[25];

    float* out = (float*)d_out;
    float* wout_base = out + (size_t)BATCH * NN * C_IN;

    // workspace layout (floats)
    float* x          = (float*)d_ws;
    float* h          = x + (size_t)NTOT * CC;
    float* hl         = h + (size_t)NTOT * CC;
    float* slices_acc = hl + (size_t)NTOT * CC;
    float* wsum       = slices_acc + BATCH * SS * CC;
    float* slices_out = wsum + BATCH * SS;
    float* csr_val    = slices_out + BATCH * SS * CC;
    int*   rowptr     = (int*)(csr_val + NE);
    int*   cursor     = rowptr + (NN + 1);
    int*   deg        = cursor + NN;
    int*   csr_col    = deg + NN;
    u16*   W1p        = (u16*)(csr_col + NE);       // NL*FFN*CC bf16
    u16*   W2p        = W1p + NL * FFN * CC;        // NL*CC*FFN bf16
    u16*   h2bf       = (u16*)h;                    // reuse h (dead after slices_acc); MPAD*CC bf16 = 25.6MB < 51.2MB

    // ---- CSR build ----
    hipMemsetAsync(deg, 0, NN * sizeof(int), stream);
    count_deg<<<(NE + 255) / 256, 256, 0, stream>>>(adj, deg);
    scan_deg<<<1, 512, 0, stream>>>(deg, rowptr);
    hipMemcpyAsync(cursor, rowptr, NN * sizeof(int), hipMemcpyDeviceToDevice, stream);
    fill_csr<<<(NE + 255) / 256, 256, 0, stream>>>(adj, adj + NE, adj_v, cursor, csr_col, csr_val);

    // ---- pack FFN weights (bf16) ----
    pack_ffn_weights<<<(NL * FFN * CC + 255) / 256, 256, 0, stream>>>(Wff1, Wff2, W1p, W2p);

    // ---- embed ----
    embed_kernel<<<NTOT, 128, 0, stream>>>(inputs, coords, t_norm, freq, embed_W, embed_b, x);

    for (int l = 0; l < NL; l++) {
        float* wl = wout_base + (size_t)l * NTOT * SS;
        ln_kernel<<<NTOT, 128, 0, stream>>>(x, ln1_g + l * CC, ln1_b + l * CC, h);
        agg_kernel<<<NTOT, 128, 0, stream>>>(h, rowptr, csr_col, csr_val, hl);
        logits_kernel<<<NTOT, 128, 0, stream>>>(h, hl, Wslice + (size_t)l * CC * SS,
                                                bslice + l * SS, Wfront + (size_t)l * CC * SS,
                                                bfront + l * SS, wl);
        hipMemsetAsync(slices_acc, 0, (BATCH * SS * CC + BATCH * SS) * sizeof(float), stream);
        dim3 g1((NN + SL_NODES - 1) / SL_NODES, BATCH);
        slices_acc_kernel<<<g1, 256, 0, stream>>>(wl, h, slices_acc, wsum);
        mha_kernel<<<BATCH, 256, 0, stream>>>(slices_acc, wsum, Win + (size_t)l * CC * 3 * CC,
                                              b_in + l * 3 * CC, Wout + (size_t)l * CC * CC,
                                              bout + l * CC, slices_out);
        dim3 g2((NN + BC_NODES - 1) / BC_NODES, BATCH);
        broadcast_kernel<<<g2, 256, 0, stream>>>(wl, slices_out, x);
        // h is dead from here; reuse as bf16 h2 buffer
        ln_bf16_kernel<<<MPAD, 128, 0, stream>>>(x, ln2_g + l * CC, ln2_b + l * CC, h2bf);
        ffn_mfma<<<FF_BLOCKS, 256, 0, stream>>>(h2bf, W1p + (size_t)l * FFN * CC,
                                                bff1 + l * FFN, W2p + (size_t)l * CC * FFN,
                                                bff2 + l * CC, x);
    }

    proj_kernel<<<NTOT, 128, 0, stream>>>(x, proj_W, proj_b, out);
}

// Round 3
// 3264.822 us; speedup vs baseline: 2.3919x; 1.1999x over previous
//
#include <hip/hip_runtime.h>
#include <math.h>

#define BATCH 2
#define NN 50000
#define NE 400000
#define C_IN 5
#define CC 128
#define SS 32
#define NH 8
#define NL 4
#define FFN 512
#define COORD_F 8
#define TIME_F 4
#define HD 16
#define BETA 1.0f
#define TWO_PI 6.283185307179586476925287f

#define SL_NODES 256
#define BC_NODES 32
#define NTOT (BATCH * NN)
#define FF_MT 128
#define FF_BLOCKS ((NTOT + FF_MT - 1) / FF_MT)   // 782
#define MPAD (FF_BLOCKS * FF_MT)                  // 100096

typedef unsigned short u16;
typedef unsigned int u32;
typedef __attribute__((ext_vector_type(8))) __bf16 bf16x8;
typedef __attribute__((ext_vector_type(4))) float f32x4;

__device__ __forceinline__ u16 f2bf(float f) {
    union { float f; u32 u; } v; v.f = f;
    u32 u = v.u;
    u32 r = (u + 0x7fffu + ((u >> 16) & 1u)) >> 16;
    return (u16)r;
}

// ---------------- CSR build ----------------
__global__ void count_deg(const int* rows, int* deg) {
    int e = blockIdx.x * blockDim.x + threadIdx.x;
    if (e < NE) atomicAdd(&deg[rows[e]], 1);
}

__global__ __launch_bounds__(512) void scan_deg(const int* deg, int* rowptr) {
    __shared__ int part[512];
    int t = threadIdx.x;
    const int CH = (NN + 511) / 512;  // 98
    int begin = t * CH, end = min(begin + CH, NN);
    int s = 0;
    for (int i = begin; i < end; i++) s += deg[i];
    part[t] = s;
    __syncthreads();
    for (int off = 1; off < 512; off <<= 1) {
        int v = (t >= off) ? part[t - off] : 0;
        __syncthreads();
        part[t] += v;
        __syncthreads();
    }
    int base = (t == 0) ? 0 : part[t - 1];
    for (int i = begin; i < end; i++) { rowptr[i] = base; base += deg[i]; }
    if (t == 511) rowptr[NN] = part[511];
}

__global__ void fill_csr(const int* rows, const int* cols, const float* vals,
                         int* cursor, int* csr_col, float* csr_val) {
    int e = blockIdx.x * blockDim.x + threadIdx.x;
    if (e < NE) {
        int p = atomicAdd(&cursor[rows[e]], 1);
        csr_col[p] = cols[e];
        csr_val[p] = vals[e];
    }
}

// ---------------- embed ----------------
__global__ __launch_bounds__(128) void embed_kernel(const float* inputs, const float* coords,
                                                    const float* t_norm, const float* freq,
                                                    const float* W, const float* bias, float* x) {
    int node = blockIdx.x;  // 0..BATCH*NN
    int b = node / NN;
    int t = threadIdx.x;
    __shared__ float feat[32];
    if (t < 8) {
        float c0 = coords[node * 2 + 0], c1 = coords[node * 2 + 1];
        float p = TWO_PI * (c0 * freq[t] + c1 * freq[8 + t]);
        feat[5 + t] = sinf(p);
        feat[13 + t] = cosf(p);
    } else if (t < 12) {
        int j = t - 8;
        float omega = powf(1000.0f, -(float)j * 0.25f);
        float ang = omega * t_norm[b] * 1000.0f;
        feat[21 + j] = sinf(ang);
        feat[25 + j] = cosf(ang);
    } else if (t >= 16 && t < 21) {
        feat[t - 16] = inputs[node * 5 + (t - 16)];
    }
    __syncthreads();
    float acc = bias[t];
    #pragma unroll
    for (int k = 0; k < 29; k++) acc += feat[k] * W[k * CC + t];
    x[(size_t)node * CC + t] = acc;
}

// ---------------- layernorm (fp32 out) ----------------
__global__ __launch_bounds__(128) void ln_kernel(const float* xin, const float* g, const float* bb,
                                                 float* outp) {
    int node = blockIdx.x;
    int t = threadIdx.x;
    __shared__ float red[128];
    float v = xin[(size_t)node * CC + t];
    red[t] = v;
    __syncthreads();
    for (int off = 64; off > 0; off >>= 1) { if (t < off) red[t] += red[t + off]; __syncthreads(); }
    float mean = red[0] * (1.0f / 128.0f);
    __syncthreads();
    float d = v - mean;
    red[t] = d * d;
    __syncthreads();
    for (int off = 64; off > 0; off >>= 1) { if (t < off) red[t] += red[t + off]; __syncthreads(); }
    float var = red[0] * (1.0f / 128.0f);
    outp[(size_t)node * CC + t] = d * rsqrtf(var + 1e-5f) * g[t] + bb[t];
}

// ---------------- layernorm (bf16 out, zero-padded to MPAD) ----------------
__global__ __launch_bounds__(128) void ln_bf16_kernel(const float* xin, const float* g,
                                                      const float* bb, u16* outp) {
    int node = blockIdx.x;
    int t = threadIdx.x;
    if (node >= NTOT) { outp[(size_t)node * CC + t] = 0; return; }
    __shared__ float red[128];
    float v = xin[(size_t)node * CC + t];
    red[t] = v;
    __syncthreads();
    for (int off = 64; off > 0; off >>= 1) { if (t < off) red[t] += red[t + off]; __syncthreads(); }
    float mean = red[0] * (1.0f / 128.0f);
    __syncthreads();
    float d = v - mean;
    red[t] = d * d;
    __syncthreads();
    for (int off = 64; off > 0; off >>= 1) { if (t < off) red[t] += red[t + off]; __syncthreads(); }
    float var = red[0] * (1.0f / 128.0f);
    outp[(size_t)node * CC + t] = f2bf(d * rsqrtf(var + 1e-5f) * g[t] + bb[t]);
}

// ---------------- sparse aggregation (gather via CSR) ----------------
__global__ __launch_bounds__(128) void agg_kernel(const float* h, const int* rowptr,
                                                  const int* csr_col, const float* csr_val,
                                                  float* hl) {
    int blk = blockIdx.x;         // 0..BATCH*NN
    int b = blk / NN, r = blk % NN;
    int t = threadIdx.x;
    int s0 = rowptr[r], s1 = rowptr[r + 1];
    const float* hb = h + (size_t)b * NN * CC;
    float acc = 0.0f;
    for (int e = s0; e < s1; e++) acc += csr_val[e] * hb[(size_t)csr_col[e] * CC + t];
    hl[(size_t)blk * CC + t] = acc;
}

// ---------------- logits + softmax -> w ----------------
__global__ __launch_bounds__(128) void logits_kernel(const float* h, const float* hl,
                                                     const float* Ws, const float* bs,
                                                     const float* Wf, const float* bf,
                                                     float* wout) {
    int node = blockIdx.x;
    int t = threadIdx.x;
    __shared__ float hsh[128], hfsh[128];
    __shared__ float part[4][32];
    float hv = h[(size_t)node * CC + t];
    float hlv = hl[(size_t)node * CC + t];
    hsh[t] = hv;
    hfsh[t] = hv - hlv;
    __syncthreads();
    int s = t & 31, chunk = t >> 5;
    float p = 0.0f;
    #pragma unroll 8
    for (int i = 0; i < 32; i++) {
        int c = chunk * 32 + i;
        p += hsh[c] * Ws[c * SS + s] + BETA * hfsh[c] * Wf[c * SS + s];
    }
    part[chunk][s] = p;
    __syncthreads();
    if (t < 32) {
        float logit = part[0][t] + part[1][t] + part[2][t] + part[3][t] + bs[t] + BETA * bf[t];
        float m = logit;
        for (int off = 16; off > 0; off >>= 1) m = fmaxf(m, __shfl_xor(m, off, 32));
        float e = expf(logit - m);
        float sum = e;
        for (int off = 16; off > 0; off >>= 1) sum += __shfl_xor(sum, off, 32);
        wout[(size_t)node * SS + t] = e / sum;
    }
}

// ---------------- slice pooling ----------------
__global__ __launch_bounds__(256) void slices_acc_kernel(const float* w, const float* h,
                                                         float* slices_acc, float* wsum) {
    int b = blockIdx.y, t = threadIdx.x;
    int n0 = blockIdx.x * SL_NODES;
    __shared__ float wsh[32];
    __shared__ float hsh[128];
    int c = t & 127, sg = t >> 7;
    float acc[16];
    #pragma unroll
    for (int k = 0; k < 16; k++) acc[k] = 0.0f;
    float wsum_loc = 0.0f;
    for (int i = 0; i < SL_NODES; i++) {
        int n = n0 + i;
        __syncthreads();
        if (n < NN) {
            if (t < 32) wsh[t] = w[((size_t)b * NN + n) * SS + t];
            else if (t >= 64 && t < 192) hsh[t - 64] = h[((size_t)b * NN + n) * CC + (t - 64)];
        } else {
            if (t < 32) wsh[t] = 0.0f;
            else if (t >= 64 && t < 192) hsh[t - 64] = 0.0f;
        }
        __syncthreads();
        float hv = hsh[c];
        #pragma unroll
        for (int k = 0; k < 16; k++) acc[k] += wsh[sg * 16 + k] * hv;
        if (t < 32) wsum_loc += wsh[t];
    }
    #pragma unroll
    for (int k = 0; k < 16; k++)
        atomicAdd(&slices_acc[(size_t)b * SS * CC + (sg * 16 + k) * CC + c], acc[k]);
    if (t < 32) atomicAdd(&wsum[b * SS + t], wsum_loc);
}

// ---------------- slice MHA, stage 1: qkv = (slices/wsum) @ Win + b_in ----------------
__global__ __launch_bounds__(128) void qkv_kernel(const float* slices_acc, const float* wsum,
                                                  const float* Win, const float* b_in_p,
                                                  float* qkv) {
    int blk = blockIdx.x;  // b*SS + s
    int b = blk >> 5;
    int t = threadIdx.x;
    __shared__ float row[128];
    float iv = 1.0f / fmaxf(wsum[blk], 1e-8f);
    row[t] = slices_acc[(size_t)blk * CC + t] * iv;
    (void)b;
    __syncthreads();
    #pragma unroll
    for (int jj = 0; jj < 3; jj++) {
        int j = t + jj * 128;
        float a = b_in_p[j];
        #pragma unroll 8
        for (int c = 0; c < 128; c++) a += row[c] * Win[c * 384 + j];
        qkv[(size_t)blk * 384 + j] = a;
    }
}

// ---------------- slice MHA, stage 2: attention per (b,h) ----------------
__global__ __launch_bounds__(64) void attn_kernel(const float* qkv, float* ovals) {
    int blk = blockIdx.x;  // b*NH + h
    int b = blk >> 3, h = blk & 7;
    int t = threadIdx.x;
    __shared__ float ksh[32 * 16], vsh[32 * 16];
    for (int i = t; i < 512; i += 64) {
        int k = i >> 4, d = i & 15;
        ksh[i] = qkv[((size_t)b * 32 + k) * 384 + 128 + h * 16 + d];
        vsh[i] = qkv[((size_t)b * 32 + k) * 384 + 256 + h * 16 + d];
    }
    __syncthreads();
    if (t < 32) {
        float qr[16];
        #pragma unroll
        for (int d = 0; d < 16; d++) qr[d] = qkv[((size_t)b * 32 + t) * 384 + h * 16 + d];
        float sc[32];
        float m = -1e30f;
        for (int k = 0; k < 32; k++) {
            float a = 0.0f;
            #pragma unroll
            for (int d = 0; d < 16; d++) a += qr[d] * ksh[k * 16 + d];
            a *= 0.25f;  // 1/sqrt(16)
            sc[k] = a;
            m = fmaxf(m, a);
        }
        float ssum = 0.0f;
        for (int k = 0; k < 32; k++) { float e = expf(sc[k] - m); sc[k] = e; ssum += e; }
        float is = 1.0f / ssum;
        float o[16];
        #pragma unroll
        for (int d = 0; d < 16; d++) o[d] = 0.0f;
        for (int k = 0; k < 32; k++) {
            float p = sc[k] * is;
            #pragma unroll
            for (int d = 0; d < 16; d++) o[d] += p * vsh[k * 16 + d];
        }
        #pragma unroll
        for (int d = 0; d < 16; d++) ovals[((size_t)b * 32 + t) * 128 + h * 16 + d] = o[d];
    }
}

// ---------------- slice MHA, stage 3: slices_out = o @ Wout + bout ----------------
__global__ __launch_bounds__(128) void mha_out_kernel(const float* ovals, const float* Wout,
                                                      const float* bout, float* slices_out) {
    int blk = blockIdx.x;  // b*SS + s
    int t = threadIdx.x;
    __shared__ float row[128];
    row[t] = ovals[(size_t)blk * 128 + t];
    __syncthreads();
    float a = bout[t];
    #pragma unroll 8
    for (int cc = 0; cc < 128; cc++) a += row[cc] * Wout[cc * CC + t];
    slices_out[(size_t)blk * 128 + t] = a;
}

// ---------------- broadcast back: x += w @ slices_out ----------------
__global__ __launch_bounds__(256) void broadcast_kernel(const float* w, const float* slices_out,
                                                        float* x) {
    int b = blockIdx.y, t = threadIdx.x;
    int n0 = blockIdx.x * BC_NODES;
    __shared__ float so[32 * 128];
    __shared__ float wt[BC_NODES * 32];
    for (int idx = t; idx < 32 * 128; idx += 256) so[idx] = slices_out[(size_t)b * SS * CC + idx];
    for (int idx = t; idx < BC_NODES * 32; idx += 256) {
        int n = n0 + (idx >> 5);
        wt[idx] = (n < NN) ? w[((size_t)b * NN + n) * SS + (idx & 31)] : 0.0f;
    }
    __syncthreads();
    #pragma unroll
    for (int k = 0; k < 16; k++) {
        int idx = t + k * 256;
        int ln = idx >> 7, c = idx & 127;
        int n = n0 + ln;
        if (n < NN) {
            float a = 0.0f;
            const float* wr = &wt[ln * 32];
            #pragma unroll 8
            for (int s = 0; s < 32; s++) a += wr[s] * so[s * 128 + c];
            x[((size_t)b * NN + n) * CC + c] += a;
        }
    }
}

// ---------------- pack FFN weights to bf16 fragment-friendly layouts ----------------
__global__ __launch_bounds__(256) void pack_ffn_weights(const float* Wff1, const float* Wff2,
                                                        u16* W1p, u16* W2p) {
    int idx = blockIdx.x * 256 + threadIdx.x;
    if (idx >= NL * FFN * CC) return;
    int l = idx / (FFN * CC);
    int r = idx - l * (FFN * CC);
    int j = r >> 7, c = r & 127;          // W1p flat index [l][j][c]
    W1p[idx] = f2bf(Wff1[(size_t)l * CC * FFN + (size_t)c * FFN + j]);
    int c2 = r >> 9, j2 = r & 511;        // W2p flat index [l][c2][j2]
    W2p[idx] = f2bf(Wff2[(size_t)l * FFN * CC + (size_t)j2 * CC + c2]);
}

// ---------------- fused FFN via MFMA: x += gelu(h2@Wff1+b1)@Wff2 + b2 ----------------
__global__ __launch_bounds__(256, 2) void ffn_mfma(const u16* __restrict__ h2bf,
                                                   const u16* __restrict__ W1p,
                                                   const float* __restrict__ bff1,
                                                   const u16* __restrict__ W2p,
                                                   const float* __restrict__ bff2,
                                                   float* __restrict__ x) {
    __shared__ u16 lds_h[128 * 136];  // hidden chunk, bf16, +8 pad
    int t = threadIdx.x;
    int wave = t >> 6, lane = t & 63;
    int wm = wave >> 1, wn = wave & 1;
    int q = lane >> 4, ln16 = lane & 15;
    size_t m_blk = (size_t)blockIdx.x * FF_MT;

    f32x4 acc2[4][4];
    #pragma unroll
    for (int mi = 0; mi < 4; mi++)
        #pragma unroll
        for (int ni = 0; ni < 4; ni++) acc2[mi][ni] = (f32x4){0.f, 0.f, 0.f, 0.f};

    float b2[4];
    #pragma unroll
    for (int ni = 0; ni < 4; ni++) b2[ni] = bff2[wn * 64 + ni * 16 + ln16];

    for (int jc = 0; jc < 4; jc++) {
        f32x4 acc1[4][4];
        #pragma unroll
        for (int mi = 0; mi < 4; mi++)
            #pragma unroll
            for (int ni = 0; ni < 4; ni++) acc1[mi][ni] = (f32x4){0.f, 0.f, 0.f, 0.f};

        #pragma unroll
        for (int ks = 0; ks < 4; ks++) {
            bf16x8 af[4], bfr[4];
            #pragma unroll
            for (int mi = 0; mi < 4; mi++)
                af[mi] = *(const bf16x8*)&h2bf[(m_blk + wm * 64 + mi * 16 + ln16) * CC + ks * 32 + q * 8];
            #pragma unroll
            for (int ni = 0; ni < 4; ni++)
                bfr[ni] = *(const bf16x8*)&W1p[(size_t)(jc * 128 + wn * 64 + ni * 16 + ln16) * CC + ks * 32 + q * 8];
            #pragma unroll
            for (int mi = 0; mi < 4; mi++)
                #pragma unroll
                for (int ni = 0; ni < 4; ni++)
                    acc1[mi][ni] = __builtin_amdgcn_mfma_f32_16x16x32_bf16(af[mi], bfr[ni], acc1[mi][ni], 0, 0, 0);
        }

        #pragma unroll
        for (int ni = 0; ni < 4; ni++) {
            float b1 = bff1[jc * 128 + wn * 64 + ni * 16 + ln16];
            #pragma unroll
            for (int mi = 0; mi < 4; mi++)
                #pragma unroll
                for (int r = 0; r < 4; r++) {
                    float a = acc1[mi][ni][r] + b1;
                    float gv = 0.5f * a * (1.0f + erff(a * 0.7071067811865475f));
                    lds_h[(wm * 64 + mi * 16 + q * 4 + r) * 136 + wn * 64 + ni * 16 + ln16] = f2bf(gv);
                }
        }
        __syncthreads();

        #pragma unroll
        for (int ks2 = 0; ks2 < 4; ks2++) {
            bf16x8 af[4], bfr[4];
            #pragma unroll
            for (int mi = 0; mi < 4; mi++)
                af[mi] = *(const bf16x8*)&lds_h[(wm * 64 + mi * 16 + ln16) * 136 + ks2 * 32 + q * 8];
            #pragma unroll
            for (int ni = 0; ni < 4; ni++)
                bfr[ni] = *(const bf16x8*)&W2p[(size_t)(wn * 64 + ni * 16 + ln16) * FFN + jc * 128 + ks2 * 32 + q * 8];
            #pragma unroll
            for (int mi = 0; mi < 4; mi++)
                #pragma unroll
                for (int ni = 0; ni < 4; ni++)
                    acc2[mi][ni] = __builtin_amdgcn_mfma_f32_16x16x32_bf16(af[mi], bfr[ni], acc2[mi][ni], 0, 0, 0);
        }
        __syncthreads();
    }

    #pragma unroll
    for (int mi = 0; mi < 4; mi++)
        #pragma unroll
        for (int r = 0; r < 4; r++) {
            size_t node = m_blk + wm * 64 + mi * 16 + q * 4 + r;
            if (node < NTOT) {
                #pragma unroll
                for (int ni = 0; ni < 4; ni++) {
                    size_t off = node * CC + wn * 64 + ni * 16 + ln16;
                    x[off] += acc2[mi][ni][r] + b2[ni];
                }
            }
        }
}

// ---------------- final projection ----------------
__global__ __launch_bounds__(128) void proj_kernel(const float* x, const float* W,
                                                   const float* bias, float* outp) {
    int node = blockIdx.x;
    int t = threadIdx.x;
    __shared__ float xr[128];
    __shared__ float pr[40];
    xr[t] = x[(size_t)node * CC + t];
    __syncthreads();
    if (t < 40) {
        int k = t / 8, part = t % 8;
        float a = 0.0f;
        #pragma unroll
        for (int i = 0; i < 16; i++) {
            int c = part * 16 + i;
            a += xr[c] * W[c * C_IN + k];
        }
        pr[t] = a;
    }
    __syncthreads();
    if (t < 5) {
        float a = bias[t];
        #pragma unroll
        for (int p = 0; p < 8; p++) a += pr[t * 8 + p];
        outp[(size_t)node * C_IN + t] = a;
    }
}

extern "C" void kernel_launch(void* const* d_in, const int* in_sizes, int n_in,
                              void* d_out, int out_size, void* d_ws, size_t ws_size,
                              hipStream_t stream) {
    const float* inputs  = (const float*)d_in[0];
    const float* coords  = (const float*)d_in[1];
    const float* t_norm  = (const float*)d_in[2];
    const int*   adj     = (const int*)d_in[3];
    const float* adj_v   = (const float*)d_in[4];
    const float* freq    = (const float*)d_in[5];
    const float* embed_W = (const float*)d_in[6];
    const float* embed_b = (const float*)d_in[7];
    const float* ln1_g   = (const float*)d_in[8];
    const float* ln1_b   = (const float*)d_in[9];
    const float* Wslice  = (const float*)d_in[10];
    const float* bslice  = (const float*)d_in[11];
    const float* Wfront  = (const float*)d_in[12];
    const float* bfront  = (const float*)d_in[13];
    const float* Win     = (const float*)d_in[14];
    const float* b_in    = (const float*)d_in[15];
    const float* Wout    = (const float*)d_in[16];
    const float* bout    = (const float*)d_in[17];
    const float* ln2_g   = (const float*)d_in[18];
    const float* ln2_b   = (const float*)d_in[19];
    const float* Wff1    = (const float*)d_in[20];
    const float* bff1    = (const float*)d_in[21];
    const float* Wff2    = (const float*)d_in[22];
    const float* bff2    = (const float*)d_in[23];
    const float* proj_W  = (const float*)d_in[24];
    const float* proj_b  = (const float*)d_in[25];

    float* out = (float*)d_out;
    float* wout_base = out + (size_t)BATCH * NN * C_IN;

    // workspace layout (floats)
    float* x          = (float*)d_ws;
    float* h          = x + (size_t)NTOT * CC;
    float* hl         = h + (size_t)NTOT * CC;
    float* slices_acc = hl + (size_t)NTOT * CC;
    float* wsum       = slices_acc + BATCH * SS * CC;
    float* slices_out = wsum + BATCH * SS;
    float* qkv_ws     = slices_out + BATCH * SS * CC;
    float* ovals_ws   = qkv_ws + BATCH * SS * 384;
    float* csr_val    = ovals_ws + BATCH * SS * CC;
    int*   rowptr     = (int*)(csr_val + NE);
    int*   cursor     = rowptr + (NN + 1);
    int*   deg        = cursor + NN;
    int*   csr_col    = deg + NN;
    u16*   W1p        = (u16*)(csr_col + NE);       // NL*FFN*CC bf16
    u16*   W2p        = W1p + NL * FFN * CC;        // NL*CC*FFN bf16
    u16*   h2bf       = (u16*)h;                    // reuse h (dead after slices_acc)

    // ---- CSR build ----
    hipMemsetAsync(deg, 0, NN * sizeof(int), stream);
    count_deg<<<(NE + 255) / 256, 256, 0, stream>>>(adj, deg);
    scan_deg<<<1, 512, 0, stream>>>(deg, rowptr);
    hipMemcpyAsync(cursor, rowptr, NN * sizeof(int), hipMemcpyDeviceToDevice, stream);
    fill_csr<<<(NE + 255) / 256, 256, 0, stream>>>(adj, adj + NE, adj_v, cursor, csr_col, csr_val);

    // ---- pack FFN weights (bf16) ----
    pack_ffn_weights<<<(NL * FFN * CC + 255) / 256, 256, 0, stream>>>(Wff1, Wff2, W1p, W2p);

    // ---- embed ----
    embed_kernel<<<NTOT, 128, 0, stream>>>(inputs, coords, t_norm, freq, embed_W, embed_b, x);

    for (int l = 0; l < NL; l++) {
        float* wl = wout_base + (size_t)l * NTOT * SS;
        ln_kernel<<<NTOT, 128, 0, stream>>>(x, ln1_g + l * CC, ln1_b + l * CC, h);
        agg_kernel<<<NTOT, 128, 0, stream>>>(h, rowptr, csr_col, csr_val, hl);
        logits_kernel<<<NTOT, 128, 0, stream>>>(h, hl, Wslice + (size_t)l * CC * SS,
                                                bslice + l * SS, Wfront + (size_t)l * CC * SS,
                                                bfront + l * SS, wl);
        hipMemsetAsync(slices_acc, 0, (BATCH * SS * CC + BATCH * SS) * sizeof(float), stream);
        dim3 g1((NN + SL_NODES - 1) / SL_NODES, BATCH);
        slices_acc_kernel<<<g1, 256, 0, stream>>>(wl, h, slices_acc, wsum);
        // MHA (parallel 3-stage)
        qkv_kernel<<<BATCH * SS, 128, 0, stream>>>(slices_acc, wsum,
                                                   Win + (size_t)l * CC * 3 * CC,
                                                   b_in + l * 3 * CC, qkv_ws);
        attn_kernel<<<BATCH * NH, 64, 0, stream>>>(qkv_ws, ovals_ws);
        mha_out_kernel<<<BATCH * SS, 128, 0, stream>>>(ovals_ws, Wout + (size_t)l * CC * CC,
                                                       bout + l * CC, slices_out);
        dim3 g2((NN + BC_NODES - 1) / BC_NODES, BATCH);
        broadcast_kernel<<<g2, 256, 0, stream>>>(wl, slices_out, x);
        // h is dead from here; reuse as bf16 h2 buffer
        ln_bf16_kernel<<<MPAD, 128, 0, stream>>>(x, ln2_g + l * CC, ln2_b + l * CC, h2bf);
        ffn_mfma<<<FF_BLOCKS, 256, 0, stream>>>(h2bf, W1p + (size_t)l * FFN * CC,
                                                bff1 + l * FFN, W2p + (size_t)l * CC * FFN,
                                                bff2 + l * CC, x);
    }

    proj_kernel<<<NTOT, 128, 0, stream>>>(x, proj_W, proj_b, out);
}

// Round 4
// 2702.552 us; speedup vs baseline: 2.8896x; 1.2081x over previous
//
#include <hip/hip_runtime.h>
#include <math.h>

#define BATCH 2
#define NN 50000
#define NE 400000
#define C_IN 5
#define CC 128
#define SS 32
#define NH 8
#define NL 4
#define FFN 512
#define COORD_F 8
#define TIME_F 4
#define HD 16
#define BETA 1.0f
#define TWO_PI 6.283185307179586476925287f

#define SL_NODES 256
#define BC_NODES 32
#define NTOT (BATCH * NN)
#define FF_MT 128
#define FF_BLOCKS ((NTOT + FF_MT - 1) / FF_MT)   // 782
#define MPAD (FF_BLOCKS * FF_MT)                  // 100096

typedef unsigned short u16;
typedef unsigned int u32;
typedef __attribute__((ext_vector_type(8))) __bf16 bf16x8;
typedef __attribute__((ext_vector_type(4))) float f32x4;

__device__ __forceinline__ u16 f2bf(float f) {
    union { float f; u32 u; } v; v.f = f;
    u32 u = v.u;
    u32 r = (u + 0x7fffu + ((u >> 16) & 1u)) >> 16;
    return (u16)r;
}

// ---------------- CSR build ----------------
__global__ void count_deg(const int* rows, int* deg) {
    int e = blockIdx.x * blockDim.x + threadIdx.x;
    if (e < NE) atomicAdd(&deg[rows[e]], 1);
}

__global__ __launch_bounds__(512) void scan_deg(const int* deg, int* rowptr) {
    __shared__ int part[512];
    int t = threadIdx.x;
    const int CH = (NN + 511) / 512;  // 98
    int begin = t * CH, end = min(begin + CH, NN);
    int s = 0;
    for (int i = begin; i < end; i++) s += deg[i];
    part[t] = s;
    __syncthreads();
    for (int off = 1; off < 512; off <<= 1) {
        int v = (t >= off) ? part[t - off] : 0;
        __syncthreads();
        part[t] += v;
        __syncthreads();
    }
    int base = (t == 0) ? 0 : part[t - 1];
    for (int i = begin; i < end; i++) { rowptr[i] = base; base += deg[i]; }
    if (t == 511) rowptr[NN] = part[511];
}

__global__ void fill_csr(const int* rows, const int* cols, const float* vals,
                         int* cursor, int* csr_col, float* csr_val) {
    int e = blockIdx.x * blockDim.x + threadIdx.x;
    if (e < NE) {
        int p = atomicAdd(&cursor[rows[e]], 1);
        csr_col[p] = cols[e];
        csr_val[p] = vals[e];
    }
}

// ---------------- embed ----------------
__global__ __launch_bounds__(128) void embed_kernel(const float* inputs, const float* coords,
                                                    const float* t_norm, const float* freq,
                                                    const float* W, const float* bias, float* x) {
    int node = blockIdx.x;  // 0..BATCH*NN
    int b = node / NN;
    int t = threadIdx.x;
    __shared__ float feat[32];
    if (t < 8) {
        float c0 = coords[node * 2 + 0], c1 = coords[node * 2 + 1];
        float p = TWO_PI * (c0 * freq[t] + c1 * freq[8 + t]);
        feat[5 + t] = sinf(p);
        feat[13 + t] = cosf(p);
    } else if (t < 12) {
        int j = t - 8;
        float omega = powf(1000.0f, -(float)j * 0.25f);
        float ang = omega * t_norm[b] * 1000.0f;
        feat[21 + j] = sinf(ang);
        feat[25 + j] = cosf(ang);
    } else if (t >= 16 && t < 21) {
        feat[t - 16] = inputs[node * 5 + (t - 16)];
    }
    __syncthreads();
    float acc = bias[t];
    #pragma unroll
    for (int k = 0; k < 29; k++) acc += feat[k] * W[k * CC + t];
    x[(size_t)node * CC + t] = acc;
}

// ---------------- layernorm 1 (fp32 + bf16 out) ----------------
__global__ __launch_bounds__(128) void ln_kernel(const float* xin, const float* g, const float* bb,
                                                 float* outp, u16* outbf) {
    int node = blockIdx.x;
    int t = threadIdx.x;
    __shared__ float red[128];
    float v = xin[(size_t)node * CC + t];
    red[t] = v;
    __syncthreads();
    for (int off = 64; off > 0; off >>= 1) { if (t < off) red[t] += red[t + off]; __syncthreads(); }
    float mean = red[0] * (1.0f / 128.0f);
    __syncthreads();
    float d = v - mean;
    red[t] = d * d;
    __syncthreads();
    for (int off = 64; off > 0; off >>= 1) { if (t < off) red[t] += red[t + off]; __syncthreads(); }
    float var = red[0] * (1.0f / 128.0f);
    float r = d * rsqrtf(var + 1e-5f) * g[t] + bb[t];
    outp[(size_t)node * CC + t] = r;
    outbf[(size_t)node * CC + t] = f2bf(r);
}

// ---------------- layernorm (bf16 out, zero-padded to MPAD) ----------------
__global__ __launch_bounds__(128) void ln_bf16_kernel(const float* xin, const float* g,
                                                      const float* bb, u16* outp) {
    int node = blockIdx.x;
    int t = threadIdx.x;
    if (node >= NTOT) { outp[(size_t)node * CC + t] = 0; return; }
    __shared__ float red[128];
    float v = xin[(size_t)node * CC + t];
    red[t] = v;
    __syncthreads();
    for (int off = 64; off > 0; off >>= 1) { if (t < off) red[t] += red[t + off]; __syncthreads(); }
    float mean = red[0] * (1.0f / 128.0f);
    __syncthreads();
    float d = v - mean;
    red[t] = d * d;
    __syncthreads();
    for (int off = 64; off > 0; off >>= 1) { if (t < off) red[t] += red[t + off]; __syncthreads(); }
    float var = red[0] * (1.0f / 128.0f);
    outp[(size_t)node * CC + t] = f2bf(d * rsqrtf(var + 1e-5f) * g[t] + bb[t]);
}

// ---------------- sparse aggregation (gather via CSR, bf16 out) ----------------
__global__ __launch_bounds__(128) void agg_kernel(const float* h, const int* rowptr,
                                                  const int* csr_col, const float* csr_val,
                                                  u16* hlbf) {
    int blk = blockIdx.x;         // 0..BATCH*NN
    int b = blk / NN, r = blk % NN;
    int t = threadIdx.x;
    int s0 = rowptr[r], s1 = rowptr[r + 1];
    const float* hb = h + (size_t)b * NN * CC;
    float acc = 0.0f;
    for (int e = s0; e < s1; e++) acc += csr_val[e] * hb[(size_t)csr_col[e] * CC + t];
    hlbf[(size_t)blk * CC + t] = f2bf(acc);
}

// ---------------- pack combined logits weights ----------------
// Wcombp[l][s][k] (32x256, k contiguous): k<128 -> Ws[k][s]+B*Wf[k][s]; else -B*Wf[k-128][s]
__global__ __launch_bounds__(256) void pack_logits_weights(const float* Ws, const float* bs,
                                                           const float* Wf, const float* bf,
                                                           u16* Wcombp, float* bcombp) {
    int idx = blockIdx.x * 256 + threadIdx.x;
    if (idx >= NL * SS * 256) return;
    int l = idx / (SS * 256);
    int r = idx - l * (SS * 256);
    int s = r >> 8, k = r & 255;
    float v;
    if (k < 128)
        v = Ws[(size_t)l * CC * SS + (size_t)k * SS + s] + BETA * Wf[(size_t)l * CC * SS + (size_t)k * SS + s];
    else
        v = -BETA * Wf[(size_t)l * CC * SS + (size_t)(k - 128) * SS + s];
    Wcombp[idx] = f2bf(v);
    if (k == 0) bcombp[l * SS + s] = bs[l * SS + s] + BETA * bf[l * SS + s];
}

// ---------------- logits + softmax via MFMA: w = softmax([h|hl] @ Wcomb^T + bcomb) ----------------
// block = 256 threads = 4 waves; 128 nodes/block, N=32, K=256.
__global__ __launch_bounds__(256, 2) void logits_mfma(const u16* __restrict__ hbf,
                                                      const u16* __restrict__ hlbf,
                                                      const u16* __restrict__ Wcomb,
                                                      const float* __restrict__ bcomb,
                                                      float* __restrict__ wout) {
    __shared__ float lg[128 * 33];
    int t = threadIdx.x;
    int wv = t >> 6, lane = t & 63;
    int q = lane >> 4, ln16 = lane & 15;
    size_t m0 = (size_t)blockIdx.x * 128 + wv * 32;

    f32x4 acc[2][2];
    #pragma unroll
    for (int mi = 0; mi < 2; mi++)
        #pragma unroll
        for (int ni = 0; ni < 2; ni++) acc[mi][ni] = (f32x4){0.f, 0.f, 0.f, 0.f};

    #pragma unroll
    for (int ks = 0; ks < 8; ks++) {
        const u16* src = (ks < 4) ? hbf : hlbf;
        int ko = (ks & 3) * 32 + q * 8;
        bf16x8 af[2], bfrg[2];
        #pragma unroll
        for (int mi = 0; mi < 2; mi++)
            af[mi] = *(const bf16x8*)&src[(m0 + mi * 16 + ln16) * CC + ko];
        #pragma unroll
        for (int ni = 0; ni < 2; ni++)
            bfrg[ni] = *(const bf16x8*)&Wcomb[(size_t)(ni * 16 + ln16) * 256 + ks * 32 + q * 8];
        #pragma unroll
        for (int mi = 0; mi < 2; mi++)
            #pragma unroll
            for (int ni = 0; ni < 2; ni++)
                acc[mi][ni] = __builtin_amdgcn_mfma_f32_16x16x32_bf16(af[mi], bfrg[ni], acc[mi][ni], 0, 0, 0);
    }

    #pragma unroll
    for (int mi = 0; mi < 2; mi++)
        #pragma unroll
        for (int ni = 0; ni < 2; ni++)
            #pragma unroll
            for (int r = 0; r < 4; r++)
                lg[(wv * 32 + mi * 16 + q * 4 + r) * 33 + ni * 16 + ln16] = acc[mi][ni][r];
    __syncthreads();

    int grp = t >> 5, s = t & 31;
    float bc = bcomb[s];
    for (int nl = grp; nl < 128; nl += 8) {
        size_t node = (size_t)blockIdx.x * 128 + nl;
        float lgt = lg[nl * 33 + s] + bc;
        float m = lgt;
        #pragma unroll
        for (int off = 16; off > 0; off >>= 1) m = fmaxf(m, __shfl_xor(m, off, 32));
        float e = expf(lgt - m);
        float sum = e;
        #pragma unroll
        for (int off = 16; off > 0; off >>= 1) sum += __shfl_xor(sum, off, 32);
        if (node < NTOT) wout[node * SS + s] = e / sum;
    }
}

// ---------------- slice pooling ----------------
__global__ __launch_bounds__(256) void slices_acc_kernel(const float* w, const float* h,
                                                         float* slices_acc, float* wsum) {
    int b = blockIdx.y, t = threadIdx.x;
    int n0 = blockIdx.x * SL_NODES;
    __shared__ float wsh[32];
    __shared__ float hsh[128];
    int c = t & 127, sg = t >> 7;
    float acc[16];
    #pragma unroll
    for (int k = 0; k < 16; k++) acc[k] = 0.0f;
    float wsum_loc = 0.0f;
    for (int i = 0; i < SL_NODES; i++) {
        int n = n0 + i;
        __syncthreads();
        if (n < NN) {
            if (t < 32) wsh[t] = w[((size_t)b * NN + n) * SS + t];
            else if (t >= 64 && t < 192) hsh[t - 64] = h[((size_t)b * NN + n) * CC + (t - 64)];
        } else {
            if (t < 32) wsh[t] = 0.0f;
            else if (t >= 64 && t < 192) hsh[t - 64] = 0.0f;
        }
        __syncthreads();
        float hv = hsh[c];
        #pragma unroll
        for (int k = 0; k < 16; k++) acc[k] += wsh[sg * 16 + k] * hv;
        if (t < 32) wsum_loc += wsh[t];
    }
    #pragma unroll
    for (int k = 0; k < 16; k++)
        atomicAdd(&slices_acc[(size_t)b * SS * CC + (sg * 16 + k) * CC + c], acc[k]);
    if (t < 32) atomicAdd(&wsum[b * SS + t], wsum_loc);
}

// ---------------- slice MHA, stage 1: qkv = (slices/wsum) @ Win + b_in ----------------
__global__ __launch_bounds__(128) void qkv_kernel(const float* slices_acc, const float* wsum,
                                                  const float* Win, const float* b_in_p,
                                                  float* qkv) {
    int blk = blockIdx.x;  // b*SS + s
    int t = threadIdx.x;
    __shared__ float row[128];
    float iv = 1.0f / fmaxf(wsum[blk], 1e-8f);
    row[t] = slices_acc[(size_t)blk * CC + t] * iv;
    __syncthreads();
    #pragma unroll
    for (int jj = 0; jj < 3; jj++) {
        int j = t + jj * 128;
        float a = b_in_p[j];
        #pragma unroll 8
        for (int c = 0; c < 128; c++) a += row[c] * Win[c * 384 + j];
        qkv[(size_t)blk * 384 + j] = a;
    }
}

// ---------------- slice MHA, stage 2: attention per (b,h) ----------------
__global__ __launch_bounds__(64) void attn_kernel(const float* qkv, float* ovals) {
    int blk = blockIdx.x;  // b*NH + h
    int b = blk >> 3, h = blk & 7;
    int t = threadIdx.x;
    __shared__ float ksh[32 * 16], vsh[32 * 16];
    for (int i = t; i < 512; i += 64) {
        int k = i >> 4, d = i & 15;
        ksh[i] = qkv[((size_t)b * 32 + k) * 384 + 128 + h * 16 + d];
        vsh[i] = qkv[((size_t)b * 32 + k) * 384 + 256 + h * 16 + d];
    }
    __syncthreads();
    if (t < 32) {
        float qr[16];
        #pragma unroll
        for (int d = 0; d < 16; d++) qr[d] = qkv[((size_t)b * 32 + t) * 384 + h * 16 + d];
        float sc[32];
        float m = -1e30f;
        for (int k = 0; k < 32; k++) {
            float a = 0.0f;
            #pragma unroll
            for (int d = 0; d < 16; d++) a += qr[d] * ksh[k * 16 + d];
            a *= 0.25f;  // 1/sqrt(16)
            sc[k] = a;
            m = fmaxf(m, a);
        }
        float ssum = 0.0f;
        for (int k = 0; k < 32; k++) { float e = expf(sc[k] - m); sc[k] = e; ssum += e; }
        float is = 1.0f / ssum;
        float o[16];
        #pragma unroll
        for (int d = 0; d < 16; d++) o[d] = 0.0f;
        for (int k = 0; k < 32; k++) {
            float p = sc[k] * is;
            #pragma unroll
            for (int d = 0; d < 16; d++) o[d] += p * vsh[k * 16 + d];
        }
        #pragma unroll
        for (int d = 0; d < 16; d++) ovals[((size_t)b * 32 + t) * 128 + h * 16 + d] = o[d];
    }
}

// ---------------- slice MHA, stage 3: slices_out = o @ Wout + bout ----------------
__global__ __launch_bounds__(128) void mha_out_kernel(const float* ovals, const float* Wout,
                                                      const float* bout, float* slices_out) {
    int blk = blockIdx.x;  // b*SS + s
    int t = threadIdx.x;
    __shared__ float row[128];
    row[t] = ovals[(size_t)blk * 128 + t];
    __syncthreads();
    float a = bout[t];
    #pragma unroll 8
    for (int cc = 0; cc < 128; cc++) a += row[cc] * Wout[cc * CC + t];
    slices_out[(size_t)blk * 128 + t] = a;
}

// ---------------- broadcast back: x += w @ slices_out ----------------
__global__ __launch_bounds__(256) void broadcast_kernel(const float* w, const float* slices_out,
                                                        float* x) {
    int b = blockIdx.y, t = threadIdx.x;
    int n0 = blockIdx.x * BC_NODES;
    __shared__ float so[32 * 128];
    __shared__ float wt[BC_NODES * 32];
    for (int idx = t; idx < 32 * 128; idx += 256) so[idx] = slices_out[(size_t)b * SS * CC + idx];
    for (int idx = t; idx < BC_NODES * 32; idx += 256) {
        int n = n0 + (idx >> 5);
        wt[idx] = (n < NN) ? w[((size_t)b * NN + n) * SS + (idx & 31)] : 0.0f;
    }
    __syncthreads();
    #pragma unroll
    for (int k = 0; k < 16; k++) {
        int idx = t + k * 256;
        int ln = idx >> 7, c = idx & 127;
        int n = n0 + ln;
        if (n < NN) {
            float a = 0.0f;
            const float* wr = &wt[ln * 32];
            #pragma unroll 8
            for (int s = 0; s < 32; s++) a += wr[s] * so[s * 128 + c];
            x[((size_t)b * NN + n) * CC + c] += a;
        }
    }
}

// ---------------- pack FFN weights to bf16 fragment-friendly layouts ----------------
__global__ __launch_bounds__(256) void pack_ffn_weights(const float* Wff1, const float* Wff2,
                                                        u16* W1p, u16* W2p) {
    int idx = blockIdx.x * 256 + threadIdx.x;
    if (idx >= NL * FFN * CC) return;
    int l = idx / (FFN * CC);
    int r = idx - l * (FFN * CC);
    int j = r >> 7, c = r & 127;          // W1p flat index [l][j][c]
    W1p[idx] = f2bf(Wff1[(size_t)l * CC * FFN + (size_t)c * FFN + j]);
    int c2 = r >> 9, j2 = r & 511;        // W2p flat index [l][c2][j2]
    W2p[idx] = f2bf(Wff2[(size_t)l * FFN * CC + (size_t)j2 * CC + c2]);
}

// ---------------- fused FFN via MFMA: x += gelu(h2@Wff1+b1)@Wff2 + b2 ----------------
__global__ __launch_bounds__(256, 2) void ffn_mfma(const u16* __restrict__ h2bf,
                                                   const u16* __restrict__ W1p,
                                                   const float* __restrict__ bff1,
                                                   const u16* __restrict__ W2p,
                                                   const float* __restrict__ bff2,
                                                   float* __restrict__ x) {
    __shared__ u16 lds_h[128 * 136];  // hidden chunk, bf16, +8 pad
    int t = threadIdx.x;
    int wave = t >> 6, lane = t & 63;
    int wm = wave >> 1, wn = wave & 1;
    int q = lane >> 4, ln16 = lane & 15;
    size_t m_blk = (size_t)blockIdx.x * FF_MT;

    f32x4 acc2[4][4];
    #pragma unroll
    for (int mi = 0; mi < 4; mi++)
        #pragma unroll
        for (int ni = 0; ni < 4; ni++) acc2[mi][ni] = (f32x4){0.f, 0.f, 0.f, 0.f};

    float b2[4];
    #pragma unroll
    for (int ni = 0; ni < 4; ni++) b2[ni] = bff2[wn * 64 + ni * 16 + ln16];

    for (int jc = 0; jc < 4; jc++) {
        f32x4 acc1[4][4];
        #pragma unroll
        for (int mi = 0; mi < 4; mi++)
            #pragma unroll
            for (int ni = 0; ni < 4; ni++) acc1[mi][ni] = (f32x4){0.f, 0.f, 0.f, 0.f};

        #pragma unroll
        for (int ks = 0; ks < 4; ks++) {
            bf16x8 af[4], bfr[4];
            #pragma unroll
            for (int mi = 0; mi < 4; mi++)
                af[mi] = *(const bf16x8*)&h2bf[(m_blk + wm * 64 + mi * 16 + ln16) * CC + ks * 32 + q * 8];
            #pragma unroll
            for (int ni = 0; ni < 4; ni++)
                bfr[ni] = *(const bf16x8*)&W1p[(size_t)(jc * 128 + wn * 64 + ni * 16 + ln16) * CC + ks * 32 + q * 8];
            #pragma unroll
            for (int mi = 0; mi < 4; mi++)
                #pragma unroll
                for (int ni = 0; ni < 4; ni++)
                    acc1[mi][ni] = __builtin_amdgcn_mfma_f32_16x16x32_bf16(af[mi], bfr[ni], acc1[mi][ni], 0, 0, 0);
        }

        #pragma unroll
        for (int ni = 0; ni < 4; ni++) {
            float b1 = bff1[jc * 128 + wn * 64 + ni * 16 + ln16];
            #pragma unroll
            for (int mi = 0; mi < 4; mi++)
                #pragma unroll
                for (int r = 0; r < 4; r++) {
                    float a = acc1[mi][ni][r] + b1;
                    float gv = 0.5f * a * (1.0f + erff(a * 0.7071067811865475f));
                    lds_h[(wm * 64 + mi * 16 + q * 4 + r) * 136 + wn * 64 + ni * 16 + ln16] = f2bf(gv);
                }
        }
        __syncthreads();

        #pragma unroll
        for (int ks2 = 0; ks2 < 4; ks2++) {
            bf16x8 af[4], bfr[4];
            #pragma unroll
            for (int mi = 0; mi < 4; mi++)
                af[mi] = *(const bf16x8*)&lds_h[(wm * 64 + mi * 16 + ln16) * 136 + ks2 * 32 + q * 8];
            #pragma unroll
            for (int ni = 0; ni < 4; ni++)
                bfr[ni] = *(const bf16x8*)&W2p[(size_t)(wn * 64 + ni * 16 + ln16) * FFN + jc * 128 + ks2 * 32 + q * 8];
            #pragma unroll
            for (int mi = 0; mi < 4; mi++)
                #pragma unroll
                for (int ni = 0; ni < 4; ni++)
                    acc2[mi][ni] = __builtin_amdgcn_mfma_f32_16x16x32_bf16(af[mi], bfr[ni], acc2[mi][ni], 0, 0, 0);
        }
        __syncthreads();
    }

    #pragma unroll
    for (int mi = 0; mi < 4; mi++)
        #pragma unroll
        for (int r = 0; r < 4; r++) {
            size_t node = m_blk + wm * 64 + mi * 16 + q * 4 + r;
            if (node < NTOT) {
                #pragma unroll
                for (int ni = 0; ni < 4; ni++) {
                    size_t off = node * CC + wn * 64 + ni * 16 + ln16;
                    x[off] += acc2[mi][ni][r] + b2[ni];
                }
            }
        }
}

// ---------------- final projection ----------------
__global__ __launch_bounds__(128) void proj_kernel(const float* x, const float* W,
                                                   const float* bias, float* outp) {
    int node = blockIdx.x;
    int t = threadIdx.x;
    __shared__ float xr[128];
    __shared__ float pr[40];
    xr[t] = x[(size_t)node * CC + t];
    __syncthreads();
    if (t < 40) {
        int k = t / 8, part = t % 8;
        float a = 0.0f;
        #pragma unroll
        for (int i = 0; i < 16; i++) {
            int c = part * 16 + i;
            a += xr[c] * W[c * C_IN + k];
        }
        pr[t] = a;
    }
    __syncthreads();
    if (t < 5) {
        float a = bias[t];
        #pragma unroll
        for (int p = 0; p < 8; p++) a += pr[t * 8 + p];
        outp[(size_t)node * C_IN + t] = a;
    }
}

extern "C" void kernel_launch(void* const* d_in, const int* in_sizes, int n_in,
                              void* d_out, int out_size, void* d_ws, size_t ws_size,
                              hipStream_t stream) {
    const float* inputs  = (const float*)d_in[0];
    const float* coords  = (const float*)d_in[1];
    const float* t_norm  = (const float*)d_in[2];
    const int*   adj     = (const int*)d_in[3];
    const float* adj_v   = (const float*)d_in[4];
    const float* freq    = (const float*)d_in[5];
    const float* embed_W = (const float*)d_in[6];
    const float* embed_b = (const float*)d_in[7];
    const float* ln1_g   = (const float*)d_in[8];
    const float* ln1_b   = (const float*)d_in[9];
    const float* Wslice  = (const float*)d_in[10];
    const float* bslice  = (const float*)d_in[11];
    const float* Wfront  = (const float*)d_in[12];
    const float* bfront  = (const float*)d_in[13];
    const float* Win     = (const float*)d_in[14];
    const float* b_in    = (const float*)d_in[15];
    const float* Wout    = (const float*)d_in[16];
    const float* bout    = (const float*)d_in[17];
    const float* ln2_g   = (const float*)d_in[18];
    const float* ln2_b   = (const float*)d_in[19];
    const float* Wff1    = (const float*)d_in[20];
    const float* bff1    = (const float*)d_in[21];
    const float* Wff2    = (const float*)d_in[22];
    const float* bff2    = (const float*)d_in[23];
    const float* proj_W  = (const float*)d_in[24];
    const float* proj_b  = (const float*)d_in[25];

    float* out = (float*)d_out;
    float* wout_base = out + (size_t)BATCH * NN * C_IN;

    // workspace layout
    float* x          = (float*)d_ws;
    float* h          = x + (size_t)NTOT * CC;
    u16*   hbf        = (u16*)(h + (size_t)NTOT * CC);
    u16*   hlbf       = hbf + (size_t)MPAD * CC;
    float* slices_acc = (float*)(hlbf + (size_t)MPAD * CC);
    float* wsum       = slices_acc + BATCH * SS * CC;
    float* slices_out = wsum + BATCH * SS;
    float* qkv_ws     = slices_out + BATCH * SS * CC;
    float* ovals_ws   = qkv_ws + BATCH * SS * 384;
    float* csr_val    = ovals_ws + BATCH * SS * CC;
    int*   rowptr     = (int*)(csr_val + NE);
    int*   cursor     = rowptr + (NN + 1);
    int*   deg        = cursor + NN;
    int*   csr_col    = deg + NN;
    u16*   W1p        = (u16*)(csr_col + NE);       // NL*FFN*CC bf16
    u16*   W2p        = W1p + NL * FFN * CC;        // NL*CC*FFN bf16
    u16*   Wcombp     = W2p + NL * CC * FFN;        // NL*SS*256 bf16
    float* bcomb      = (float*)(Wcombp + NL * SS * 256);  // NL*SS fp32
    u16*   h2bf       = (u16*)h;                    // reuse h (dead after slices_acc)

    // ---- CSR build ----
    hipMemsetAsync(deg, 0, NN * sizeof(int), stream);
    count_deg<<<(NE + 255) / 256, 256, 0, stream>>>(adj, deg);
    scan_deg<<<1, 512, 0, stream>>>(deg, rowptr);
    hipMemcpyAsync(cursor, rowptr, NN * sizeof(int), hipMemcpyDeviceToDevice, stream);
    fill_csr<<<(NE + 255) / 256, 256, 0, stream>>>(adj, adj + NE, adj_v, cursor, csr_col, csr_val);

    // ---- pack weights (bf16) ----
    pack_ffn_weights<<<(NL * FFN * CC + 255) / 256, 256, 0, stream>>>(Wff1, Wff2, W1p, W2p);
    pack_logits_weights<<<(NL * SS * 256 + 255) / 256, 256, 0, stream>>>(Wslice, bslice, Wfront,
                                                                         bfront, Wcombp, bcomb);

    // ---- embed ----
    embed_kernel<<<NTOT, 128, 0, stream>>>(inputs, coords, t_norm, freq, embed_W, embed_b, x);

    for (int l = 0; l < NL; l++) {
        float* wl = wout_base + (size_t)l * NTOT * SS;
        ln_kernel<<<NTOT, 128, 0, stream>>>(x, ln1_g + l * CC, ln1_b + l * CC, h, hbf);
        agg_kernel<<<NTOT, 128, 0, stream>>>(h, rowptr, csr_col, csr_val, hlbf);
        logits_mfma<<<FF_BLOCKS, 256, 0, stream>>>(hbf, hlbf, Wcombp + (size_t)l * SS * 256,
                                                   bcomb + l * SS, wl);
        hipMemsetAsync(slices_acc, 0, (BATCH * SS * CC + BATCH * SS) * sizeof(float), stream);
        dim3 g1((NN + SL_NODES - 1) / SL_NODES, BATCH);
        slices_acc_kernel<<<g1, 256, 0, stream>>>(wl, h, slices_acc, wsum);
        // MHA (parallel 3-stage)
        qkv_kernel<<<BATCH * SS, 128, 0, stream>>>(slices_acc, wsum,
                                                   Win + (size_t)l * CC * 3 * CC,
                                                   b_in + l * 3 * CC, qkv_ws);
        attn_kernel<<<BATCH * NH, 64, 0, stream>>>(qkv_ws, ovals_ws);
        mha_out_kernel<<<BATCH * SS, 128, 0, stream>>>(ovals_ws, Wout + (size_t)l * CC * CC,
                                                       bout + l * CC, slices_out);
        dim3 g2((NN + BC_NODES - 1) / BC_NODES, BATCH);
        broadcast_kernel<<<g2, 256, 0, stream>>>(wl, slices_out, x);
        // h is dead from here; reuse as bf16 h2 buffer
        ln_bf16_kernel<<<MPAD, 128, 0, stream>>>(x, ln2_g + l * CC, ln2_b + l * CC, h2bf);
        ffn_mfma<<<FF_BLOCKS, 256, 0, stream>>>(h2bf, W1p + (size_t)l * FFN * CC,
                                                bff1 + l * FFN, W2p + (size_t)l * CC * FFN,
                                                bff2 + l * CC, x);
    }

    proj_kernel<<<NTOT, 128, 0, stream>>>(x, proj_W, proj_b, out);
}

// Round 5
// 2479.622 us; speedup vs baseline: 3.1494x; 1.0899x over previous
//
#include <hip/hip_runtime.h>
#include <math.h>

#define BATCH 2
#define NN 50000
#define NE 400000
#define C_IN 5
#define CC 128
#define SS 32
#define NH 8
#define NL 4
#define FFN 512
#define COORD_F 8
#define TIME_F 4
#define HD 16
#define BETA 1.0f
#define TWO_PI 6.283185307179586476925287f

#define SL_NODES 256
#define BC_NODES 32
#define NTOT (BATCH * NN)
#define FF_MT 128
#define FF_BLOCKS ((NTOT + FF_MT - 1) / FF_MT)   // 782
#define MPAD (FF_BLOCKS * FF_MT)                  // 100096

typedef unsigned short u16;
typedef unsigned int u32;
typedef __attribute__((ext_vector_type(8))) __bf16 bf16x8;
typedef __attribute__((ext_vector_type(4))) float f32x4;
typedef __attribute__((ext_vector_type(4))) u32 u32x4;

__device__ __forceinline__ u16 f2bf(float f) {
    union { float f; u32 u; } v; v.f = f;
    u32 u = v.u;
    u32 r = (u + 0x7fffu + ((u >> 16) & 1u)) >> 16;
    return (u16)r;
}

__device__ __forceinline__ float bf2f(u16 h) {
    union { u32 u; float f; } v; v.u = ((u32)h) << 16;
    return v.f;
}

// exact-enough gelu: erf via Abramowitz-Stegun 7.1.26 (max abs err 1.5e-7)
__device__ __forceinline__ float gelu_f(float a) {
    float xx = a * 0.7071067811865475f;
    float ax = fabsf(xx);
    float t = 1.0f / fmaf(0.3275911f, ax, 1.0f);
    float poly = t * fmaf(t, fmaf(t, fmaf(t, fmaf(t, 1.061405429f, -1.453152027f),
                                          1.421413741f), -0.284496736f), 0.254829592f);
    float e = __expf(-ax * ax);
    float erfv = copysignf(fmaf(-poly, e, 1.0f), xx);
    return 0.5f * a * (1.0f + erfv);
}

// ---------------- CSR build ----------------
__global__ void count_deg(const int* rows, int* deg) {
    int e = blockIdx.x * blockDim.x + threadIdx.x;
    if (e < NE) atomicAdd(&deg[rows[e]], 1);
}

__global__ __launch_bounds__(512) void scan_deg(const int* deg, int* rowptr) {
    __shared__ int part[512];
    int t = threadIdx.x;
    const int CH = (NN + 511) / 512;  // 98
    int begin = t * CH, end = min(begin + CH, NN);
    int s = 0;
    for (int i = begin; i < end; i++) s += deg[i];
    part[t] = s;
    __syncthreads();
    for (int off = 1; off < 512; off <<= 1) {
        int v = (t >= off) ? part[t - off] : 0;
        __syncthreads();
        part[t] += v;
        __syncthreads();
    }
    int base = (t == 0) ? 0 : part[t - 1];
    for (int i = begin; i < end; i++) { rowptr[i] = base; base += deg[i]; }
    if (t == 511) rowptr[NN] = part[511];
}

__global__ void fill_csr(const int* rows, const int* cols, const float* vals,
                         int* cursor, int* csr_col, float* csr_val) {
    int e = blockIdx.x * blockDim.x + threadIdx.x;
    if (e < NE) {
        int p = atomicAdd(&cursor[rows[e]], 1);
        csr_col[p] = cols[e];
        csr_val[p] = vals[e];
    }
}

// ---------------- embed ----------------
__global__ __launch_bounds__(128) void embed_kernel(const float* inputs, const float* coords,
                                                    const float* t_norm, const float* freq,
                                                    const float* W, const float* bias, float* x) {
    int node = blockIdx.x;  // 0..BATCH*NN
    int b = node / NN;
    int t = threadIdx.x;
    __shared__ float feat[32];
    if (t < 8) {
        float c0 = coords[node * 2 + 0], c1 = coords[node * 2 + 1];
        float p = TWO_PI * (c0 * freq[t] + c1 * freq[8 + t]);
        feat[5 + t] = sinf(p);
        feat[13 + t] = cosf(p);
    } else if (t < 12) {
        int j = t - 8;
        float omega = powf(1000.0f, -(float)j * 0.25f);
        float ang = omega * t_norm[b] * 1000.0f;
        feat[21 + j] = sinf(ang);
        feat[25 + j] = cosf(ang);
    } else if (t >= 16 && t < 21) {
        feat[t - 16] = inputs[node * 5 + (t - 16)];
    }
    __syncthreads();
    float acc = bias[t];
    #pragma unroll
    for (int k = 0; k < 29; k++) acc += feat[k] * W[k * CC + t];
    x[(size_t)node * CC + t] = acc;
}

// ---------------- layernorm 1 (bf16 out only, shuffle reduce) ----------------
__global__ __launch_bounds__(128) void ln1_kernel(const float* xin, const float* g,
                                                  const float* bb, u16* outbf) {
    int node = blockIdx.x;
    int t = threadIdx.x;
    __shared__ float sm[4];
    float v = xin[(size_t)node * CC + t];
    float s = v;
    #pragma unroll
    for (int off = 32; off > 0; off >>= 1) s += __shfl_xor(s, off, 64);
    if ((t & 63) == 0) sm[t >> 6] = s;
    __syncthreads();
    float mean = (sm[0] + sm[1]) * (1.0f / 128.0f);
    float d = v - mean;
    float ss = d * d;
    #pragma unroll
    for (int off = 32; off > 0; off >>= 1) ss += __shfl_xor(ss, off, 64);
    if ((t & 63) == 0) sm[2 + (t >> 6)] = ss;
    __syncthreads();
    float var = (sm[2] + sm[3]) * (1.0f / 128.0f);
    outbf[(size_t)node * CC + t] = f2bf(d * rsqrtf(var + 1e-5f) * g[t] + bb[t]);
}

// ---------------- sparse aggregation (gather via CSR, bf16 in/out) ----------------
__global__ __launch_bounds__(128) void agg_kernel(const u16* hbf, const int* rowptr,
                                                  const int* csr_col, const float* csr_val,
                                                  u16* hlbf) {
    int blk = blockIdx.x;         // 0..BATCH*NN
    int b = blk / NN, r = blk % NN;
    int t = threadIdx.x;
    int s0 = rowptr[r], s1 = rowptr[r + 1];
    const u16* hb = hbf + (size_t)b * NN * CC;
    float acc = 0.0f;
    for (int e = s0; e < s1; e++) acc += csr_val[e] * bf2f(hb[(size_t)csr_col[e] * CC + t]);
    hlbf[(size_t)blk * CC + t] = f2bf(acc);
}

// ---------------- pack combined logits weights ----------------
// Wcombp[l][s][k] (32x256, k contiguous): k<128 -> Ws[k][s]+B*Wf[k][s]; else -B*Wf[k-128][s]
__global__ __launch_bounds__(256) void pack_logits_weights(const float* Ws, const float* bs,
                                                           const float* Wf, const float* bf,
                                                           u16* Wcombp, float* bcombp) {
    int idx = blockIdx.x * 256 + threadIdx.x;
    if (idx >= NL * SS * 256) return;
    int l = idx / (SS * 256);
    int r = idx - l * (SS * 256);
    int s = r >> 8, k = r & 255;
    float v;
    if (k < 128)
        v = Ws[(size_t)l * CC * SS + (size_t)k * SS + s] + BETA * Wf[(size_t)l * CC * SS + (size_t)k * SS + s];
    else
        v = -BETA * Wf[(size_t)l * CC * SS + (size_t)(k - 128) * SS + s];
    Wcombp[idx] = f2bf(v);
    if (k == 0) bcombp[l * SS + s] = bs[l * SS + s] + BETA * bf[l * SS + s];
}

// ---------------- logits + softmax via MFMA: w = softmax([h|hl] @ Wcomb^T + bcomb) ----------------
__global__ __launch_bounds__(256, 2) void logits_mfma(const u16* __restrict__ hbf,
                                                      const u16* __restrict__ hlbf,
                                                      const u16* __restrict__ Wcomb,
                                                      const float* __restrict__ bcomb,
                                                      float* __restrict__ wout) {
    __shared__ float lg[128 * 33];
    int t = threadIdx.x;
    int wv = t >> 6, lane = t & 63;
    int q = lane >> 4, ln16 = lane & 15;
    size_t m0 = (size_t)blockIdx.x * 128 + wv * 32;

    f32x4 acc[2][2];
    #pragma unroll
    for (int mi = 0; mi < 2; mi++)
        #pragma unroll
        for (int ni = 0; ni < 2; ni++) acc[mi][ni] = (f32x4){0.f, 0.f, 0.f, 0.f};

    #pragma unroll
    for (int ks = 0; ks < 8; ks++) {
        const u16* src = (ks < 4) ? hbf : hlbf;
        int ko = (ks & 3) * 32 + q * 8;
        bf16x8 af[2], bfrg[2];
        #pragma unroll
        for (int mi = 0; mi < 2; mi++)
            af[mi] = *(const bf16x8*)&src[(m0 + mi * 16 + ln16) * CC + ko];
        #pragma unroll
        for (int ni = 0; ni < 2; ni++)
            bfrg[ni] = *(const bf16x8*)&Wcomb[(size_t)(ni * 16 + ln16) * 256 + ks * 32 + q * 8];
        #pragma unroll
        for (int mi = 0; mi < 2; mi++)
            #pragma unroll
            for (int ni = 0; ni < 2; ni++)
                acc[mi][ni] = __builtin_amdgcn_mfma_f32_16x16x32_bf16(af[mi], bfrg[ni], acc[mi][ni], 0, 0, 0);
    }

    #pragma unroll
    for (int mi = 0; mi < 2; mi++)
        #pragma unroll
        for (int ni = 0; ni < 2; ni++)
            #pragma unroll
            for (int r = 0; r < 4; r++)
                lg[(wv * 32 + mi * 16 + q * 4 + r) * 33 + ni * 16 + ln16] = acc[mi][ni][r];
    __syncthreads();

    int grp = t >> 5, s = t & 31;
    float bc = bcomb[s];
    for (int nl = grp; nl < 128; nl += 8) {
        size_t node = (size_t)blockIdx.x * 128 + nl;
        float lgt = lg[nl * 33 + s] + bc;
        float m = lgt;
        #pragma unroll
        for (int off = 16; off > 0; off >>= 1) m = fmaxf(m, __shfl_xor(m, off, 32));
        float e = expf(lgt - m);
        float sum = e;
        #pragma unroll
        for (int off = 16; off > 0; off >>= 1) sum += __shfl_xor(sum, off, 32);
        if (node < NTOT) wout[node * SS + s] = e / sum;
    }
}

// ---------------- slice pooling (bf16 h) ----------------
__global__ __launch_bounds__(256) void slices_acc_kernel(const float* w, const u16* hbf,
                                                         float* slices_acc, float* wsum) {
    int b = blockIdx.y, t = threadIdx.x;
    int n0 = blockIdx.x * SL_NODES;
    __shared__ float wsh[32];
    __shared__ float hsh[128];
    int c = t & 127, sg = t >> 7;
    float acc[16];
    #pragma unroll
    for (int k = 0; k < 16; k++) acc[k] = 0.0f;
    float wsum_loc = 0.0f;
    for (int i = 0; i < SL_NODES; i++) {
        int n = n0 + i;
        __syncthreads();
        if (n < NN) {
            if (t < 32) wsh[t] = w[((size_t)b * NN + n) * SS + t];
            else if (t >= 64 && t < 192) hsh[t - 64] = bf2f(hbf[((size_t)b * NN + n) * CC + (t - 64)]);
        } else {
            if (t < 32) wsh[t] = 0.0f;
            else if (t >= 64 && t < 192) hsh[t - 64] = 0.0f;
        }
        __syncthreads();
        float hv = hsh[c];
        #pragma unroll
        for (int k = 0; k < 16; k++) acc[k] += wsh[sg * 16 + k] * hv;
        if (t < 32) wsum_loc += wsh[t];
    }
    #pragma unroll
    for (int k = 0; k < 16; k++)
        atomicAdd(&slices_acc[(size_t)b * SS * CC + (sg * 16 + k) * CC + c], acc[k]);
    if (t < 32) atomicAdd(&wsum[b * SS + t], wsum_loc);
}

// ---------------- slice MHA, stage 1: qkv = (slices/wsum) @ Win + b_in ----------------
__global__ __launch_bounds__(128) void qkv_kernel(const float* slices_acc, const float* wsum,
                                                  const float* Win, const float* b_in_p,
                                                  float* qkv) {
    int blk = blockIdx.x;  // b*SS + s
    int t = threadIdx.x;
    __shared__ float row[128];
    float iv = 1.0f / fmaxf(wsum[blk], 1e-8f);
    row[t] = slices_acc[(size_t)blk * CC + t] * iv;
    __syncthreads();
    #pragma unroll
    for (int jj = 0; jj < 3; jj++) {
        int j = t + jj * 128;
        float a = b_in_p[j];
        #pragma unroll 8
        for (int c = 0; c < 128; c++) a += row[c] * Win[c * 384 + j];
        qkv[(size_t)blk * 384 + j] = a;
    }
}

// ---------------- slice MHA, stage 2: attention per (b,h) ----------------
__global__ __launch_bounds__(64) void attn_kernel(const float* qkv, float* ovals) {
    int blk = blockIdx.x;  // b*NH + h
    int b = blk >> 3, h = blk & 7;
    int t = threadIdx.x;
    __shared__ float ksh[32 * 16], vsh[32 * 16];
    for (int i = t; i < 512; i += 64) {
        int k = i >> 4, d = i & 15;
        ksh[i] = qkv[((size_t)b * 32 + k) * 384 + 128 + h * 16 + d];
        vsh[i] = qkv[((size_t)b * 32 + k) * 384 + 256 + h * 16 + d];
    }
    __syncthreads();
    if (t < 32) {
        float qr[16];
        #pragma unroll
        for (int d = 0; d < 16; d++) qr[d] = qkv[((size_t)b * 32 + t) * 384 + h * 16 + d];
        float sc[32];
        float m = -1e30f;
        for (int k = 0; k < 32; k++) {
            float a = 0.0f;
            #pragma unroll
            for (int d = 0; d < 16; d++) a += qr[d] * ksh[k * 16 + d];
            a *= 0.25f;  // 1/sqrt(16)
            sc[k] = a;
            m = fmaxf(m, a);
        }
        float ssum = 0.0f;
        for (int k = 0; k < 32; k++) { float e = expf(sc[k] - m); sc[k] = e; ssum += e; }
        float is = 1.0f / ssum;
        float o[16];
        #pragma unroll
        for (int d = 0; d < 16; d++) o[d] = 0.0f;
        for (int k = 0; k < 32; k++) {
            float p = sc[k] * is;
            #pragma unroll
            for (int d = 0; d < 16; d++) o[d] += p * vsh[k * 16 + d];
        }
        #pragma unroll
        for (int d = 0; d < 16; d++) ovals[((size_t)b * 32 + t) * 128 + h * 16 + d] = o[d];
    }
}

// ---------------- slice MHA, stage 3: slices_out = o @ Wout + bout ----------------
__global__ __launch_bounds__(128) void mha_out_kernel(const float* ovals, const float* Wout,
                                                      const float* bout, float* slices_out) {
    int blk = blockIdx.x;  // b*SS + s
    int t = threadIdx.x;
    __shared__ float row[128];
    row[t] = ovals[(size_t)blk * 128 + t];
    __syncthreads();
    float a = bout[t];
    #pragma unroll 8
    for (int cc = 0; cc < 128; cc++) a += row[cc] * Wout[cc * CC + t];
    slices_out[(size_t)blk * 128 + t] = a;
}

// ---------------- broadcast + LN2 fused: x += w @ slices_out; h2bf = bf16(LN2(x)) ----------------
__global__ __launch_bounds__(256) void broadcast_ln2(const float* w, const float* slices_out,
                                                     const float* g, const float* bb,
                                                     float* x, u16* h2bf) {
    int b = blockIdx.y, t = threadIdx.x;
    int n0 = blockIdx.x * BC_NODES;
    __shared__ float so[32 * 128];
    __shared__ float wt[BC_NODES * 32];
    __shared__ float xs[BC_NODES * 132];  // +4 pad to break bank alias in phase B
    __shared__ float gs[128], bsv[128];
    for (int idx = t; idx < 32 * 128; idx += 256) so[idx] = slices_out[(size_t)b * SS * CC + idx];
    for (int idx = t; idx < BC_NODES * 32; idx += 256) {
        int n = n0 + (idx >> 5);
        wt[idx] = (n < NN) ? w[((size_t)b * NN + n) * SS + (idx & 31)] : 0.0f;
    }
    if (t < 128) { gs[t] = g[t]; bsv[t] = bb[t]; }
    __syncthreads();
    #pragma unroll
    for (int k = 0; k < 16; k++) {
        int idx = t + k * 256;
        int ln = idx >> 7, c = idx & 127;
        int n = n0 + ln;
        float a = 0.0f;
        const float* wr = &wt[ln * 32];
        #pragma unroll 8
        for (int s = 0; s < 32; s++) a += wr[s] * so[s * 128 + c];
        float xv = 0.0f;
        if (n < NN) {
            size_t off = ((size_t)b * NN + n) * CC + c;
            xv = x[off] + a;
            x[off] = xv;
        }
        xs[ln * 132 + c] = xv;
    }
    __syncthreads();
    // LN per node: 8 threads/node, 16 cols each, shuffle-reduce within the 8-lane group
    int node = t >> 3, lgi = t & 7;
    const float* xr = &xs[node * 132 + lgi * 16];
    float vals[16];
    float s = 0.0f;
    #pragma unroll
    for (int i = 0; i < 16; i++) { vals[i] = xr[i]; s += vals[i]; }
    #pragma unroll
    for (int off = 1; off < 8; off <<= 1) s += __shfl_xor(s, off, 64);
    float mean = s * (1.0f / 128.0f);
    float ss = 0.0f;
    #pragma unroll
    for (int i = 0; i < 16; i++) { float d = vals[i] - mean; ss += d * d; }
    #pragma unroll
    for (int off = 1; off < 8; off <<= 1) ss += __shfl_xor(ss, off, 64);
    float rstd = rsqrtf(ss * (1.0f / 128.0f) + 1e-5f);
    int n = n0 + node;
    if (n < NN) {
        size_t base = ((size_t)b * NN + n) * CC + lgi * 16;  // u16 index, 32B aligned
        u32 outw[8];
        #pragma unroll
        for (int i = 0; i < 8; i++) {
            int c0 = lgi * 16 + 2 * i;
            u16 lo = f2bf((vals[2 * i] - mean) * rstd * gs[c0] + bsv[c0]);
            u16 hi = f2bf((vals[2 * i + 1] - mean) * rstd * gs[c0 + 1] + bsv[c0 + 1]);
            outw[i] = (u32)lo | ((u32)hi << 16);
        }
        *((u32x4*)&h2bf[base]) = (u32x4){outw[0], outw[1], outw[2], outw[3]};
        *((u32x4*)&h2bf[base + 8]) = (u32x4){outw[4], outw[5], outw[6], outw[7]};
    }
}

// ---------------- pack FFN weights to bf16 fragment-friendly layouts ----------------
__global__ __launch_bounds__(256) void pack_ffn_weights(const float* Wff1, const float* Wff2,
                                                        u16* W1p, u16* W2p) {
    int idx = blockIdx.x * 256 + threadIdx.x;
    if (idx >= NL * FFN * CC) return;
    int l = idx / (FFN * CC);
    int r = idx - l * (FFN * CC);
    int j = r >> 7, c = r & 127;          // W1p flat index [l][j][c]
    W1p[idx] = f2bf(Wff1[(size_t)l * CC * FFN + (size_t)c * FFN + j]);
    int c2 = r >> 9, j2 = r & 511;        // W2p flat index [l][c2][j2]
    W2p[idx] = f2bf(Wff2[(size_t)l * FFN * CC + (size_t)j2 * CC + c2]);
}

// ---------------- fused FFN via MFMA: x += gelu(h2@Wff1+b1)@Wff2 + b2 ----------------
__global__ __launch_bounds__(256, 2) void ffn_mfma(const u16* __restrict__ h2bf,
                                                   const u16* __restrict__ W1p,
                                                   const float* __restrict__ bff1,
                                                   const u16* __restrict__ W2p,
                                                   const float* __restrict__ bff2,
                                                   float* __restrict__ x) {
    __shared__ u16 lds_h[128 * 136];  // hidden chunk, bf16, +8 pad
    int t = threadIdx.x;
    int wave = t >> 6, lane = t & 63;
    int wm = wave >> 1, wn = wave & 1;
    int q = lane >> 4, ln16 = lane & 15;
    size_t m_blk = (size_t)blockIdx.x * FF_MT;

    f32x4 acc2[4][4];
    #pragma unroll
    for (int mi = 0; mi < 4; mi++)
        #pragma unroll
        for (int ni = 0; ni < 4; ni++) acc2[mi][ni] = (f32x4){0.f, 0.f, 0.f, 0.f};

    float b2[4];
    #pragma unroll
    for (int ni = 0; ni < 4; ni++) b2[ni] = bff2[wn * 64 + ni * 16 + ln16];

    for (int jc = 0; jc < 4; jc++) {
        f32x4 acc1[4][4];
        #pragma unroll
        for (int mi = 0; mi < 4; mi++)
            #pragma unroll
            for (int ni = 0; ni < 4; ni++) acc1[mi][ni] = (f32x4){0.f, 0.f, 0.f, 0.f};

        #pragma unroll
        for (int ks = 0; ks < 4; ks++) {
            bf16x8 af[4], bfr[4];
            #pragma unroll
            for (int mi = 0; mi < 4; mi++)
                af[mi] = *(const bf16x8*)&h2bf[(m_blk + wm * 64 + mi * 16 + ln16) * CC + ks * 32 + q * 8];
            #pragma unroll
            for (int ni = 0; ni < 4; ni++)
                bfr[ni] = *(const bf16x8*)&W1p[(size_t)(jc * 128 + wn * 64 + ni * 16 + ln16) * CC + ks * 32 + q * 8];
            #pragma unroll
            for (int mi = 0; mi < 4; mi++)
                #pragma unroll
                for (int ni = 0; ni < 4; ni++)
                    acc1[mi][ni] = __builtin_amdgcn_mfma_f32_16x16x32_bf16(af[mi], bfr[ni], acc1[mi][ni], 0, 0, 0);
        }

        #pragma unroll
        for (int ni = 0; ni < 4; ni++) {
            float b1 = bff1[jc * 128 + wn * 64 + ni * 16 + ln16];
            #pragma unroll
            for (int mi = 0; mi < 4; mi++)
                #pragma unroll
                for (int r = 0; r < 4; r++) {
                    float a = acc1[mi][ni][r] + b1;
                    lds_h[(wm * 64 + mi * 16 + q * 4 + r) * 136 + wn * 64 + ni * 16 + ln16] = f2bf(gelu_f(a));
                }
        }
        __syncthreads();

        #pragma unroll
        for (int ks2 = 0; ks2 < 4; ks2++) {
            bf16x8 af[4], bfr[4];
            #pragma unroll
            for (int mi = 0; mi < 4; mi++)
                af[mi] = *(const bf16x8*)&lds_h[(wm * 64 + mi * 16 + ln16) * 136 + ks2 * 32 + q * 8];
            #pragma unroll
            for (int ni = 0; ni < 4; ni++)
                bfr[ni] = *(const bf16x8*)&W2p[(size_t)(wn * 64 + ni * 16 + ln16) * FFN + jc * 128 + ks2 * 32 + q * 8];
            #pragma unroll
            for (int mi = 0; mi < 4; mi++)
                #pragma unroll
                for (int ni = 0; ni < 4; ni++)
                    acc2[mi][ni] = __builtin_amdgcn_mfma_f32_16x16x32_bf16(af[mi], bfr[ni], acc2[mi][ni], 0, 0, 0);
        }
        __syncthreads();
    }

    #pragma unroll
    for (int mi = 0; mi < 4; mi++)
        #pragma unroll
        for (int r = 0; r < 4; r++) {
            size_t node = m_blk + wm * 64 + mi * 16 + q * 4 + r;
            if (node < NTOT) {
                #pragma unroll
                for (int ni = 0; ni < 4; ni++) {
                    size_t off = node * CC + wn * 64 + ni * 16 + ln16;
                    x[off] += acc2[mi][ni][r] + b2[ni];
                }
            }
        }
}

// ---------------- final projection ----------------
__global__ __launch_bounds__(128) void proj_kernel(const float* x, const float* W,
                                                   const float* bias, float* outp) {
    int node = blockIdx.x;
    int t = threadIdx.x;
    __shared__ float xr[128];
    __shared__ float pr[40];
    xr[t] = x[(size_t)node * CC + t];
    __syncthreads();
    if (t < 40) {
        int k = t / 8, part = t % 8;
        float a = 0.0f;
        #pragma unroll
        for (int i = 0; i < 16; i++) {
            int c = part * 16 + i;
            a += xr[c] * W[c * C_IN + k];
        }
        pr[t] = a;
    }
    __syncthreads();
    if (t < 5) {
        float a = bias[t];
        #pragma unroll
        for (int p = 0; p < 8; p++) a += pr[t * 8 + p];
        outp[(size_t)node * C_IN + t] = a;
    }
}

extern "C" void kernel_launch(void* const* d_in, const int* in_sizes, int n_in,
                              void* d_out, int out_size, void* d_ws, size_t ws_size,
                              hipStream_t stream) {
    const float* inputs  = (const float*)d_in[0];
    const float* coords  = (const float*)d_in[1];
    const float* t_norm  = (const float*)d_in[2];
    const int*   adj     = (const int*)d_in[3];
    const float* adj_v   = (const float*)d_in[4];
    const float* freq    = (const float*)d_in[5];
    const float* embed_W = (const float*)d_in[6];
    const float* embed_b = (const float*)d_in[7];
    const float* ln1_g   = (const float*)d_in[8];
    const float* ln1_b   = (const float*)d_in[9];
    const float* Wslice  = (const float*)d_in[10];
    const float* bslice  = (const float*)d_in[11];
    const float* Wfront  = (const float*)d_in[12];
    const float* bfront  = (const float*)d_in[13];
    const float* Win     = (const float*)d_in[14];
    const float* b_in    = (const float*)d_in[15];
    const float* Wout    = (const float*)d_in[16];
    const float* bout    = (const float*)d_in[17];
    const float* ln2_g   = (const float*)d_in[18];
    const float* ln2_b   = (const float*)d_in[19];
    const float* Wff1    = (const float*)d_in[20];
    const float* bff1    = (const float*)d_in[21];
    const float* Wff2    = (const float*)d_in[22];
    const float* bff2    = (const float*)d_in[23];
    const float* proj_W  = (const float*)d_in[24];
    const float* proj_b  = (const float*)d_in[25];

    float* out = (float*)d_out;
    float* wout_base = out + (size_t)BATCH * NN * C_IN;

    // workspace layout
    float* x          = (float*)d_ws;
    u16*   hbf        = (u16*)(x + (size_t)NTOT * CC);
    u16*   hlbf       = hbf + (size_t)MPAD * CC;
    u16*   h2bf       = hlbf + (size_t)MPAD * CC;
    float* slices_acc = (float*)(h2bf + (size_t)MPAD * CC);
    float* wsum       = slices_acc + BATCH * SS * CC;
    float* slices_out = wsum + BATCH * SS;
    float* qkv_ws     = slices_out + BATCH * SS * CC;
    float* ovals_ws   = qkv_ws + BATCH * SS * 384;
    float* csr_val    = ovals_ws + BATCH * SS * CC;
    int*   rowptr     = (int*)(csr_val + NE);
    int*   cursor     = rowptr + (NN + 1);
    int*   deg        = cursor + NN;
    int*   csr_col    = deg + NN;
    u16*   W1p        = (u16*)(csr_col + NE);       // NL*FFN*CC bf16
    u16*   W2p        = W1p + NL * FFN * CC;        // NL*CC*FFN bf16
    u16*   Wcombp     = W2p + NL * CC * FFN;        // NL*SS*256 bf16
    float* bcomb      = (float*)(Wcombp + NL * SS * 256);  // NL*SS fp32

    // ---- CSR build ----
    hipMemsetAsync(deg, 0, NN * sizeof(int), stream);
    count_deg<<<(NE + 255) / 256, 256, 0, stream>>>(adj, deg);
    scan_deg<<<1, 512, 0, stream>>>(deg, rowptr);
    hipMemcpyAsync(cursor, rowptr, NN * sizeof(int), hipMemcpyDeviceToDevice, stream);
    fill_csr<<<(NE + 255) / 256, 256, 0, stream>>>(adj, adj + NE, adj_v, cursor, csr_col, csr_val);

    // ---- pack weights (bf16) ----
    pack_ffn_weights<<<(NL * FFN * CC + 255) / 256, 256, 0, stream>>>(Wff1, Wff2, W1p, W2p);
    pack_logits_weights<<<(NL * SS * 256 + 255) / 256, 256, 0, stream>>>(Wslice, bslice, Wfront,
                                                                         bfront, Wcombp, bcomb);

    // ---- embed ----
    embed_kernel<<<NTOT, 128, 0, stream>>>(inputs, coords, t_norm, freq, embed_W, embed_b, x);

    for (int l = 0; l < NL; l++) {
        float* wl = wout_base + (size_t)l * NTOT * SS;
        ln1_kernel<<<NTOT, 128, 0, stream>>>(x, ln1_g + l * CC, ln1_b + l * CC, hbf);
        agg_kernel<<<NTOT, 128, 0, stream>>>(hbf, rowptr, csr_col, csr_val, hlbf);
        logits_mfma<<<FF_BLOCKS, 256, 0, stream>>>(hbf, hlbf, Wcombp + (size_t)l * SS * 256,
                                                   bcomb + l * SS, wl);
        hipMemsetAsync(slices_acc, 0, (BATCH * SS * CC + BATCH * SS) * sizeof(float), stream);
        dim3 g1((NN + SL_NODES - 1) / SL_NODES, BATCH);
        slices_acc_kernel<<<g1, 256, 0, stream>>>(wl, hbf, slices_acc, wsum);
        // MHA (parallel 3-stage)
        qkv_kernel<<<BATCH * SS, 128, 0, stream>>>(slices_acc, wsum,
                                                   Win + (size_t)l * CC * 3 * CC,
                                                   b_in + l * 3 * CC, qkv_ws);
        attn_kernel<<<BATCH * NH, 64, 0, stream>>>(qkv_ws, ovals_ws);
        mha_out_kernel<<<BATCH * SS, 128, 0, stream>>>(ovals_ws, Wout + (size_t)l * CC * CC,
                                                       bout + l * CC, slices_out);
        // broadcast + LN2 fused (also emits bf16 h2 for FFN)
        dim3 g2((NN + BC_NODES - 1) / BC_NODES, BATCH);
        broadcast_ln2<<<g2, 256, 0, stream>>>(wl, slices_out, ln2_g + l * CC, ln2_b + l * CC,
                                              x, h2bf);
        ffn_mfma<<<FF_BLOCKS, 256, 0, stream>>>(h2bf, W1p + (size_t)l * FFN * CC,
                                                bff1 + l * FFN, W2p + (size_t)l * CC * FFN,
                                                bff2 + l * CC, x);
    }

    proj_kernel<<<NTOT, 128, 0, stream>>>(x, proj_W, proj_b, out);
}

// Round 6
// 2134.868 us; speedup vs baseline: 3.6579x; 1.1615x over previous
//
#include <hip/hip_runtime.h>
#include <math.h>

#define BATCH 2
#define NN 50000
#define NE 400000
#define C_IN 5
#define CC 128
#define SS 32
#define NH 8
#define NL 4
#define FFN 512
#define COORD_F 8
#define TIME_F 4
#define HD 16
#define BETA 1.0f
#define TWO_PI 6.283185307179586476925287f

#define SL_NODES 256
#define NTOT (BATCH * NN)
#define FF_MT 128
#define FF_BLOCKS ((NTOT + FF_MT - 1) / FF_MT)   // 782 (for logits grid)
#define MPAD (FF_BLOCKS * FF_MT)                  // 100096
#define NBLK ((NN + 127) / 128)                   // 391 per-batch blocks for ffn_mega

typedef unsigned short u16;
typedef unsigned int u32;
typedef __attribute__((ext_vector_type(8))) __bf16 bf16x8;
typedef __attribute__((ext_vector_type(4))) float f32x4;

__device__ __forceinline__ u16 f2bf(float f) {
    union { float f; u32 u; } v; v.f = f;
    u32 u = v.u;
    u32 r = (u + 0x7fffu + ((u >> 16) & 1u)) >> 16;
    return (u16)r;
}

__device__ __forceinline__ float bf2f(u16 h) {
    union { u32 u; float f; } v; v.u = ((u32)h) << 16;
    return v.f;
}

// erf via Abramowitz-Stegun 7.1.26 (max abs err 1.5e-7)
__device__ __forceinline__ float gelu_f(float a) {
    float xx = a * 0.7071067811865475f;
    float ax = fabsf(xx);
    float t = 1.0f / fmaf(0.3275911f, ax, 1.0f);
    float poly = t * fmaf(t, fmaf(t, fmaf(t, fmaf(t, 1.061405429f, -1.453152027f),
                                          1.421413741f), -0.284496736f), 0.254829592f);
    float e = __expf(-ax * ax);
    float erfv = copysignf(fmaf(-poly, e, 1.0f), xx);
    return 0.5f * a * (1.0f + erfv);
}

// ---------------- CSR build ----------------
__global__ void count_deg(const int* rows, int* deg) {
    int e = blockIdx.x * blockDim.x + threadIdx.x;
    if (e < NE) atomicAdd(&deg[rows[e]], 1);
}

__global__ __launch_bounds__(512) void scan_deg(const int* deg, int* rowptr) {
    __shared__ int part[512];
    int t = threadIdx.x;
    const int CH = (NN + 511) / 512;  // 98
    int begin = t * CH, end = min(begin + CH, NN);
    int s = 0;
    for (int i = begin; i < end; i++) s += deg[i];
    part[t] = s;
    __syncthreads();
    for (int off = 1; off < 512; off <<= 1) {
        int v = (t >= off) ? part[t - off] : 0;
        __syncthreads();
        part[t] += v;
        __syncthreads();
    }
    int base = (t == 0) ? 0 : part[t - 1];
    for (int i = begin; i < end; i++) { rowptr[i] = base; base += deg[i]; }
    if (t == 511) rowptr[NN] = part[511];
}

__global__ void fill_csr(const int* rows, const int* cols, const float* vals,
                         int* cursor, int* csr_col, float* csr_val) {
    int e = blockIdx.x * blockDim.x + threadIdx.x;
    if (e < NE) {
        int p = atomicAdd(&cursor[rows[e]], 1);
        csr_col[p] = cols[e];
        csr_val[p] = vals[e];
    }
}

// ---------------- embed ----------------
__global__ __launch_bounds__(128) void embed_kernel(const float* inputs, const float* coords,
                                                    const float* t_norm, const float* freq,
                                                    const float* W, const float* bias, float* x) {
    int node = blockIdx.x;  // 0..BATCH*NN
    int b = node / NN;
    int t = threadIdx.x;
    __shared__ float feat[32];
    if (t < 8) {
        float c0 = coords[node * 2 + 0], c1 = coords[node * 2 + 1];
        float p = TWO_PI * (c0 * freq[t] + c1 * freq[8 + t]);
        feat[5 + t] = sinf(p);
        feat[13 + t] = cosf(p);
    } else if (t < 12) {
        int j = t - 8;
        float omega = powf(1000.0f, -(float)j * 0.25f);
        float ang = omega * t_norm[b] * 1000.0f;
        feat[21 + j] = sinf(ang);
        feat[25 + j] = cosf(ang);
    } else if (t >= 16 && t < 21) {
        feat[t - 16] = inputs[node * 5 + (t - 16)];
    }
    __syncthreads();
    float acc = bias[t];
    #pragma unroll
    for (int k = 0; k < 29; k++) acc += feat[k] * W[k * CC + t];
    x[(size_t)node * CC + t] = acc;
}

// ---------------- layernorm 1 (bf16 out, shuffle reduce) ----------------
__global__ __launch_bounds__(128) void ln1_kernel(const float* xin, const float* g,
                                                  const float* bb, u16* outbf) {
    int node = blockIdx.x;
    int t = threadIdx.x;
    __shared__ float sm[4];
    float v = xin[(size_t)node * CC + t];
    float s = v;
    #pragma unroll
    for (int off = 32; off > 0; off >>= 1) s += __shfl_xor(s, off, 64);
    if ((t & 63) == 0) sm[t >> 6] = s;
    __syncthreads();
    float mean = (sm[0] + sm[1]) * (1.0f / 128.0f);
    float d = v - mean;
    float ss = d * d;
    #pragma unroll
    for (int off = 32; off > 0; off >>= 1) ss += __shfl_xor(ss, off, 64);
    if ((t & 63) == 0) sm[2 + (t >> 6)] = ss;
    __syncthreads();
    float var = (sm[2] + sm[3]) * (1.0f / 128.0f);
    outbf[(size_t)node * CC + t] = f2bf(d * rsqrtf(var + 1e-5f) * g[t] + bb[t]);
}

// ---------------- sparse aggregation (gather via CSR, bf16 in/out) ----------------
__global__ __launch_bounds__(128) void agg_kernel(const u16* hbf, const int* rowptr,
                                                  const int* csr_col, const float* csr_val,
                                                  u16* hlbf) {
    int blk = blockIdx.x;         // 0..BATCH*NN
    int b = blk / NN, r = blk % NN;
    int t = threadIdx.x;
    int s0 = rowptr[r], s1 = rowptr[r + 1];
    const u16* hb = hbf + (size_t)b * NN * CC;
    float acc = 0.0f;
    for (int e = s0; e < s1; e++) acc += csr_val[e] * bf2f(hb[(size_t)csr_col[e] * CC + t]);
    hlbf[(size_t)blk * CC + t] = f2bf(acc);
}

// ---------------- pack combined logits weights ----------------
__global__ __launch_bounds__(256) void pack_logits_weights(const float* Ws, const float* bs,
                                                           const float* Wf, const float* bf,
                                                           u16* Wcombp, float* bcombp) {
    int idx = blockIdx.x * 256 + threadIdx.x;
    if (idx >= NL * SS * 256) return;
    int l = idx / (SS * 256);
    int r = idx - l * (SS * 256);
    int s = r >> 8, k = r & 255;
    float v;
    if (k < 128)
        v = Ws[(size_t)l * CC * SS + (size_t)k * SS + s] + BETA * Wf[(size_t)l * CC * SS + (size_t)k * SS + s];
    else
        v = -BETA * Wf[(size_t)l * CC * SS + (size_t)(k - 128) * SS + s];
    Wcombp[idx] = f2bf(v);
    if (k == 0) bcombp[l * SS + s] = bs[l * SS + s] + BETA * bf[l * SS + s];
}

// ---------------- logits + softmax via MFMA (also emits w hi/lo bf16 pair) ----------------
__global__ __launch_bounds__(256, 2) void logits_mfma(const u16* __restrict__ hbf,
                                                      const u16* __restrict__ hlbf,
                                                      const u16* __restrict__ Wcomb,
                                                      const float* __restrict__ bcomb,
                                                      float* __restrict__ wout,
                                                      u16* __restrict__ whi,
                                                      u16* __restrict__ wlo) {
    __shared__ float lg[128 * 33];
    int t = threadIdx.x;
    int wv = t >> 6, lane = t & 63;
    int q = lane >> 4, ln16 = lane & 15;
    size_t m0 = (size_t)blockIdx.x * 128 + wv * 32;

    f32x4 acc[2][2];
    #pragma unroll
    for (int mi = 0; mi < 2; mi++)
        #pragma unroll
        for (int ni = 0; ni < 2; ni++) acc[mi][ni] = (f32x4){0.f, 0.f, 0.f, 0.f};

    #pragma unroll
    for (int ks = 0; ks < 8; ks++) {
        const u16* src = (ks < 4) ? hbf : hlbf;
        int ko = (ks & 3) * 32 + q * 8;
        bf16x8 af[2], bfrg[2];
        #pragma unroll
        for (int mi = 0; mi < 2; mi++)
            af[mi] = *(const bf16x8*)&src[(m0 + mi * 16 + ln16) * CC + ko];
        #pragma unroll
        for (int ni = 0; ni < 2; ni++)
            bfrg[ni] = *(const bf16x8*)&Wcomb[(size_t)(ni * 16 + ln16) * 256 + ks * 32 + q * 8];
        #pragma unroll
        for (int mi = 0; mi < 2; mi++)
            #pragma unroll
            for (int ni = 0; ni < 2; ni++)
                acc[mi][ni] = __builtin_amdgcn_mfma_f32_16x16x32_bf16(af[mi], bfrg[ni], acc[mi][ni], 0, 0, 0);
    }

    #pragma unroll
    for (int mi = 0; mi < 2; mi++)
        #pragma unroll
        for (int ni = 0; ni < 2; ni++)
            #pragma unroll
            for (int r = 0; r < 4; r++)
                lg[(wv * 32 + mi * 16 + q * 4 + r) * 33 + ni * 16 + ln16] = acc[mi][ni][r];
    __syncthreads();

    int grp = t >> 5, s = t & 31;
    float bc = bcomb[s];
    for (int nl = grp; nl < 128; nl += 8) {
        size_t node = (size_t)blockIdx.x * 128 + nl;
        float lgt = lg[nl * 33 + s] + bc;
        float m = lgt;
        #pragma unroll
        for (int off = 16; off > 0; off >>= 1) m = fmaxf(m, __shfl_xor(m, off, 32));
        float e = expf(lgt - m);
        float sum = e;
        #pragma unroll
        for (int off = 16; off > 0; off >>= 1) sum += __shfl_xor(sum, off, 32);
        if (node < NTOT) {
            float wv2 = e / sum;
            wout[node * SS + s] = wv2;
            u16 hi = f2bf(wv2);
            whi[node * SS + s] = hi;
            wlo[node * SS + s] = f2bf(wv2 - bf2f(hi));
        }
    }
}

// ---------------- slice pooling (bf16 h) ----------------
__global__ __launch_bounds__(256) void slices_acc_kernel(const float* w, const u16* hbf,
                                                         float* slices_acc, float* wsum) {
    int b = blockIdx.y, t = threadIdx.x;
    int n0 = blockIdx.x * SL_NODES;
    __shared__ float wsh[32];
    __shared__ float hsh[128];
    int c = t & 127, sg = t >> 7;
    float acc[16];
    #pragma unroll
    for (int k = 0; k < 16; k++) acc[k] = 0.0f;
    float wsum_loc = 0.0f;
    for (int i = 0; i < SL_NODES; i++) {
        int n = n0 + i;
        __syncthreads();
        if (n < NN) {
            if (t < 32) wsh[t] = w[((size_t)b * NN + n) * SS + t];
            else if (t >= 64 && t < 192) hsh[t - 64] = bf2f(hbf[((size_t)b * NN + n) * CC + (t - 64)]);
        } else {
            if (t < 32) wsh[t] = 0.0f;
            else if (t >= 64 && t < 192) hsh[t - 64] = 0.0f;
        }
        __syncthreads();
        float hv = hsh[c];
        #pragma unroll
        for (int k = 0; k < 16; k++) acc[k] += wsh[sg * 16 + k] * hv;
        if (t < 32) wsum_loc += wsh[t];
    }
    #pragma unroll
    for (int k = 0; k < 16; k++)
        atomicAdd(&slices_acc[(size_t)b * SS * CC + (sg * 16 + k) * CC + c], acc[k]);
    if (t < 32) atomicAdd(&wsum[b * SS + t], wsum_loc);
}

// ---------------- slice MHA, stage 1: qkv = (slices/wsum) @ Win + b_in ----------------
__global__ __launch_bounds__(128) void qkv_kernel(const float* slices_acc, const float* wsum,
                                                  const float* Win, const float* b_in_p,
                                                  float* qkv) {
    int blk = blockIdx.x;  // b*SS + s
    int t = threadIdx.x;
    __shared__ float row[128];
    float iv = 1.0f / fmaxf(wsum[blk], 1e-8f);
    row[t] = slices_acc[(size_t)blk * CC + t] * iv;
    __syncthreads();
    #pragma unroll
    for (int jj = 0; jj < 3; jj++) {
        int j = t + jj * 128;
        float a = b_in_p[j];
        #pragma unroll 8
        for (int c = 0; c < 128; c++) a += row[c] * Win[c * 384 + j];
        qkv[(size_t)blk * 384 + j] = a;
    }
}

// ---------------- slice MHA, stage 2: attention per (b,h) ----------------
__global__ __launch_bounds__(64) void attn_kernel(const float* qkv, float* ovals) {
    int blk = blockIdx.x;  // b*NH + h
    int b = blk >> 3, h = blk & 7;
    int t = threadIdx.x;
    __shared__ float ksh[32 * 16], vsh[32 * 16];
    for (int i = t; i < 512; i += 64) {
        int k = i >> 4, d = i & 15;
        ksh[i] = qkv[((size_t)b * 32 + k) * 384 + 128 + h * 16 + d];
        vsh[i] = qkv[((size_t)b * 32 + k) * 384 + 256 + h * 16 + d];
    }
    __syncthreads();
    if (t < 32) {
        float qr[16];
        #pragma unroll
        for (int d = 0; d < 16; d++) qr[d] = qkv[((size_t)b * 32 + t) * 384 + h * 16 + d];
        float sc[32];
        float m = -1e30f;
        for (int k = 0; k < 32; k++) {
            float a = 0.0f;
            #pragma unroll
            for (int d = 0; d < 16; d++) a += qr[d] * ksh[k * 16 + d];
            a *= 0.25f;  // 1/sqrt(16)
            sc[k] = a;
            m = fmaxf(m, a);
        }
        float ssum = 0.0f;
        for (int k = 0; k < 32; k++) { float e = expf(sc[k] - m); sc[k] = e; ssum += e; }
        float is = 1.0f / ssum;
        float o[16];
        #pragma unroll
        for (int d = 0; d < 16; d++) o[d] = 0.0f;
        for (int k = 0; k < 32; k++) {
            float p = sc[k] * is;
            #pragma unroll
            for (int d = 0; d < 16; d++) o[d] += p * vsh[k * 16 + d];
        }
        #pragma unroll
        for (int d = 0; d < 16; d++) ovals[((size_t)b * 32 + t) * 128 + h * 16 + d] = o[d];
    }
}

// ---------------- slice MHA, stage 3: soT hi/lo = (o @ Wout + bout)^T, split bf16 ----------------
__global__ __launch_bounds__(128) void mha_out_kernel(const float* ovals, const float* Wout,
                                                      const float* bout,
                                                      u16* soThi, u16* soTlo) {
    int blk = blockIdx.x;  // b*SS + s
    int b = blk >> 5, s = blk & 31;
    int t = threadIdx.x;   // = output col c
    __shared__ float row[128];
    row[t] = ovals[(size_t)blk * 128 + t];
    __syncthreads();
    float a = bout[t];
    #pragma unroll 8
    for (int cc = 0; cc < 128; cc++) a += row[cc] * Wout[cc * CC + t];
    u16 hi = f2bf(a);
    size_t idx = (size_t)b * CC * SS + (size_t)t * SS + s;
    soThi[idx] = hi;
    soTlo[idx] = f2bf(a - bf2f(hi));
}

// ---------------- pack FFN weights to bf16 fragment-friendly layouts ----------------
__global__ __launch_bounds__(256) void pack_ffn_weights(const float* Wff1, const float* Wff2,
                                                        u16* W1p, u16* W2p) {
    int idx = blockIdx.x * 256 + threadIdx.x;
    if (idx >= NL * FFN * CC) return;
    int l = idx / (FFN * CC);
    int r = idx - l * (FFN * CC);
    int j = r >> 7, c = r & 127;          // W1p flat index [l][j][c]
    W1p[idx] = f2bf(Wff1[(size_t)l * CC * FFN + (size_t)c * FFN + j]);
    int c2 = r >> 9, j2 = r & 511;        // W2p flat index [l][c2][j2]
    W2p[idx] = f2bf(Wff2[(size_t)l * FFN * CC + (size_t)j2 * CC + c2]);
}

// ---------------- mega kernel: x += w@so (split-bf16 MFMA, fp32-grade);
//                  LN2 in-register; FFN MFMA from LDS; x = xv + ffn out ----------------
// grid (NBLK, BATCH); block 256 = 4 waves (wm,wn in 2x2); 128 nodes/block.
__global__ __launch_bounds__(256, 2) void ffn_mega(float* __restrict__ x,
                                                   const u16* __restrict__ whi,
                                                   const u16* __restrict__ wlo,
                                                   const u16* __restrict__ soThi,
                                                   const u16* __restrict__ soTlo,
                                                   const float* __restrict__ g,
                                                   const float* __restrict__ bb,
                                                   const u16* __restrict__ W1p,
                                                   const float* __restrict__ bff1,
                                                   const u16* __restrict__ W2p,
                                                   const float* __restrict__ bff2) {
    __shared__ u16 h2t[128 * 136];     // LN2 output tile (bf16), lives whole kernel
    __shared__ u16 hid[128 * 72];      // hidden chunk (64 j), bf16, +8 pad
    __shared__ float rowst[128][4];    // per-row {sum,sumsq} x {wn}
    __shared__ float gs[128], bsv[128];
    int t = threadIdx.x;
    int b = blockIdx.y;
    int n0 = blockIdx.x * 128;         // local node base within batch
    int wave = t >> 6, lane = t & 63;
    int wm = wave >> 1, wn = wave & 1;
    int q = lane >> 4, ln16 = lane & 15;
    if (t < 128) { gs[t] = g[t]; bsv[t] = bb[t]; }

    f32x4 acc2[4][4];
    #pragma unroll
    for (int mi = 0; mi < 4; mi++)
        #pragma unroll
        for (int ni = 0; ni < 4; ni++) acc2[mi][ni] = (f32x4){0.f, 0.f, 0.f, 0.f};

    // ---- phase 0: acc2 = w@so via 3-pass hi/lo MFMA ----
    {
        const u16* soh = soThi + (size_t)b * CC * SS;
        const u16* sol = soTlo + (size_t)b * CC * SS;
        bf16x8 bh[4], bl[4], ah[4], al[4];
        bf16x8 zf;
        #pragma unroll
        for (int i = 0; i < 8; i++) zf[i] = (__bf16)0.0f;
        #pragma unroll
        for (int ni = 0; ni < 4; ni++) {
            int c = wn * 64 + ni * 16 + ln16;
            bh[ni] = *(const bf16x8*)&soh[c * SS + q * 8];
            bl[ni] = *(const bf16x8*)&sol[c * SS + q * 8];
        }
        #pragma unroll
        for (int mi = 0; mi < 4; mi++) {
            int row = n0 + wm * 64 + mi * 16 + ln16;
            if (row < NN) {
                size_t base = ((size_t)b * NN + row) * SS + q * 8;
                ah[mi] = *(const bf16x8*)&whi[base];
                al[mi] = *(const bf16x8*)&wlo[base];
            } else { ah[mi] = zf; al[mi] = zf; }
        }
        #pragma unroll
        for (int mi = 0; mi < 4; mi++)
            #pragma unroll
            for (int ni = 0; ni < 4; ni++) {
                acc2[mi][ni] = __builtin_amdgcn_mfma_f32_16x16x32_bf16(ah[mi], bh[ni], acc2[mi][ni], 0, 0, 0);
                acc2[mi][ni] = __builtin_amdgcn_mfma_f32_16x16x32_bf16(al[mi], bh[ni], acc2[mi][ni], 0, 0, 0);
                acc2[mi][ni] = __builtin_amdgcn_mfma_f32_16x16x32_bf16(ah[mi], bl[ni], acc2[mi][ni], 0, 0, 0);
            }
    }

    // ---- phase 1: acc2 += x (residual); LN2 stats; h2 -> LDS ----
    #pragma unroll
    for (int mi = 0; mi < 4; mi++)
        #pragma unroll
        for (int r = 0; r < 4; r++) {
            int row = n0 + wm * 64 + mi * 16 + q * 4 + r;
            if (row < NN) {
                const float* xr = &x[((size_t)b * NN + row) * CC + wn * 64 + ln16];
                #pragma unroll
                for (int ni = 0; ni < 4; ni++) acc2[mi][ni][r] += xr[ni * 16];
            }
        }
    #pragma unroll
    for (int mi = 0; mi < 4; mi++)
        #pragma unroll
        for (int r = 0; r < 4; r++) {
            float a = acc2[mi][0][r] + acc2[mi][1][r] + acc2[mi][2][r] + acc2[mi][3][r];
            float a2 = acc2[mi][0][r] * acc2[mi][0][r] + acc2[mi][1][r] * acc2[mi][1][r] +
                       acc2[mi][2][r] * acc2[mi][2][r] + acc2[mi][3][r] * acc2[mi][3][r];
            #pragma unroll
            for (int msk = 1; msk < 16; msk <<= 1) {
                a += __shfl_xor(a, msk, 64);
                a2 += __shfl_xor(a2, msk, 64);
            }
            if (ln16 == 0) {
                int m = wm * 64 + mi * 16 + q * 4 + r;
                rowst[m][wn * 2] = a;
                rowst[m][wn * 2 + 1] = a2;
            }
        }
    __syncthreads();
    #pragma unroll
    for (int mi = 0; mi < 4; mi++)
        #pragma unroll
        for (int r = 0; r < 4; r++) {
            int m = wm * 64 + mi * 16 + q * 4 + r;
            float s1 = rowst[m][0] + rowst[m][2];
            float s2 = rowst[m][1] + rowst[m][3];
            float mean = s1 * (1.0f / 128.0f);
            float var = s2 * (1.0f / 128.0f) - mean * mean;
            float rstd = rsqrtf(fmaxf(var, 0.0f) + 1e-5f);
            #pragma unroll
            for (int ni = 0; ni < 4; ni++) {
                int col = wn * 64 + ni * 16 + ln16;
                h2t[m * 136 + col] = f2bf((acc2[mi][ni][r] - mean) * rstd * gs[col] + bsv[col]);
            }
        }
    __syncthreads();

    // ---- phase 2: FFN; acc2 (holding xv) accumulates GEMM2 output ----
    for (int jc = 0; jc < 8; jc++) {
        f32x4 acc1[4][2];
        #pragma unroll
        for (int mi = 0; mi < 4; mi++)
            #pragma unroll
            for (int ni = 0; ni < 2; ni++) acc1[mi][ni] = (f32x4){0.f, 0.f, 0.f, 0.f};

        #pragma unroll
        for (int ks = 0; ks < 4; ks++) {
            bf16x8 af[4], bfr[2];
            #pragma unroll
            for (int mi = 0; mi < 4; mi++)
                af[mi] = *(const bf16x8*)&h2t[(wm * 64 + mi * 16 + ln16) * 136 + ks * 32 + q * 8];
            #pragma unroll
            for (int ni = 0; ni < 2; ni++)
                bfr[ni] = *(const bf16x8*)&W1p[(size_t)(jc * 64 + wn * 32 + ni * 16 + ln16) * CC + ks * 32 + q * 8];
            #pragma unroll
            for (int mi = 0; mi < 4; mi++)
                #pragma unroll
                for (int ni = 0; ni < 2; ni++)
                    acc1[mi][ni] = __builtin_amdgcn_mfma_f32_16x16x32_bf16(af[mi], bfr[ni], acc1[mi][ni], 0, 0, 0);
        }

        #pragma unroll
        for (int ni = 0; ni < 2; ni++) {
            float b1 = bff1[jc * 64 + wn * 32 + ni * 16 + ln16];
            #pragma unroll
            for (int mi = 0; mi < 4; mi++)
                #pragma unroll
                for (int r = 0; r < 4; r++)
                    hid[(wm * 64 + mi * 16 + q * 4 + r) * 72 + wn * 32 + ni * 16 + ln16] =
                        f2bf(gelu_f(acc1[mi][ni][r] + b1));
        }
        __syncthreads();

        #pragma unroll
        for (int ks2 = 0; ks2 < 2; ks2++) {
            bf16x8 af[4], bfr[4];
            #pragma unroll
            for (int mi = 0; mi < 4; mi++)
                af[mi] = *(const bf16x8*)&hid[(wm * 64 + mi * 16 + ln16) * 72 + ks2 * 32 + q * 8];
            #pragma unroll
            for (int ni = 0; ni < 4; ni++)
                bfr[ni] = *(const bf16x8*)&W2p[(size_t)(wn * 64 + ni * 16 + ln16) * FFN + jc * 64 + ks2 * 32 + q * 8];
            #pragma unroll
            for (int mi = 0; mi < 4; mi++)
                #pragma unroll
                for (int ni = 0; ni < 4; ni++)
                    acc2[mi][ni] = __builtin_amdgcn_mfma_f32_16x16x32_bf16(af[mi], bfr[ni], acc2[mi][ni], 0, 0, 0);
        }
        __syncthreads();
    }

    // ---- epilogue: x = acc2 + bff2 (plain store) ----
    float b2[4];
    #pragma unroll
    for (int ni = 0; ni < 4; ni++) b2[ni] = bff2[wn * 64 + ni * 16 + ln16];
    #pragma unroll
    for (int mi = 0; mi < 4; mi++)
        #pragma unroll
        for (int r = 0; r < 4; r++) {
            int row = n0 + wm * 64 + mi * 16 + q * 4 + r;
            if (row < NN) {
                float* xo = &x[((size_t)b * NN + row) * CC + wn * 64 + ln16];
                #pragma unroll
                for (int ni = 0; ni < 4; ni++) xo[ni * 16] = acc2[mi][ni][r] + b2[ni];
            }
        }
}

// ---------------- final projection ----------------
__global__ __launch_bounds__(128) void proj_kernel(const float* x, const float* W,
                                                   const float* bias, float* outp) {
    int node = blockIdx.x;
    int t = threadIdx.x;
    __shared__ float xr[128];
    __shared__ float pr[40];
    xr[t] = x[(size_t)node * CC + t];
    __syncthreads();
    if (t < 40) {
        int k = t / 8, part = t % 8;
        float a = 0.0f;
        #pragma unroll
        for (int i = 0; i < 16; i++) {
            int c = part * 16 + i;
            a += xr[c] * W[c * C_IN + k];
        }
        pr[t] = a;
    }
    __syncthreads();
    if (t < 5) {
        float a = bias[t];
        #pragma unroll
        for (int p = 0; p < 8; p++) a += pr[t * 8 + p];
        outp[(size_t)node * C_IN + t] = a;
    }
}

extern "C" void kernel_launch(void* const* d_in, const int* in_sizes, int n_in,
                              void* d_out, int out_size, void* d_ws, size_t ws_size,
                              hipStream_t stream) {
    const float* inputs  = (const float*)d_in[0];
    const float* coords  = (const float*)d_in[1];
    const float* t_norm  = (const float*)d_in[2];
    const int*   adj     = (const int*)d_in[3];
    const float* adj_v   = (const float*)d_in[4];
    const float* freq    = (const float*)d_in[5];
    const float* embed_W = (const float*)d_in[6];
    const float* embed_b = (const float*)d_in[7];
    const float* ln1_g   = (const float*)d_in[8];
    const float* ln1_b   = (const float*)d_in[9];
    const float* Wslice  = (const float*)d_in[10];
    const float* bslice  = (const float*)d_in[11];
    const float* Wfront  = (const float*)d_in[12];
    const float* bfront  = (const float*)d_in[13];
    const float* Win     = (const float*)d_in[14];
    const float* b_in    = (const float*)d_in[15];
    const float* Wout    = (const float*)d_in[16];
    const float* bout    = (const float*)d_in[17];
    const float* ln2_g   = (const float*)d_in[18];
    const float* ln2_b   = (const float*)d_in[19];
    const float* Wff1    = (const float*)d_in[20];
    const float* bff1    = (const float*)d_in[21];
    const float* Wff2    = (const float*)d_in[22];
    const float* bff2    = (const float*)d_in[23];
    const float* proj_W  = (const float*)d_in[24];
    const float* proj_b  = (const float*)d_in[25];

    float* out = (float*)d_out;
    float* wout_base = out + (size_t)BATCH * NN * C_IN;

    // workspace layout
    float* x          = (float*)d_ws;
    u16*   hbf        = (u16*)(x + (size_t)NTOT * CC);
    u16*   hlbf       = hbf + (size_t)MPAD * CC;
    u16*   whi        = hlbf + (size_t)MPAD * CC;            // (NTOT+128)*SS
    u16*   wlo        = whi + (size_t)(NTOT + 128) * SS;
    u16*   soThi      = wlo + (size_t)(NTOT + 128) * SS;     // BATCH*CC*SS
    u16*   soTlo      = soThi + BATCH * CC * SS;
    float* slices_acc = (float*)(soTlo + BATCH * CC * SS);
    float* wsum       = slices_acc + BATCH * SS * CC;
    float* qkv_ws     = wsum + BATCH * SS;
    float* ovals_ws   = qkv_ws + BATCH * SS * 384;
    float* csr_val    = ovals_ws + BATCH * SS * CC;
    int*   rowptr     = (int*)(csr_val + NE);
    int*   cursor     = rowptr + (NN + 1);
    int*   deg        = cursor + NN;
    int*   csr_col    = deg + NN;
    u16*   W1p        = (u16*)(csr_col + NE);       // NL*FFN*CC bf16
    u16*   W2p        = W1p + NL * FFN * CC;        // NL*CC*FFN bf16
    u16*   Wcombp     = W2p + NL * CC * FFN;        // NL*SS*256 bf16
    float* bcomb      = (float*)(Wcombp + NL * SS * 256);  // NL*SS fp32

    // ---- CSR build ----
    hipMemsetAsync(deg, 0, NN * sizeof(int), stream);
    count_deg<<<(NE + 255) / 256, 256, 0, stream>>>(adj, deg);
    scan_deg<<<1, 512, 0, stream>>>(deg, rowptr);
    hipMemcpyAsync(cursor, rowptr, NN * sizeof(int), hipMemcpyDeviceToDevice, stream);
    fill_csr<<<(NE + 255) / 256, 256, 0, stream>>>(adj, adj + NE, adj_v, cursor, csr_col, csr_val);

    // ---- pack weights (bf16) ----
    pack_ffn_weights<<<(NL * FFN * CC + 255) / 256, 256, 0, stream>>>(Wff1, Wff2, W1p, W2p);
    pack_logits_weights<<<(NL * SS * 256 + 255) / 256, 256, 0, stream>>>(Wslice, bslice, Wfront,
                                                                         bfront, Wcombp, bcomb);

    // ---- embed ----
    embed_kernel<<<NTOT, 128, 0, stream>>>(inputs, coords, t_norm, freq, embed_W, embed_b, x);

    for (int l = 0; l < NL; l++) {
        float* wl = wout_base + (size_t)l * NTOT * SS;
        ln1_kernel<<<NTOT, 128, 0, stream>>>(x, ln1_g + l * CC, ln1_b + l * CC, hbf);
        agg_kernel<<<NTOT, 128, 0, stream>>>(hbf, rowptr, csr_col, csr_val, hlbf);
        logits_mfma<<<FF_BLOCKS, 256, 0, stream>>>(hbf, hlbf, Wcombp + (size_t)l * SS * 256,
                                                   bcomb + l * SS, wl, whi, wlo);
        hipMemsetAsync(slices_acc, 0, (BATCH * SS * CC + BATCH * SS) * sizeof(float), stream);
        dim3 g1((NN + SL_NODES - 1) / SL_NODES, BATCH);
        slices_acc_kernel<<<g1, 256, 0, stream>>>(wl, hbf, slices_acc, wsum);
        // MHA (parallel 3-stage)
        qkv_kernel<<<BATCH * SS, 128, 0, stream>>>(slices_acc, wsum,
                                                   Win + (size_t)l * CC * 3 * CC,
                                                   b_in + l * 3 * CC, qkv_ws);
        attn_kernel<<<BATCH * NH, 64, 0, stream>>>(qkv_ws, ovals_ws);
        mha_out_kernel<<<BATCH * SS, 128, 0, stream>>>(ovals_ws, Wout + (size_t)l * CC * CC,
                                                       bout + l * CC, soThi, soTlo);
        // fused broadcast + LN2 + FFN
        dim3 g3(NBLK, BATCH);
        ffn_mega<<<g3, 256, 0, stream>>>(x, whi, wlo, soThi, soTlo,
                                         ln2_g + l * CC, ln2_b + l * CC,
                                         W1p + (size_t)l * FFN * CC, bff1 + l * FFN,
                                         W2p + (size_t)l * CC * FFN, bff2 + l * CC);
    }

    proj_kernel<<<NTOT, 128, 0, stream>>>(x, proj_W, proj_b, out);
}

// Round 7
// 1929.950 us; speedup vs baseline: 4.0463x; 1.1062x over previous
//
#include <hip/hip_runtime.h>
#include <math.h>

#define BATCH 2
#define NN 50000
#define NE 400000
#define C_IN 5
#define CC 128
#define SS 32
#define NH 8
#define NL 4
#define FFN 512
#define COORD_F 8
#define TIME_F 4
#define HD 16
#define BETA 1.0f
#define TWO_PI 6.283185307179586476925287f

#define NTOT (BATCH * NN)
#define FF_MT 128
#define FF_BLOCKS ((NTOT + FF_MT - 1) / FF_MT)   // 782 (buffer sizing)
#define MPAD (FF_BLOCKS * FF_MT)                  // 100096
#define NBLK ((NN + 127) / 128)                   // 391 per-batch blocks
#define LP_PAD 136                                // u16 row pad (272B, 16B-aligned)

typedef unsigned short u16;
typedef unsigned int u32;
typedef __attribute__((ext_vector_type(8))) __bf16 bf16x8;
typedef __attribute__((ext_vector_type(4))) float f32x4;

__device__ __forceinline__ u16 f2bf(float f) {
    union { float f; u32 u; } v; v.f = f;
    u32 u = v.u;
    u32 r = (u + 0x7fffu + ((u >> 16) & 1u)) >> 16;
    return (u16)r;
}

__device__ __forceinline__ float bf2f(u16 h) {
    union { u32 u; float f; } v; v.u = ((u32)h) << 16;
    return v.f;
}

// erf via Abramowitz-Stegun 7.1.26 (max abs err 1.5e-7)
__device__ __forceinline__ float gelu_f(float a) {
    float xx = a * 0.7071067811865475f;
    float ax = fabsf(xx);
    float t = 1.0f / fmaf(0.3275911f, ax, 1.0f);
    float poly = t * fmaf(t, fmaf(t, fmaf(t, fmaf(t, 1.061405429f, -1.453152027f),
                                          1.421413741f), -0.284496736f), 0.254829592f);
    float e = __expf(-ax * ax);
    float erfv = copysignf(fmaf(-poly, e, 1.0f), xx);
    return 0.5f * a * (1.0f + erfv);
}

// ---------------- CSR build ----------------
__global__ void count_deg(const int* rows, int* deg) {
    int e = blockIdx.x * blockDim.x + threadIdx.x;
    if (e < NE) atomicAdd(&deg[rows[e]], 1);
}

__global__ __launch_bounds__(512) void scan_deg(const int* deg, int* rowptr) {
    __shared__ int part[512];
    int t = threadIdx.x;
    const int CH = (NN + 511) / 512;  // 98
    int begin = t * CH, end = min(begin + CH, NN);
    int s = 0;
    for (int i = begin; i < end; i++) s += deg[i];
    part[t] = s;
    __syncthreads();
    for (int off = 1; off < 512; off <<= 1) {
        int v = (t >= off) ? part[t - off] : 0;
        __syncthreads();
        part[t] += v;
        __syncthreads();
    }
    int base = (t == 0) ? 0 : part[t - 1];
    for (int i = begin; i < end; i++) { rowptr[i] = base; base += deg[i]; }
    if (t == 511) rowptr[NN] = part[511];
}

__global__ void fill_csr(const int* rows, const int* cols, const float* vals,
                         int* cursor, int* csr_col, float* csr_val) {
    int e = blockIdx.x * blockDim.x + threadIdx.x;
    if (e < NE) {
        int p = atomicAdd(&cursor[rows[e]], 1);
        csr_col[p] = cols[e];
        csr_val[p] = vals[e];
    }
}

// ---------------- embed + LN1 fused ----------------
__global__ __launch_bounds__(128) void embed_ln1_kernel(const float* inputs, const float* coords,
                                                        const float* t_norm, const float* freq,
                                                        const float* W, const float* bias,
                                                        const float* g, const float* bb,
                                                        float* x, u16* hbf) {
    int node = blockIdx.x;  // 0..NTOT
    int b = node / NN;
    int t = threadIdx.x;
    __shared__ float feat[32];
    __shared__ float sm[4];
    if (t < 8) {
        float c0 = coords[node * 2 + 0], c1 = coords[node * 2 + 1];
        float p = TWO_PI * (c0 * freq[t] + c1 * freq[8 + t]);
        feat[5 + t] = sinf(p);
        feat[13 + t] = cosf(p);
    } else if (t < 12) {
        int j = t - 8;
        float omega = powf(1000.0f, -(float)j * 0.25f);
        float ang = omega * t_norm[b] * 1000.0f;
        feat[21 + j] = sinf(ang);
        feat[25 + j] = cosf(ang);
    } else if (t >= 16 && t < 21) {
        feat[t - 16] = inputs[node * 5 + (t - 16)];
    }
    __syncthreads();
    float acc = bias[t];
    #pragma unroll
    for (int k = 0; k < 29; k++) acc += feat[k] * W[k * CC + t];
    x[(size_t)node * CC + t] = acc;
    // LN1
    float s = acc;
    #pragma unroll
    for (int off = 32; off > 0; off >>= 1) s += __shfl_xor(s, off, 64);
    if ((t & 63) == 0) sm[t >> 6] = s;
    __syncthreads();
    float mean = (sm[0] + sm[1]) * (1.0f / 128.0f);
    float d = acc - mean;
    float ss = d * d;
    #pragma unroll
    for (int off = 32; off > 0; off >>= 1) ss += __shfl_xor(ss, off, 64);
    if ((t & 63) == 0) sm[2 + (t >> 6)] = ss;
    __syncthreads();
    float var = (sm[2] + sm[3]) * (1.0f / 128.0f);
    hbf[(size_t)node * CC + t] = f2bf(d * rsqrtf(var + 1e-5f) * g[t] + bb[t]);
}

// ---------------- sparse aggregation (gather via CSR, bf16 in/out) ----------------
__global__ __launch_bounds__(128) void agg_kernel(const u16* hbf, const int* rowptr,
                                                  const int* csr_col, const float* csr_val,
                                                  u16* hlbf) {
    int blk = blockIdx.x;         // 0..NTOT
    int b = blk / NN, r = blk % NN;
    int t = threadIdx.x;
    int s0 = rowptr[r], s1 = rowptr[r + 1];
    const u16* hb = hbf + (size_t)b * NN * CC;
    float acc = 0.0f;
    for (int e = s0; e < s1; e++) acc += csr_val[e] * bf2f(hb[(size_t)csr_col[e] * CC + t]);
    hlbf[(size_t)blk * CC + t] = f2bf(acc);
}

// ---------------- pack combined logits weights ----------------
__global__ __launch_bounds__(256) void pack_logits_weights(const float* Ws, const float* bs,
                                                           const float* Wf, const float* bf,
                                                           u16* Wcombp, float* bcombp) {
    int idx = blockIdx.x * 256 + threadIdx.x;
    if (idx >= NL * SS * 256) return;
    int l = idx / (SS * 256);
    int r = idx - l * (SS * 256);
    int s = r >> 8, k = r & 255;
    float v;
    if (k < 128)
        v = Ws[(size_t)l * CC * SS + (size_t)k * SS + s] + BETA * Wf[(size_t)l * CC * SS + (size_t)k * SS + s];
    else
        v = -BETA * Wf[(size_t)l * CC * SS + (size_t)(k - 128) * SS + s];
    Wcombp[idx] = f2bf(v);
    if (k == 0) bcombp[l * SS + s] = bs[l * SS + s] + BETA * bf[l * SS + s];
}

// ---------------- fused logits + softmax + slice pooling ----------------
// grid (NBLK, BATCH); 256 thr = 4 waves; 128 nodes/block; each wave owns 32 nodes.
// Logits D-layout: node = wv*32 + mi*16 + q*4 + r (local), s = ni*16 + ln16.
__global__ __launch_bounds__(256, 2) void logits_pool(const u16* __restrict__ hbf,
                                                      const u16* __restrict__ hlbf,
                                                      const u16* __restrict__ Wcomb,
                                                      const float* __restrict__ bcomb,
                                                      float* __restrict__ wout,
                                                      u16* __restrict__ whi,
                                                      u16* __restrict__ wlo,
                                                      float* __restrict__ slices_acc,
                                                      float* __restrict__ wsum) {
    __shared__ __align__(16) u16 hT[128 * LP_PAD];   // [c][n_local]; reused as fp32 reduce buf
    __shared__ __align__(16) u16 wTh[SS * LP_PAD];   // [s][n_local] hi
    __shared__ __align__(16) u16 wTl[SS * LP_PAD];   // lo
    __shared__ float wsum_sh[SS];
    int t = threadIdx.x;
    int b = blockIdx.y;
    int nl0 = blockIdx.x * 128;                      // local node base (within batch)
    int wv = t >> 6, lane = t & 63;
    int q = lane >> 4, ln16 = lane & 15;
    int nl0w = nl0 + wv * 32;                        // this wave's 32-node base
    if (t < SS) wsum_sh[t] = 0.0f;
    __syncthreads();

    // ---- logits GEMM + hT transpose ----
    f32x4 acc[2][2];
    #pragma unroll
    for (int mi = 0; mi < 2; mi++)
        #pragma unroll
        for (int ni = 0; ni < 2; ni++) acc[mi][ni] = (f32x4){0.f, 0.f, 0.f, 0.f};

    #pragma unroll
    for (int ks = 0; ks < 8; ks++) {
        const u16* src = (ks < 4) ? hbf : hlbf;
        int ko = (ks & 3) * 32 + q * 8;
        bf16x8 af[2], bfrg[2];
        #pragma unroll
        for (int mi = 0; mi < 2; mi++) {
            int nl = nl0w + mi * 16 + ln16;          // local node of this A row
            af[mi] = *(const bf16x8*)&src[((size_t)b * NN + nl) * CC + ko];
            if (ks < 4) {
                bool valid = nl < NN;
                const u16* ap = (const u16*)&af[mi];
                int nlb = nl - nl0;                  // 0..127 within block
                #pragma unroll
                for (int i = 0; i < 8; i++)
                    hT[(ko + i) * LP_PAD + nlb] = valid ? ap[i] : (u16)0;
            }
        }
        #pragma unroll
        for (int ni = 0; ni < 2; ni++)
            bfrg[ni] = *(const bf16x8*)&Wcomb[(size_t)(ni * 16 + ln16) * 256 + ks * 32 + q * 8];
        #pragma unroll
        for (int mi = 0; mi < 2; mi++)
            #pragma unroll
            for (int ni = 0; ni < 2; ni++)
                acc[mi][ni] = __builtin_amdgcn_mfma_f32_16x16x32_bf16(af[mi], bfrg[ni], acc[mi][ni], 0, 0, 0);
    }

    // ---- in-register softmax + w outputs + wT tiles + wsum ----
    float bc0 = bcomb[ln16], bc1 = bcomb[16 + ln16];
    float ws0 = 0.0f, ws1 = 0.0f;
    #pragma unroll
    for (int mi = 0; mi < 2; mi++)
        #pragma unroll
        for (int r = 0; r < 4; r++) {
            float l0 = acc[mi][0][r] + bc0;
            float l1 = acc[mi][1][r] + bc1;
            float m = fmaxf(l0, l1);
            #pragma unroll
            for (int msk = 1; msk < 16; msk <<= 1) m = fmaxf(m, __shfl_xor(m, msk, 64));
            float e0 = __expf(l0 - m), e1 = __expf(l1 - m);
            float sum = e0 + e1;
            #pragma unroll
            for (int msk = 1; msk < 16; msk <<= 1) sum += __shfl_xor(sum, msk, 64);
            float is = 1.0f / sum;
            int nl = nl0w + mi * 16 + q * 4 + r;     // local node (row)
            bool valid = nl < NN;
            float w0 = valid ? e0 * is : 0.0f;
            float w1 = valid ? e1 * is : 0.0f;
            u16 h0 = f2bf(w0), h1 = f2bf(w1);
            u16 lo0 = f2bf(w0 - bf2f(h0)), lo1 = f2bf(w1 - bf2f(h1));
            if (valid) {
                size_t gb = ((size_t)b * NN + nl) * SS;
                wout[gb + ln16] = w0;
                wout[gb + 16 + ln16] = w1;
                whi[gb + ln16] = h0;  wlo[gb + ln16] = lo0;
                whi[gb + 16 + ln16] = h1;  wlo[gb + 16 + ln16] = lo1;
            }
            int nlb = nl - nl0;
            wTh[ln16 * LP_PAD + nlb] = h0;  wTl[ln16 * LP_PAD + nlb] = lo0;
            wTh[(16 + ln16) * LP_PAD + nlb] = h1;  wTl[(16 + ln16) * LP_PAD + nlb] = lo1;
            ws0 += w0;  ws1 += w1;
        }
    // reduce wsum partials across q groups (lanes with same ln16)
    ws0 += __shfl_xor(ws0, 16, 64); ws0 += __shfl_xor(ws0, 32, 64);
    ws1 += __shfl_xor(ws1, 16, 64); ws1 += __shfl_xor(ws1, 32, 64);
    if (q == 0) {
        atomicAdd(&wsum_sh[ln16], ws0);
        atomicAdd(&wsum_sh[16 + ln16], ws1);
    }
    __syncthreads();

    // ---- pooling MFMA: D[s][c] += wT(32 x K32) @ h(K32 x 128), per-wave K-slice ----
    f32x4 pacc[2][8];
    #pragma unroll
    for (int st = 0; st < 2; st++)
        #pragma unroll
        for (int ct = 0; ct < 8; ct++) pacc[st][ct] = (f32x4){0.f, 0.f, 0.f, 0.f};
    {
        int kb = wv * 32 + q * 8;
        bf16x8 wh[2], wl2[2];
        #pragma unroll
        for (int st = 0; st < 2; st++) {
            wh[st] = *(const bf16x8*)&wTh[(st * 16 + ln16) * LP_PAD + kb];
            wl2[st] = *(const bf16x8*)&wTl[(st * 16 + ln16) * LP_PAD + kb];
        }
        #pragma unroll
        for (int ct = 0; ct < 8; ct++) {
            bf16x8 bfr = *(const bf16x8*)&hT[(ct * 16 + ln16) * LP_PAD + kb];
            #pragma unroll
            for (int st = 0; st < 2; st++) {
                pacc[st][ct] = __builtin_amdgcn_mfma_f32_16x16x32_bf16(wh[st], bfr, pacc[st][ct], 0, 0, 0);
                pacc[st][ct] = __builtin_amdgcn_mfma_f32_16x16x32_bf16(wl2[st], bfr, pacc[st][ct], 0, 0, 0);
            }
        }
    }
    __syncthreads();

    // ---- cross-wave reduce (reuse hT as fp32 [32][128]) then global atomics ----
    float* red = (float*)hT;
    for (int i = t; i < SS * CC; i += 256) red[i] = 0.0f;
    __syncthreads();
    #pragma unroll
    for (int st = 0; st < 2; st++)
        #pragma unroll
        for (int ct = 0; ct < 8; ct++)
            #pragma unroll
            for (int r = 0; r < 4; r++)
                atomicAdd(&red[(st * 16 + q * 4 + r) * CC + ct * 16 + ln16], pacc[st][ct][r]);
    __syncthreads();
    if (t < SS) atomicAdd(&wsum[b * SS + t], wsum_sh[t]);
    #pragma unroll
    for (int k = 0; k < 16; k++) {
        int idx = k * 256 + t;
        atomicAdd(&slices_acc[(size_t)b * SS * CC + idx], red[idx]);
    }
}

// ---------------- slice MHA, stage 1: qkv = (slices/wsum) @ Win + b_in ----------------
__global__ __launch_bounds__(128) void qkv_kernel(const float* slices_acc, const float* wsum,
                                                  const float* Win, const float* b_in_p,
                                                  float* qkv) {
    int blk = blockIdx.x;  // b*SS + s
    int t = threadIdx.x;
    __shared__ float row[128];
    float iv = 1.0f / fmaxf(wsum[blk], 1e-8f);
    row[t] = slices_acc[(size_t)blk * CC + t] * iv;
    __syncthreads();
    #pragma unroll
    for (int jj = 0; jj < 3; jj++) {
        int j = t + jj * 128;
        float a = b_in_p[j];
        #pragma unroll 8
        for (int c = 0; c < 128; c++) a += row[c] * Win[c * 384 + j];
        qkv[(size_t)blk * 384 + j] = a;
    }
}

// ---------------- slice MHA, stage 2: attention per (b,h) ----------------
__global__ __launch_bounds__(64) void attn_kernel(const float* qkv, float* ovals) {
    int blk = blockIdx.x;  // b*NH + h
    int b = blk >> 3, h = blk & 7;
    int t = threadIdx.x;
    __shared__ float ksh[32 * 16], vsh[32 * 16];
    for (int i = t; i < 512; i += 64) {
        int k = i >> 4, d = i & 15;
        ksh[i] = qkv[((size_t)b * 32 + k) * 384 + 128 + h * 16 + d];
        vsh[i] = qkv[((size_t)b * 32 + k) * 384 + 256 + h * 16 + d];
    }
    __syncthreads();
    if (t < 32) {
        float qr[16];
        #pragma unroll
        for (int d = 0; d < 16; d++) qr[d] = qkv[((size_t)b * 32 + t) * 384 + h * 16 + d];
        float sc[32];
        float m = -1e30f;
        for (int k = 0; k < 32; k++) {
            float a = 0.0f;
            #pragma unroll
            for (int d = 0; d < 16; d++) a += qr[d] * ksh[k * 16 + d];
            a *= 0.25f;  // 1/sqrt(16)
            sc[k] = a;
            m = fmaxf(m, a);
        }
        float ssum = 0.0f;
        for (int k = 0; k < 32; k++) { float e = expf(sc[k] - m); sc[k] = e; ssum += e; }
        float is = 1.0f / ssum;
        float o[16];
        #pragma unroll
        for (int d = 0; d < 16; d++) o[d] = 0.0f;
        for (int k = 0; k < 32; k++) {
            float p = sc[k] * is;
            #pragma unroll
            for (int d = 0; d < 16; d++) o[d] += p * vsh[k * 16 + d];
        }
        #pragma unroll
        for (int d = 0; d < 16; d++) ovals[((size_t)b * 32 + t) * 128 + h * 16 + d] = o[d];
    }
}

// ---------------- slice MHA, stage 3: soT hi/lo = (o @ Wout + bout)^T, split bf16 ----------------
__global__ __launch_bounds__(128) void mha_out_kernel(const float* ovals, const float* Wout,
                                                      const float* bout,
                                                      u16* soThi, u16* soTlo) {
    int blk = blockIdx.x;  // b*SS + s
    int b = blk >> 5, s = blk & 31;
    int t = threadIdx.x;   // = output col c
    __shared__ float row[128];
    row[t] = ovals[(size_t)blk * 128 + t];
    __syncthreads();
    float a = bout[t];
    #pragma unroll 8
    for (int cc = 0; cc < 128; cc++) a += row[cc] * Wout[cc * CC + t];
    u16 hi = f2bf(a);
    size_t idx = (size_t)b * CC * SS + (size_t)t * SS + s;
    soThi[idx] = hi;
    soTlo[idx] = f2bf(a - bf2f(hi));
}

// ---------------- pack FFN weights to bf16 fragment-friendly layouts ----------------
__global__ __launch_bounds__(256) void pack_ffn_weights(const float* Wff1, const float* Wff2,
                                                        u16* W1p, u16* W2p) {
    int idx = blockIdx.x * 256 + threadIdx.x;
    if (idx >= NL * FFN * CC) return;
    int l = idx / (FFN * CC);
    int r = idx - l * (FFN * CC);
    int j = r >> 7, c = r & 127;          // W1p flat index [l][j][c]
    W1p[idx] = f2bf(Wff1[(size_t)l * CC * FFN + (size_t)c * FFN + j]);
    int c2 = r >> 9, j2 = r & 511;        // W2p flat index [l][c2][j2]
    W2p[idx] = f2bf(Wff2[(size_t)l * FFN * CC + (size_t)j2 * CC + c2]);
}

// ---------------- mega kernel: broadcast + residual + LN2 + FFN + next-layer LN1 ----------------
__global__ __launch_bounds__(256, 2) void ffn_mega(float* __restrict__ x,
                                                   const u16* __restrict__ whi,
                                                   const u16* __restrict__ wlo,
                                                   const u16* __restrict__ soThi,
                                                   const u16* __restrict__ soTlo,
                                                   const float* __restrict__ g,
                                                   const float* __restrict__ bb,
                                                   const u16* __restrict__ W1p,
                                                   const float* __restrict__ bff1,
                                                   const u16* __restrict__ W2p,
                                                   const float* __restrict__ bff2,
                                                   const float* __restrict__ g1,
                                                   const float* __restrict__ b1,
                                                   u16* __restrict__ hbf_out) {
    __shared__ u16 h2t[128 * 136];     // LN2 output tile (bf16)
    __shared__ u16 hid[128 * 72];      // hidden chunk (64 j), bf16, +8 pad
    __shared__ float rowst[128][4];    // per-row {sum,sumsq} x {wn}
    __shared__ float gs[128], bsv[128], gs1[128], bs1[128];
    int t = threadIdx.x;
    int b = blockIdx.y;
    int n0 = blockIdx.x * 128;
    int wave = t >> 6, lane = t & 63;
    int wm = wave >> 1, wn = wave & 1;
    int q = lane >> 4, ln16 = lane & 15;
    bool emit = (g1 != nullptr);
    if (t < 128) {
        gs[t] = g[t]; bsv[t] = bb[t];
        if (emit) { gs1[t] = g1[t]; bs1[t] = b1[t]; }
    }

    f32x4 acc2[4][4];
    #pragma unroll
    for (int mi = 0; mi < 4; mi++)
        #pragma unroll
        for (int ni = 0; ni < 4; ni++) acc2[mi][ni] = (f32x4){0.f, 0.f, 0.f, 0.f};

    // ---- phase 0: acc2 = w@so via 3-pass hi/lo MFMA ----
    {
        const u16* soh = soThi + (size_t)b * CC * SS;
        const u16* sol = soTlo + (size_t)b * CC * SS;
        bf16x8 bh[4], bl[4], ah[4], al[4];
        bf16x8 zf;
        #pragma unroll
        for (int i = 0; i < 8; i++) zf[i] = (__bf16)0.0f;
        #pragma unroll
        for (int ni = 0; ni < 4; ni++) {
            int c = wn * 64 + ni * 16 + ln16;
            bh[ni] = *(const bf16x8*)&soh[c * SS + q * 8];
            bl[ni] = *(const bf16x8*)&sol[c * SS + q * 8];
        }
        #pragma unroll
        for (int mi = 0; mi < 4; mi++) {
            int row = n0 + wm * 64 + mi * 16 + ln16;
            if (row < NN) {
                size_t base = ((size_t)b * NN + row) * SS + q * 8;
                ah[mi] = *(const bf16x8*)&whi[base];
                al[mi] = *(const bf16x8*)&wlo[base];
            } else { ah[mi] = zf; al[mi] = zf; }
        }
        #pragma unroll
        for (int mi = 0; mi < 4; mi++)
            #pragma unroll
            for (int ni = 0; ni < 4; ni++) {
                acc2[mi][ni] = __builtin_amdgcn_mfma_f32_16x16x32_bf16(ah[mi], bh[ni], acc2[mi][ni], 0, 0, 0);
                acc2[mi][ni] = __builtin_amdgcn_mfma_f32_16x16x32_bf16(al[mi], bh[ni], acc2[mi][ni], 0, 0, 0);
                acc2[mi][ni] = __builtin_amdgcn_mfma_f32_16x16x32_bf16(ah[mi], bl[ni], acc2[mi][ni], 0, 0, 0);
            }
    }

    // ---- phase 1: acc2 += x (residual); LN2 stats; h2 -> LDS ----
    #pragma unroll
    for (int mi = 0; mi < 4; mi++)
        #pragma unroll
        for (int r = 0; r < 4; r++) {
            int row = n0 + wm * 64 + mi * 16 + q * 4 + r;
            if (row < NN) {
                const float* xr = &x[((size_t)b * NN + row) * CC + wn * 64 + ln16];
                #pragma unroll
                for (int ni = 0; ni < 4; ni++) acc2[mi][ni][r] += xr[ni * 16];
            }
        }
    #pragma unroll
    for (int mi = 0; mi < 4; mi++)
        #pragma unroll
        for (int r = 0; r < 4; r++) {
            float a = acc2[mi][0][r] + acc2[mi][1][r] + acc2[mi][2][r] + acc2[mi][3][r];
            float a2 = acc2[mi][0][r] * acc2[mi][0][r] + acc2[mi][1][r] * acc2[mi][1][r] +
                       acc2[mi][2][r] * acc2[mi][2][r] + acc2[mi][3][r] * acc2[mi][3][r];
            #pragma unroll
            for (int msk = 1; msk < 16; msk <<= 1) {
                a += __shfl_xor(a, msk, 64);
                a2 += __shfl_xor(a2, msk, 64);
            }
            if (ln16 == 0) {
                int m = wm * 64 + mi * 16 + q * 4 + r;
                rowst[m][wn * 2] = a;
                rowst[m][wn * 2 + 1] = a2;
            }
        }
    __syncthreads();
    #pragma unroll
    for (int mi = 0; mi < 4; mi++)
        #pragma unroll
        for (int r = 0; r < 4; r++) {
            int m = wm * 64 + mi * 16 + q * 4 + r;
            float s1 = rowst[m][0] + rowst[m][2];
            float s2 = rowst[m][1] + rowst[m][3];
            float mean = s1 * (1.0f / 128.0f);
            float var = s2 * (1.0f / 128.0f) - mean * mean;
            float rstd = rsqrtf(fmaxf(var, 0.0f) + 1e-5f);
            #pragma unroll
            for (int ni = 0; ni < 4; ni++) {
                int col = wn * 64 + ni * 16 + ln16;
                h2t[m * 136 + col] = f2bf((acc2[mi][ni][r] - mean) * rstd * gs[col] + bsv[col]);
            }
        }
    __syncthreads();

    // ---- phase 2: FFN; acc2 (holding xv) accumulates GEMM2 output ----
    for (int jc = 0; jc < 8; jc++) {
        f32x4 acc1[4][2];
        #pragma unroll
        for (int mi = 0; mi < 4; mi++)
            #pragma unroll
            for (int ni = 0; ni < 2; ni++) acc1[mi][ni] = (f32x4){0.f, 0.f, 0.f, 0.f};

        #pragma unroll
        for (int ks = 0; ks < 4; ks++) {
            bf16x8 af[4], bfr[2];
            #pragma unroll
            for (int mi = 0; mi < 4; mi++)
                af[mi] = *(const bf16x8*)&h2t[(wm * 64 + mi * 16 + ln16) * 136 + ks * 32 + q * 8];
            #pragma unroll
            for (int ni = 0; ni < 2; ni++)
                bfr[ni] = *(const bf16x8*)&W1p[(size_t)(jc * 64 + wn * 32 + ni * 16 + ln16) * CC + ks * 32 + q * 8];
            #pragma unroll
            for (int mi = 0; mi < 4; mi++)
                #pragma unroll
                for (int ni = 0; ni < 2; ni++)
                    acc1[mi][ni] = __builtin_amdgcn_mfma_f32_16x16x32_bf16(af[mi], bfr[ni], acc1[mi][ni], 0, 0, 0);
        }

        #pragma unroll
        for (int ni = 0; ni < 2; ni++) {
            float b1v = bff1[jc * 64 + wn * 32 + ni * 16 + ln16];
            #pragma unroll
            for (int mi = 0; mi < 4; mi++)
                #pragma unroll
                for (int r = 0; r < 4; r++)
                    hid[(wm * 64 + mi * 16 + q * 4 + r) * 72 + wn * 32 + ni * 16 + ln16] =
                        f2bf(gelu_f(acc1[mi][ni][r] + b1v));
        }
        __syncthreads();

        #pragma unroll
        for (int ks2 = 0; ks2 < 2; ks2++) {
            bf16x8 af[4], bfr[4];
            #pragma unroll
            for (int mi = 0; mi < 4; mi++)
                af[mi] = *(const bf16x8*)&hid[(wm * 64 + mi * 16 + ln16) * 72 + ks2 * 32 + q * 8];
            #pragma unroll
            for (int ni = 0; ni < 4; ni++)
                bfr[ni] = *(const bf16x8*)&W2p[(size_t)(wn * 64 + ni * 16 + ln16) * FFN + jc * 64 + ks2 * 32 + q * 8];
            #pragma unroll
            for (int mi = 0; mi < 4; mi++)
                #pragma unroll
                for (int ni = 0; ni < 4; ni++)
                    acc2[mi][ni] = __builtin_amdgcn_mfma_f32_16x16x32_bf16(af[mi], bfr[ni], acc2[mi][ni], 0, 0, 0);
        }
        __syncthreads();
    }

    // ---- epilogue: fold bff2; store x; optional next-layer LN1 -> hbf ----
    float b2[4];
    #pragma unroll
    for (int ni = 0; ni < 4; ni++) b2[ni] = bff2[wn * 64 + ni * 16 + ln16];
    #pragma unroll
    for (int mi = 0; mi < 4; mi++)
        #pragma unroll
        for (int ni = 0; ni < 4; ni++)
            #pragma unroll
            for (int r = 0; r < 4; r++) acc2[mi][ni][r] += b2[ni];

    #pragma unroll
    for (int mi = 0; mi < 4; mi++)
        #pragma unroll
        for (int r = 0; r < 4; r++) {
            int row = n0 + wm * 64 + mi * 16 + q * 4 + r;
            if (row < NN) {
                float* xo = &x[((size_t)b * NN + row) * CC + wn * 64 + ln16];
                #pragma unroll
                for (int ni = 0; ni < 4; ni++) xo[ni * 16] = acc2[mi][ni][r];
            }
        }

    if (emit) {
        #pragma unroll
        for (int mi = 0; mi < 4; mi++)
            #pragma unroll
            for (int r = 0; r < 4; r++) {
                float a = acc2[mi][0][r] + acc2[mi][1][r] + acc2[mi][2][r] + acc2[mi][3][r];
                float a2 = acc2[mi][0][r] * acc2[mi][0][r] + acc2[mi][1][r] * acc2[mi][1][r] +
                           acc2[mi][2][r] * acc2[mi][2][r] + acc2[mi][3][r] * acc2[mi][3][r];
                #pragma unroll
                for (int msk = 1; msk < 16; msk <<= 1) {
                    a += __shfl_xor(a, msk, 64);
                    a2 += __shfl_xor(a2, msk, 64);
                }
                if (ln16 == 0) {
                    int m = wm * 64 + mi * 16 + q * 4 + r;
                    rowst[m][wn * 2] = a;
                    rowst[m][wn * 2 + 1] = a2;
                }
            }
        __syncthreads();
        #pragma unroll
        for (int mi = 0; mi < 4; mi++)
            #pragma unroll
            for (int r = 0; r < 4; r++) {
                int m = wm * 64 + mi * 16 + q * 4 + r;
                int row = n0 + m;
                if (row < NN) {
                    float s1 = rowst[m][0] + rowst[m][2];
                    float s2 = rowst[m][1] + rowst[m][3];
                    float mean = s1 * (1.0f / 128.0f);
                    float var = s2 * (1.0f / 128.0f) - mean * mean;
                    float rstd = rsqrtf(fmaxf(var, 0.0f) + 1e-5f);
                    u16* ho = &hbf_out[((size_t)b * NN + row) * CC + wn * 64 + ln16];
                    #pragma unroll
                    for (int ni = 0; ni < 4; ni++) {
                        int col = wn * 64 + ni * 16 + ln16;
                        ho[ni * 16] = f2bf((acc2[mi][ni][r] - mean) * rstd * gs1[col] + bs1[col]);
                    }
                }
            }
    }
}

// ---------------- final projection ----------------
__global__ __launch_bounds__(128) void proj_kernel(const float* x, const float* W,
                                                   const float* bias, float* outp) {
    int node = blockIdx.x;
    int t = threadIdx.x;
    __shared__ float xr[128];
    __shared__ float pr[40];
    xr[t] = x[(size_t)node * CC + t];
    __syncthreads();
    if (t < 40) {
        int k = t / 8, part = t % 8;
        float a = 0.0f;
        #pragma unroll
        for (int i = 0; i < 16; i++) {
            int c = part * 16 + i;
            a += xr[c] * W[c * C_IN + k];
        }
        pr[t] = a;
    }
    __syncthreads();
    if (t < 5) {
        float a = bias[t];
        #pragma unroll
        for (int p = 0; p < 8; p++) a += pr[t * 8 + p];
        outp[(size_t)node * C_IN + t] = a;
    }
}

extern "C" void kernel_launch(void* const* d_in, const int* in_sizes, int n_in,
                              void* d_out, int out_size, void* d_ws, size_t ws_size,
                              hipStream_t stream) {
    const float* inputs  = (const float*)d_in[0];
    const float* coords  = (const float*)d_in[1];
    const float* t_norm  = (const float*)d_in[2];
    const int*   adj     = (const int*)d_in[3];
    const float* adj_v   = (const float*)d_in[4];
    const float* freq    = (const float*)d_in[5];
    const float* embed_W = (const float*)d_in[6];
    const float* embed_b = (const float*)d_in[7];
    const float* ln1_g   = (const float*)d_in[8];
    const float* ln1_b   = (const float*)d_in[9];
    const float* Wslice  = (const float*)d_in[10];
    const float* bslice  = (const float*)d_in[11];
    const float* Wfront  = (const float*)d_in[12];
    const float* bfront  = (const float*)d_in[13];
    const float* Win     = (const float*)d_in[14];
    const float* b_in    = (const float*)d_in[15];
    const float* Wout    = (const float*)d_in[16];
    const float* bout    = (const float*)d_in[17];
    const float* ln2_g   = (const float*)d_in[18];
    const float* ln2_b   = (const float*)d_in[19];
    const float* Wff1    = (const float*)d_in[20];
    const float* bff1    = (const float*)d_in[21];
    const float* Wff2    = (const float*)d_in[22];
    const float* bff2    = (const float*)d_in[23];
    const float* proj_W  = (const float*)d_in[24];
    const float* proj_b  = (const float*)d_in[25];

    float* out = (float*)d_out;
    float* wout_base = out + (size_t)BATCH * NN * C_IN;

    // workspace layout
    float* x          = (float*)d_ws;
    u16*   hbf        = (u16*)(x + (size_t)NTOT * CC);
    u16*   hlbf       = hbf + (size_t)MPAD * CC;
    u16*   whi        = hlbf + (size_t)MPAD * CC;            // (NTOT+128)*SS
    u16*   wlo        = whi + (size_t)(NTOT + 128) * SS;
    u16*   soThi      = wlo + (size_t)(NTOT + 128) * SS;     // BATCH*CC*SS
    u16*   soTlo      = soThi + BATCH * CC * SS;
    float* slices_acc = (float*)(soTlo + BATCH * CC * SS);
    float* wsum       = slices_acc + BATCH * SS * CC;
    float* qkv_ws     = wsum + BATCH * SS;
    float* ovals_ws   = qkv_ws + BATCH * SS * 384;
    float* csr_val    = ovals_ws + BATCH * SS * CC;
    int*   rowptr     = (int*)(csr_val + NE);
    int*   cursor     = rowptr + (NN + 1);
    int*   deg        = cursor + NN;
    int*   csr_col    = deg + NN;
    u16*   W1p        = (u16*)(csr_col + NE);       // NL*FFN*CC bf16
    u16*   W2p        = W1p + NL * FFN * CC;        // NL*CC*FFN bf16
    u16*   Wcombp     = W2p + NL * CC * FFN;        // NL*SS*256 bf16
    float* bcomb      = (float*)(Wcombp + NL * SS * 256);  // NL*SS fp32

    // ---- CSR build ----
    hipMemsetAsync(deg, 0, NN * sizeof(int), stream);
    count_deg<<<(NE + 255) / 256, 256, 0, stream>>>(adj, deg);
    scan_deg<<<1, 512, 0, stream>>>(deg, rowptr);
    hipMemcpyAsync(cursor, rowptr, NN * sizeof(int), hipMemcpyDeviceToDevice, stream);
    fill_csr<<<(NE + 255) / 256, 256, 0, stream>>>(adj, adj + NE, adj_v, cursor, csr_col, csr_val);

    // ---- pack weights (bf16) ----
    pack_ffn_weights<<<(NL * FFN * CC + 255) / 256, 256, 0, stream>>>(Wff1, Wff2, W1p, W2p);
    pack_logits_weights<<<(NL * SS * 256 + 255) / 256, 256, 0, stream>>>(Wslice, bslice, Wfront,
                                                                         bfront, Wcombp, bcomb);

    // ---- embed + LN1(layer 0) ----
    embed_ln1_kernel<<<NTOT, 128, 0, stream>>>(inputs, coords, t_norm, freq, embed_W, embed_b,
                                               ln1_g, ln1_b, x, hbf);

    for (int l = 0; l < NL; l++) {
        float* wl = wout_base + (size_t)l * NTOT * SS;
        agg_kernel<<<NTOT, 128, 0, stream>>>(hbf, rowptr, csr_col, csr_val, hlbf);
        hipMemsetAsync(slices_acc, 0, (BATCH * SS * CC + BATCH * SS) * sizeof(float), stream);
        dim3 glp(NBLK, BATCH);
        logits_pool<<<glp, 256, 0, stream>>>(hbf, hlbf, Wcombp + (size_t)l * SS * 256,
                                             bcomb + l * SS, wl, whi, wlo, slices_acc, wsum);
        // MHA (parallel 3-stage)
        qkv_kernel<<<BATCH * SS, 128, 0, stream>>>(slices_acc, wsum,
                                                   Win + (size_t)l * CC * 3 * CC,
                                                   b_in + l * 3 * CC, qkv_ws);
        attn_kernel<<<BATCH * NH, 64, 0, stream>>>(qkv_ws, ovals_ws);
        mha_out_kernel<<<BATCH * SS, 128, 0, stream>>>(ovals_ws, Wout + (size_t)l * CC * CC,
                                                       bout + l * CC, soThi, soTlo);
        // fused broadcast + LN2 + FFN + next-layer LN1
        const float* g1n = (l + 1 < NL) ? (ln1_g + (size_t)(l + 1) * CC) : nullptr;
        const float* b1n = (l + 1 < NL) ? (ln1_b + (size_t)(l + 1) * CC) : nullptr;
        dim3 g3(NBLK, BATCH);
        ffn_mega<<<g3, 256, 0, stream>>>(x, whi, wlo, soThi, soTlo,
                                         ln2_g + l * CC, ln2_b + l * CC,
                                         W1p + (size_t)l * FFN * CC, bff1 + l * FFN,
                                         W2p + (size_t)l * CC * FFN, bff2 + l * CC,
                                         g1n, b1n, hbf);
    }

    proj_kernel<<<NTOT, 128, 0, stream>>>(x, proj_W, proj_b, out);
}

// Round 8
// 1888.539 us; speedup vs baseline: 4.1351x; 1.0219x over previous
//
#include <hip/hip_runtime.h>
#include <math.h>

#define BATCH 2
#define NN 50000
#define NE 400000
#define C_IN 5
#define CC 128
#define SS 32
#define NH 8
#define NL 4
#define FFN 512
#define COORD_F 8
#define TIME_F 4
#define HD 16
#define BETA 1.0f
#define TWO_PI 6.283185307179586476925287f

#define NTOT (BATCH * NN)
#define FF_MT 128
#define FF_BLOCKS ((NTOT + FF_MT - 1) / FF_MT)   // 782 (buffer sizing)
#define MPAD (FF_BLOCKS * FF_MT)                  // 100096
#define NBLK ((NN + 127) / 128)                   // 391 per-batch blocks
#define LP_PAD 136                                // u16 row pad (272B, 16B-aligned)

typedef unsigned short u16;
typedef unsigned int u32;
typedef __attribute__((ext_vector_type(8))) __bf16 bf16x8;
typedef __attribute__((ext_vector_type(4))) float f32x4;

__device__ __forceinline__ u16 f2bf(float f) {
    union { float f; u32 u; } v; v.f = f;
    u32 u = v.u;
    u32 r = (u + 0x7fffu + ((u >> 16) & 1u)) >> 16;
    return (u16)r;
}

__device__ __forceinline__ float bf2f(u16 h) {
    union { u32 u; float f; } v; v.u = ((u32)h) << 16;
    return v.f;
}

// erf via Abramowitz-Stegun 7.1.26 (max abs err 1.5e-7)
__device__ __forceinline__ float gelu_f(float a) {
    float xx = a * 0.7071067811865475f;
    float ax = fabsf(xx);
    float t = 1.0f / fmaf(0.3275911f, ax, 1.0f);
    float poly = t * fmaf(t, fmaf(t, fmaf(t, fmaf(t, 1.061405429f, -1.453152027f),
                                          1.421413741f), -0.284496736f), 0.254829592f);
    float e = __expf(-ax * ax);
    float erfv = copysignf(fmaf(-poly, e, 1.0f), xx);
    return 0.5f * a * (1.0f + erfv);
}

// ---------------- CSR build ----------------
__global__ void count_deg(const int* rows, int* deg) {
    int e = blockIdx.x * blockDim.x + threadIdx.x;
    if (e < NE) atomicAdd(&deg[rows[e]], 1);
}

__global__ __launch_bounds__(512) void scan_deg(const int* deg, int* rowptr) {
    __shared__ int part[512];
    int t = threadIdx.x;
    const int CH = (NN + 511) / 512;  // 98
    int begin = t * CH, end = min(begin + CH, NN);
    int s = 0;
    for (int i = begin; i < end; i++) s += deg[i];
    part[t] = s;
    __syncthreads();
    for (int off = 1; off < 512; off <<= 1) {
        int v = (t >= off) ? part[t - off] : 0;
        __syncthreads();
        part[t] += v;
        __syncthreads();
    }
    int base = (t == 0) ? 0 : part[t - 1];
    for (int i = begin; i < end; i++) { rowptr[i] = base; base += deg[i]; }
    if (t == 511) rowptr[NN] = part[511];
}

__global__ void fill_csr(const int* rows, const int* cols, const float* vals,
                         int* cursor, int* csr_col, float* csr_val) {
    int e = blockIdx.x * blockDim.x + threadIdx.x;
    if (e < NE) {
        int p = atomicAdd(&cursor[rows[e]], 1);
        csr_col[p] = cols[e];
        csr_val[p] = vals[e];
    }
}

// ---------------- embed + LN1 fused ----------------
__global__ __launch_bounds__(128) void embed_ln1_kernel(const float* inputs, const float* coords,
                                                        const float* t_norm, const float* freq,
                                                        const float* W, const float* bias,
                                                        const float* g, const float* bb,
                                                        float* x, u16* hbf) {
    int node = blockIdx.x;  // 0..NTOT
    int b = node / NN;
    int t = threadIdx.x;
    __shared__ float feat[32];
    __shared__ float sm[4];
    if (t < 8) {
        float c0 = coords[node * 2 + 0], c1 = coords[node * 2 + 1];
        float p = TWO_PI * (c0 * freq[t] + c1 * freq[8 + t]);
        feat[5 + t] = sinf(p);
        feat[13 + t] = cosf(p);
    } else if (t < 12) {
        int j = t - 8;
        float omega = powf(1000.0f, -(float)j * 0.25f);
        float ang = omega * t_norm[b] * 1000.0f;
        feat[21 + j] = sinf(ang);
        feat[25 + j] = cosf(ang);
    } else if (t >= 16 && t < 21) {
        feat[t - 16] = inputs[node * 5 + (t - 16)];
    }
    __syncthreads();
    float acc = bias[t];
    #pragma unroll
    for (int k = 0; k < 29; k++) acc += feat[k] * W[k * CC + t];
    x[(size_t)node * CC + t] = acc;
    // LN1
    float s = acc;
    #pragma unroll
    for (int off = 32; off > 0; off >>= 1) s += __shfl_xor(s, off, 64);
    if ((t & 63) == 0) sm[t >> 6] = s;
    __syncthreads();
    float mean = (sm[0] + sm[1]) * (1.0f / 128.0f);
    float d = acc - mean;
    float ss = d * d;
    #pragma unroll
    for (int off = 32; off > 0; off >>= 1) ss += __shfl_xor(ss, off, 64);
    if ((t & 63) == 0) sm[2 + (t >> 6)] = ss;
    __syncthreads();
    float var = (sm[2] + sm[3]) * (1.0f / 128.0f);
    hbf[(size_t)node * CC + t] = f2bf(d * rsqrtf(var + 1e-5f) * g[t] + bb[t]);
}

// ---------------- sparse aggregation (gather via CSR, bf16 in/out, 4-way pipelined) ----------------
__global__ __launch_bounds__(128) void agg_kernel(const u16* hbf, const int* rowptr,
                                                  const int* csr_col, const float* csr_val,
                                                  u16* hlbf) {
    int blk = blockIdx.x;         // 0..NTOT
    int b = blk / NN, r = blk % NN;
    int t = threadIdx.x;
    int s0 = rowptr[r], s1 = rowptr[r + 1];
    const u16* hb = hbf + (size_t)b * NN * CC;
    float a0 = 0.0f, a1 = 0.0f, a2 = 0.0f, a3 = 0.0f;
    int e = s0;
    for (; e + 4 <= s1; e += 4) {
        int c0 = csr_col[e], c1 = csr_col[e + 1], c2 = csr_col[e + 2], c3 = csr_col[e + 3];
        float v0 = csr_val[e], v1 = csr_val[e + 1], v2 = csr_val[e + 2], v3 = csr_val[e + 3];
        u16 h0 = hb[(size_t)c0 * CC + t];
        u16 h1 = hb[(size_t)c1 * CC + t];
        u16 h2 = hb[(size_t)c2 * CC + t];
        u16 h3 = hb[(size_t)c3 * CC + t];
        a0 += v0 * bf2f(h0);
        a1 += v1 * bf2f(h1);
        a2 += v2 * bf2f(h2);
        a3 += v3 * bf2f(h3);
    }
    for (; e < s1; e++) a0 += csr_val[e] * bf2f(hb[(size_t)csr_col[e] * CC + t]);
    hlbf[(size_t)blk * CC + t] = f2bf((a0 + a1) + (a2 + a3));
}

// ---------------- pack combined logits weights ----------------
__global__ __launch_bounds__(256) void pack_logits_weights(const float* Ws, const float* bs,
                                                           const float* Wf, const float* bf,
                                                           u16* Wcombp, float* bcombp) {
    int idx = blockIdx.x * 256 + threadIdx.x;
    if (idx >= NL * SS * 256) return;
    int l = idx / (SS * 256);
    int r = idx - l * (SS * 256);
    int s = r >> 8, k = r & 255;
    float v;
    if (k < 128)
        v = Ws[(size_t)l * CC * SS + (size_t)k * SS + s] + BETA * Wf[(size_t)l * CC * SS + (size_t)k * SS + s];
    else
        v = -BETA * Wf[(size_t)l * CC * SS + (size_t)(k - 128) * SS + s];
    Wcombp[idx] = f2bf(v);
    if (k == 0) bcombp[l * SS + s] = bs[l * SS + s] + BETA * bf[l * SS + s];
}

// ---------------- fused logits + softmax + slice pooling ----------------
// grid (NBLK, BATCH); 256 thr = 4 waves; 128 nodes/block; each wave owns 32 nodes.
__global__ __launch_bounds__(256, 2) void logits_pool(const u16* __restrict__ hbf,
                                                      const u16* __restrict__ hlbf,
                                                      const u16* __restrict__ Wcomb,
                                                      const float* __restrict__ bcomb,
                                                      float* __restrict__ wout,
                                                      u16* __restrict__ whi,
                                                      u16* __restrict__ wlo,
                                                      float* __restrict__ slices_acc,
                                                      float* __restrict__ wsum) {
    __shared__ __align__(16) u16 hT[128 * LP_PAD];   // [c][n_local]; reused as fp32 reduce buf
    __shared__ __align__(16) u16 wTh[SS * LP_PAD];   // [s][n_local] hi
    __shared__ __align__(16) u16 wTl[SS * LP_PAD];   // lo
    __shared__ float wsum_sh[SS];
    int t = threadIdx.x;
    int b = blockIdx.y;
    int nl0 = blockIdx.x * 128;                      // local node base (within batch)
    int wv = t >> 6, lane = t & 63;
    int q = lane >> 4, ln16 = lane & 15;
    int nl0w = nl0 + wv * 32;                        // this wave's 32-node base
    if (t < SS) wsum_sh[t] = 0.0f;
    __syncthreads();

    // ---- logits GEMM + hT transpose ----
    f32x4 acc[2][2];
    #pragma unroll
    for (int mi = 0; mi < 2; mi++)
        #pragma unroll
        for (int ni = 0; ni < 2; ni++) acc[mi][ni] = (f32x4){0.f, 0.f, 0.f, 0.f};

    #pragma unroll
    for (int ks = 0; ks < 8; ks++) {
        const u16* src = (ks < 4) ? hbf : hlbf;
        int ko = (ks & 3) * 32 + q * 8;
        bf16x8 af[2], bfrg[2];
        #pragma unroll
        for (int mi = 0; mi < 2; mi++) {
            int nl = nl0w + mi * 16 + ln16;          // local node of this A row
            af[mi] = *(const bf16x8*)&src[((size_t)b * NN + nl) * CC + ko];
            if (ks < 4) {
                bool valid = nl < NN;
                const u16* ap = (const u16*)&af[mi];
                int nlb = nl - nl0;                  // 0..127 within block
                #pragma unroll
                for (int i = 0; i < 8; i++)
                    hT[(ko + i) * LP_PAD + nlb] = valid ? ap[i] : (u16)0;
            }
        }
        #pragma unroll
        for (int ni = 0; ni < 2; ni++)
            bfrg[ni] = *(const bf16x8*)&Wcomb[(size_t)(ni * 16 + ln16) * 256 + ks * 32 + q * 8];
        #pragma unroll
        for (int mi = 0; mi < 2; mi++)
            #pragma unroll
            for (int ni = 0; ni < 2; ni++)
                acc[mi][ni] = __builtin_amdgcn_mfma_f32_16x16x32_bf16(af[mi], bfrg[ni], acc[mi][ni], 0, 0, 0);
    }

    // ---- in-register softmax + w outputs + wT tiles + wsum ----
    float bc0 = bcomb[ln16], bc1 = bcomb[16 + ln16];
    float ws0 = 0.0f, ws1 = 0.0f;
    #pragma unroll
    for (int mi = 0; mi < 2; mi++)
        #pragma unroll
        for (int r = 0; r < 4; r++) {
            float l0 = acc[mi][0][r] + bc0;
            float l1 = acc[mi][1][r] + bc1;
            float m = fmaxf(l0, l1);
            #pragma unroll
            for (int msk = 1; msk < 16; msk <<= 1) m = fmaxf(m, __shfl_xor(m, msk, 64));
            float e0 = __expf(l0 - m), e1 = __expf(l1 - m);
            float sum = e0 + e1;
            #pragma unroll
            for (int msk = 1; msk < 16; msk <<= 1) sum += __shfl_xor(sum, msk, 64);
            float is = 1.0f / sum;
            int nl = nl0w + mi * 16 + q * 4 + r;     // local node (row)
            bool valid = nl < NN;
            float w0 = valid ? e0 * is : 0.0f;
            float w1 = valid ? e1 * is : 0.0f;
            u16 h0 = f2bf(w0), h1 = f2bf(w1);
            u16 lo0 = f2bf(w0 - bf2f(h0)), lo1 = f2bf(w1 - bf2f(h1));
            if (valid) {
                size_t gb = ((size_t)b * NN + nl) * SS;
                wout[gb + ln16] = w0;
                wout[gb + 16 + ln16] = w1;
                whi[gb + ln16] = h0;  wlo[gb + ln16] = lo0;
                whi[gb + 16 + ln16] = h1;  wlo[gb + 16 + ln16] = lo1;
            }
            int nlb = nl - nl0;
            wTh[ln16 * LP_PAD + nlb] = h0;  wTl[ln16 * LP_PAD + nlb] = lo0;
            wTh[(16 + ln16) * LP_PAD + nlb] = h1;  wTl[(16 + ln16) * LP_PAD + nlb] = lo1;
            ws0 += w0;  ws1 += w1;
        }
    // reduce wsum partials across q groups (lanes with same ln16)
    ws0 += __shfl_xor(ws0, 16, 64); ws0 += __shfl_xor(ws0, 32, 64);
    ws1 += __shfl_xor(ws1, 16, 64); ws1 += __shfl_xor(ws1, 32, 64);
    if (q == 0) {
        atomicAdd(&wsum_sh[ln16], ws0);
        atomicAdd(&wsum_sh[16 + ln16], ws1);
    }
    __syncthreads();

    // ---- pooling MFMA: D[s][c] += wT(32 x K32) @ h(K32 x 128), per-wave K-slice ----
    f32x4 pacc[2][8];
    #pragma unroll
    for (int st = 0; st < 2; st++)
        #pragma unroll
        for (int ct = 0; ct < 8; ct++) pacc[st][ct] = (f32x4){0.f, 0.f, 0.f, 0.f};
    {
        int kb = wv * 32 + q * 8;
        bf16x8 wh[2], wl2[2];
        #pragma unroll
        for (int st = 0; st < 2; st++) {
            wh[st] = *(const bf16x8*)&wTh[(st * 16 + ln16) * LP_PAD + kb];
            wl2[st] = *(const bf16x8*)&wTl[(st * 16 + ln16) * LP_PAD + kb];
        }
        #pragma unroll
        for (int ct = 0; ct < 8; ct++) {
            bf16x8 bfr = *(const bf16x8*)&hT[(ct * 16 + ln16) * LP_PAD + kb];
            #pragma unroll
            for (int st = 0; st < 2; st++) {
                pacc[st][ct] = __builtin_amdgcn_mfma_f32_16x16x32_bf16(wh[st], bfr, pacc[st][ct], 0, 0, 0);
                pacc[st][ct] = __builtin_amdgcn_mfma_f32_16x16x32_bf16(wl2[st], bfr, pacc[st][ct], 0, 0, 0);
            }
        }
    }
    __syncthreads();

    // ---- cross-wave reduce (reuse hT as fp32 [32][128]) then global atomics ----
    float* red = (float*)hT;
    for (int i = t; i < SS * CC; i += 256) red[i] = 0.0f;
    __syncthreads();
    #pragma unroll
    for (int st = 0; st < 2; st++)
        #pragma unroll
        for (int ct = 0; ct < 8; ct++)
            #pragma unroll
            for (int r = 0; r < 4; r++)
                atomicAdd(&red[(st * 16 + q * 4 + r) * CC + ct * 16 + ln16], pacc[st][ct][r]);
    __syncthreads();
    if (t < SS) atomicAdd(&wsum[b * SS + t], wsum_sh[t]);
    #pragma unroll
    for (int k = 0; k < 16; k++) {
        int idx = k * 256 + t;
        atomicAdd(&slices_acc[(size_t)b * SS * CC + idx], red[idx]);
    }
}

// ---------------- slice MHA, stage 1: qkv = (slices/wsum) @ Win + b_in ----------------
__global__ __launch_bounds__(128) void qkv_kernel(const float* slices_acc, const float* wsum,
                                                  const float* Win, const float* b_in_p,
                                                  float* qkv) {
    int blk = blockIdx.x;  // b*SS + s
    int t = threadIdx.x;
    __shared__ float row[128];
    float iv = 1.0f / fmaxf(wsum[blk], 1e-8f);
    row[t] = slices_acc[(size_t)blk * CC + t] * iv;
    __syncthreads();
    #pragma unroll
    for (int jj = 0; jj < 3; jj++) {
        int j = t + jj * 128;
        float a = b_in_p[j];
        #pragma unroll 8
        for (int c = 0; c < 128; c++) a += row[c] * Win[c * 384 + j];
        qkv[(size_t)blk * 384 + j] = a;
    }
}

// ---------------- slice MHA, stage 2: attention per (b,h) ----------------
__global__ __launch_bounds__(64) void attn_kernel(const float* qkv, float* ovals) {
    int blk = blockIdx.x;  // b*NH + h
    int b = blk >> 3, h = blk & 7;
    int t = threadIdx.x;
    __shared__ float ksh[32 * 16], vsh[32 * 16];
    for (int i = t; i < 512; i += 64) {
        int k = i >> 4, d = i & 15;
        ksh[i] = qkv[((size_t)b * 32 + k) * 384 + 128 + h * 16 + d];
        vsh[i] = qkv[((size_t)b * 32 + k) * 384 + 256 + h * 16 + d];
    }
    __syncthreads();
    if (t < 32) {
        float qr[16];
        #pragma unroll
        for (int d = 0; d < 16; d++) qr[d] = qkv[((size_t)b * 32 + t) * 384 + h * 16 + d];
        float sc[32];
        float m = -1e30f;
        for (int k = 0; k < 32; k++) {
            float a = 0.0f;
            #pragma unroll
            for (int d = 0; d < 16; d++) a += qr[d] * ksh[k * 16 + d];
            a *= 0.25f;  // 1/sqrt(16)
            sc[k] = a;
            m = fmaxf(m, a);
        }
        float ssum = 0.0f;
        for (int k = 0; k < 32; k++) { float e = expf(sc[k] - m); sc[k] = e; ssum += e; }
        float is = 1.0f / ssum;
        float o[16];
        #pragma unroll
        for (int d = 0; d < 16; d++) o[d] = 0.0f;
        for (int k = 0; k < 32; k++) {
            float p = sc[k] * is;
            #pragma unroll
            for (int d = 0; d < 16; d++) o[d] += p * vsh[k * 16 + d];
        }
        #pragma unroll
        for (int d = 0; d < 16; d++) ovals[((size_t)b * 32 + t) * 128 + h * 16 + d] = o[d];
    }
}

// ---------------- slice MHA, stage 3: soT hi/lo = (o @ Wout + bout)^T, split bf16 ----------------
__global__ __launch_bounds__(128) void mha_out_kernel(const float* ovals, const float* Wout,
                                                      const float* bout,
                                                      u16* soThi, u16* soTlo) {
    int blk = blockIdx.x;  // b*SS + s
    int b = blk >> 5, s = blk & 31;
    int t = threadIdx.x;   // = output col c
    __shared__ float row[128];
    row[t] = ovals[(size_t)blk * 128 + t];
    __syncthreads();
    float a = bout[t];
    #pragma unroll 8
    for (int cc = 0; cc < 128; cc++) a += row[cc] * Wout[cc * CC + t];
    u16 hi = f2bf(a);
    size_t idx = (size_t)b * CC * SS + (size_t)t * SS + s;
    soThi[idx] = hi;
    soTlo[idx] = f2bf(a - bf2f(hi));
}

// ---------------- pack FFN weights to bf16 fragment-friendly layouts ----------------
__global__ __launch_bounds__(256) void pack_ffn_weights(const float* Wff1, const float* Wff2,
                                                        u16* W1p, u16* W2p) {
    int idx = blockIdx.x * 256 + threadIdx.x;
    if (idx >= NL * FFN * CC) return;
    int l = idx / (FFN * CC);
    int r = idx - l * (FFN * CC);
    int j = r >> 7, c = r & 127;          // W1p flat index [l][j][c]
    W1p[idx] = f2bf(Wff1[(size_t)l * CC * FFN + (size_t)c * FFN + j]);
    int c2 = r >> 9, j2 = r & 511;        // W2p flat index [l][c2][j2]
    W2p[idx] = f2bf(Wff2[(size_t)l * FFN * CC + (size_t)j2 * CC + c2]);
}

// ---------------- mega kernel: broadcast + residual + LN2 + FFN + next-layer LN1 ----------------
// LDS diet: rowst aliases the hid region (temporally disjoint); LN params in registers.
// 53248 B LDS -> 3 blocks/CU.
__global__ __launch_bounds__(256, 3) void ffn_mega(float* __restrict__ x,
                                                   const u16* __restrict__ whi,
                                                   const u16* __restrict__ wlo,
                                                   const u16* __restrict__ soThi,
                                                   const u16* __restrict__ soTlo,
                                                   const float* __restrict__ g,
                                                   const float* __restrict__ bb,
                                                   const u16* __restrict__ W1p,
                                                   const float* __restrict__ bff1,
                                                   const u16* __restrict__ W2p,
                                                   const float* __restrict__ bff2,
                                                   const float* __restrict__ g1,
                                                   const float* __restrict__ b1,
                                                   u16* __restrict__ hbf_out) {
    __shared__ __align__(16) u16 smem[128 * 136 + 128 * 72];  // 53248 B
    u16* h2t = smem;                       // LN2 tile, stride 136, persists all jc
    u16* hid = smem + 128 * 136;           // hidden chunk, stride 72
    float* rowst = (float*)(smem + 128 * 136);  // aliases hid: used only when hid dead
    int t = threadIdx.x;
    int b = blockIdx.y;
    int n0 = blockIdx.x * 128;
    int wave = t >> 6, lane = t & 63;
    int wm = wave >> 1, wn = wave & 1;
    int q = lane >> 4, ln16 = lane & 15;
    bool emit = (g1 != nullptr);

    // per-thread LN params (cols fixed per thread)
    float gr[4], br[4], g1r[4], b1r[4];
    #pragma unroll
    for (int ni = 0; ni < 4; ni++) {
        int col = wn * 64 + ni * 16 + ln16;
        gr[ni] = g[col]; br[ni] = bb[col];
        if (emit) { g1r[ni] = g1[col]; b1r[ni] = b1[col]; }
    }

    f32x4 acc2[4][4];
    #pragma unroll
    for (int mi = 0; mi < 4; mi++)
        #pragma unroll
        for (int ni = 0; ni < 4; ni++) acc2[mi][ni] = (f32x4){0.f, 0.f, 0.f, 0.f};

    // ---- phase 0: acc2 = w@so via 3-pass hi/lo MFMA ----
    {
        const u16* soh = soThi + (size_t)b * CC * SS;
        const u16* sol = soTlo + (size_t)b * CC * SS;
        bf16x8 bh[4], bl[4], ah[4], al[4];
        bf16x8 zf;
        #pragma unroll
        for (int i = 0; i < 8; i++) zf[i] = (__bf16)0.0f;
        #pragma unroll
        for (int ni = 0; ni < 4; ni++) {
            int c = wn * 64 + ni * 16 + ln16;
            bh[ni] = *(const bf16x8*)&soh[c * SS + q * 8];
            bl[ni] = *(const bf16x8*)&sol[c * SS + q * 8];
        }
        #pragma unroll
        for (int mi = 0; mi < 4; mi++) {
            int row = n0 + wm * 64 + mi * 16 + ln16;
            if (row < NN) {
                size_t base = ((size_t)b * NN + row) * SS + q * 8;
                ah[mi] = *(const bf16x8*)&whi[base];
                al[mi] = *(const bf16x8*)&wlo[base];
            } else { ah[mi] = zf; al[mi] = zf; }
        }
        #pragma unroll
        for (int mi = 0; mi < 4; mi++)
            #pragma unroll
            for (int ni = 0; ni < 4; ni++) {
                acc2[mi][ni] = __builtin_amdgcn_mfma_f32_16x16x32_bf16(ah[mi], bh[ni], acc2[mi][ni], 0, 0, 0);
                acc2[mi][ni] = __builtin_amdgcn_mfma_f32_16x16x32_bf16(al[mi], bh[ni], acc2[mi][ni], 0, 0, 0);
                acc2[mi][ni] = __builtin_amdgcn_mfma_f32_16x16x32_bf16(ah[mi], bl[ni], acc2[mi][ni], 0, 0, 0);
            }
    }

    // ---- phase 1: acc2 += x (residual); LN2 stats (rowst in hid region); h2 -> LDS ----
    #pragma unroll
    for (int mi = 0; mi < 4; mi++)
        #pragma unroll
        for (int r = 0; r < 4; r++) {
            int row = n0 + wm * 64 + mi * 16 + q * 4 + r;
            if (row < NN) {
                const float* xr = &x[((size_t)b * NN + row) * CC + wn * 64 + ln16];
                #pragma unroll
                for (int ni = 0; ni < 4; ni++) acc2[mi][ni][r] += xr[ni * 16];
            }
        }
    #pragma unroll
    for (int mi = 0; mi < 4; mi++)
        #pragma unroll
        for (int r = 0; r < 4; r++) {
            float a = acc2[mi][0][r] + acc2[mi][1][r] + acc2[mi][2][r] + acc2[mi][3][r];
            float a2 = acc2[mi][0][r] * acc2[mi][0][r] + acc2[mi][1][r] * acc2[mi][1][r] +
                       acc2[mi][2][r] * acc2[mi][2][r] + acc2[mi][3][r] * acc2[mi][3][r];
            #pragma unroll
            for (int msk = 1; msk < 16; msk <<= 1) {
                a += __shfl_xor(a, msk, 64);
                a2 += __shfl_xor(a2, msk, 64);
            }
            if (ln16 == 0) {
                int m = wm * 64 + mi * 16 + q * 4 + r;
                rowst[m * 4 + wn * 2] = a;
                rowst[m * 4 + wn * 2 + 1] = a2;
            }
        }
    __syncthreads();
    #pragma unroll
    for (int mi = 0; mi < 4; mi++)
        #pragma unroll
        for (int r = 0; r < 4; r++) {
            int m = wm * 64 + mi * 16 + q * 4 + r;
            float s1 = rowst[m * 4 + 0] + rowst[m * 4 + 2];
            float s2 = rowst[m * 4 + 1] + rowst[m * 4 + 3];
            float mean = s1 * (1.0f / 128.0f);
            float var = s2 * (1.0f / 128.0f) - mean * mean;
            float rstd = rsqrtf(fmaxf(var, 0.0f) + 1e-5f);
            #pragma unroll
            for (int ni = 0; ni < 4; ni++) {
                int col = wn * 64 + ni * 16 + ln16;
                h2t[m * 136 + col] = f2bf((acc2[mi][ni][r] - mean) * rstd * gr[ni] + br[ni]);
            }
        }
    __syncthreads();   // rowst reads done; hid region may now be overwritten

    // ---- phase 2: FFN; acc2 (holding xv) accumulates GEMM2 output ----
    for (int jc = 0; jc < 8; jc++) {
        f32x4 acc1[4][2];
        #pragma unroll
        for (int mi = 0; mi < 4; mi++)
            #pragma unroll
            for (int ni = 0; ni < 2; ni++) acc1[mi][ni] = (f32x4){0.f, 0.f, 0.f, 0.f};

        #pragma unroll
        for (int ks = 0; ks < 4; ks++) {
            bf16x8 af[4], bfr[2];
            #pragma unroll
            for (int mi = 0; mi < 4; mi++)
                af[mi] = *(const bf16x8*)&h2t[(wm * 64 + mi * 16 + ln16) * 136 + ks * 32 + q * 8];
            #pragma unroll
            for (int ni = 0; ni < 2; ni++)
                bfr[ni] = *(const bf16x8*)&W1p[(size_t)(jc * 64 + wn * 32 + ni * 16 + ln16) * CC + ks * 32 + q * 8];
            #pragma unroll
            for (int mi = 0; mi < 4; mi++)
                #pragma unroll
                for (int ni = 0; ni < 2; ni++)
                    acc1[mi][ni] = __builtin_amdgcn_mfma_f32_16x16x32_bf16(af[mi], bfr[ni], acc1[mi][ni], 0, 0, 0);
        }

        #pragma unroll
        for (int ni = 0; ni < 2; ni++) {
            float b1v = bff1[jc * 64 + wn * 32 + ni * 16 + ln16];
            #pragma unroll
            for (int mi = 0; mi < 4; mi++)
                #pragma unroll
                for (int r = 0; r < 4; r++)
                    hid[(wm * 64 + mi * 16 + q * 4 + r) * 72 + wn * 32 + ni * 16 + ln16] =
                        f2bf(gelu_f(acc1[mi][ni][r] + b1v));
        }
        __syncthreads();

        #pragma unroll
        for (int ks2 = 0; ks2 < 2; ks2++) {
            bf16x8 af[4], bfr[4];
            #pragma unroll
            for (int mi = 0; mi < 4; mi++)
                af[mi] = *(const bf16x8*)&hid[(wm * 64 + mi * 16 + ln16) * 72 + ks2 * 32 + q * 8];
            #pragma unroll
            for (int ni = 0; ni < 4; ni++)
                bfr[ni] = *(const bf16x8*)&W2p[(size_t)(wn * 64 + ni * 16 + ln16) * FFN + jc * 64 + ks2 * 32 + q * 8];
            #pragma unroll
            for (int mi = 0; mi < 4; mi++)
                #pragma unroll
                for (int ni = 0; ni < 4; ni++)
                    acc2[mi][ni] = __builtin_amdgcn_mfma_f32_16x16x32_bf16(af[mi], bfr[ni], acc2[mi][ni], 0, 0, 0);
        }
        __syncthreads();
    }

    // ---- epilogue: fold bff2; store x; optional next-layer LN1 -> hbf ----
    float b2[4];
    #pragma unroll
    for (int ni = 0; ni < 4; ni++) b2[ni] = bff2[wn * 64 + ni * 16 + ln16];
    #pragma unroll
    for (int mi = 0; mi < 4; mi++)
        #pragma unroll
        for (int ni = 0; ni < 4; ni++)
            #pragma unroll
            for (int r = 0; r < 4; r++) acc2[mi][ni][r] += b2[ni];

    #pragma unroll
    for (int mi = 0; mi < 4; mi++)
        #pragma unroll
        for (int r = 0; r < 4; r++) {
            int row = n0 + wm * 64 + mi * 16 + q * 4 + r;
            if (row < NN) {
                float* xo = &x[((size_t)b * NN + row) * CC + wn * 64 + ln16];
                #pragma unroll
                for (int ni = 0; ni < 4; ni++) xo[ni * 16] = acc2[mi][ni][r];
            }
        }

    if (emit) {
        // hid region dead after final jc barrier -> rowst reusable
        #pragma unroll
        for (int mi = 0; mi < 4; mi++)
            #pragma unroll
            for (int r = 0; r < 4; r++) {
                float a = acc2[mi][0][r] + acc2[mi][1][r] + acc2[mi][2][r] + acc2[mi][3][r];
                float a2 = acc2[mi][0][r] * acc2[mi][0][r] + acc2[mi][1][r] * acc2[mi][1][r] +
                           acc2[mi][2][r] * acc2[mi][2][r] + acc2[mi][3][r] * acc2[mi][3][r];
                #pragma unroll
                for (int msk = 1; msk < 16; msk <<= 1) {
                    a += __shfl_xor(a, msk, 64);
                    a2 += __shfl_xor(a2, msk, 64);
                }
                if (ln16 == 0) {
                    int m = wm * 64 + mi * 16 + q * 4 + r;
                    rowst[m * 4 + wn * 2] = a;
                    rowst[m * 4 + wn * 2 + 1] = a2;
                }
            }
        __syncthreads();
        #pragma unroll
        for (int mi = 0; mi < 4; mi++)
            #pragma unroll
            for (int r = 0; r < 4; r++) {
                int m = wm * 64 + mi * 16 + q * 4 + r;
                int row = n0 + m;
                if (row < NN) {
                    float s1 = rowst[m * 4 + 0] + rowst[m * 4 + 2];
                    float s2 = rowst[m * 4 + 1] + rowst[m * 4 + 3];
                    float mean = s1 * (1.0f / 128.0f);
                    float var = s2 * (1.0f / 128.0f) - mean * mean;
                    float rstd = rsqrtf(fmaxf(var, 0.0f) + 1e-5f);
                    u16* ho = &hbf_out[((size_t)b * NN + row) * CC + wn * 64 + ln16];
                    #pragma unroll
                    for (int ni = 0; ni < 4; ni++)
                        ho[ni * 16] = f2bf((acc2[mi][ni][r] - mean) * rstd * g1r[ni] + b1r[ni]);
                }
            }
    }
}

// ---------------- final projection ----------------
__global__ __launch_bounds__(128) void proj_kernel(const float* x, const float* W,
                                                   const float* bias, float* outp) {
    int node = blockIdx.x;
    int t = threadIdx.x;
    __shared__ float xr[128];
    __shared__ float pr[40];
    xr[t] = x[(size_t)node * CC + t];
    __syncthreads();
    if (t < 40) {
        int k = t / 8, part = t % 8;
        float a = 0.0f;
        #pragma unroll
        for (int i = 0; i < 16; i++) {
            int c = part * 16 + i;
            a += xr[c] * W[c * C_IN + k];
        }
        pr[t] = a;
    }
    __syncthreads();
    if (t < 5) {
        float a = bias[t];
        #pragma unroll
        for (int p = 0; p < 8; p++) a += pr[t * 8 + p];
        outp[(size_t)node * C_IN + t] = a;
    }
}

extern "C" void kernel_launch(void* const* d_in, const int* in_sizes, int n_in,
                              void* d_out, int out_size, void* d_ws, size_t ws_size,
                              hipStream_t stream) {
    const float* inputs  = (const float*)d_in[0];
    const float* coords  = (const float*)d_in[1];
    const float* t_norm  = (const float*)d_in[2];
    const int*   adj     = (const int*)d_in[3];
    const float* adj_v   = (const float*)d_in[4];
    const float* freq    = (const float*)d_in[5];
    const float* embed_W = (const float*)d_in[6];
    const float* embed_b = (const float*)d_in[7];
    const float* ln1_g   = (const float*)d_in[8];
    const float* ln1_b   = (const float*)d_in[9];
    const float* Wslice  = (const float*)d_in[10];
    const float* bslice  = (const float*)d_in[11];
    const float* Wfront  = (const float*)d_in[12];
    const float* bfront  = (const float*)d_in[13];
    const float* Win     = (const float*)d_in[14];
    const float* b_in    = (const float*)d_in[15];
    const float* Wout    = (const float*)d_in[16];
    const float* bout    = (const float*)d_in[17];
    const float* ln2_g   = (const float*)d_in[18];
    const float* ln2_b   = (const float*)d_in[19];
    const float* Wff1    = (const float*)d_in[20];
    const float* bff1    = (const float*)d_in[21];
    const float* Wff2    = (const float*)d_in[22];
    const float* bff2    = (const float*)d_in[23];
    const float* proj_W  = (const float*)d_in[24];
    const float* proj_b  = (const float*)d_in[25];

    float* out = (float*)d_out;
    float* wout_base = out + (size_t)BATCH * NN * C_IN;

    // workspace layout
    float* x          = (float*)d_ws;
    u16*   hbf        = (u16*)(x + (size_t)NTOT * CC);
    u16*   hlbf       = hbf + (size_t)MPAD * CC;
    u16*   whi        = hlbf + (size_t)MPAD * CC;            // (NTOT+128)*SS
    u16*   wlo        = whi + (size_t)(NTOT + 128) * SS;
    u16*   soThi      = wlo + (size_t)(NTOT + 128) * SS;     // BATCH*CC*SS
    u16*   soTlo      = soThi + BATCH * CC * SS;
    float* slices_acc = (float*)(soTlo + BATCH * CC * SS);
    float* wsum       = slices_acc + BATCH * SS * CC;
    float* qkv_ws     = wsum + BATCH * SS;
    float* ovals_ws   = qkv_ws + BATCH * SS * 384;
    float* csr_val    = ovals_ws + BATCH * SS * CC;
    int*   rowptr     = (int*)(csr_val + NE);
    int*   cursor     = rowptr + (NN + 1);
    int*   deg        = cursor + NN;
    int*   csr_col    = deg + NN;
    u16*   W1p        = (u16*)(csr_col + NE);       // NL*FFN*CC bf16
    u16*   W2p        = W1p + NL * FFN * CC;        // NL*CC*FFN bf16
    u16*   Wcombp     = W2p + NL * CC * FFN;        // NL*SS*256 bf16
    float* bcomb      = (float*)(Wcombp + NL * SS * 256);  // NL*SS fp32

    // ---- CSR build ----
    hipMemsetAsync(deg, 0, NN * sizeof(int), stream);
    count_deg<<<(NE + 255) / 256, 256, 0, stream>>>(adj, deg);
    scan_deg<<<1, 512, 0, stream>>>(deg, rowptr);
    hipMemcpyAsync(cursor, rowptr, NN * sizeof(int), hipMemcpyDeviceToDevice, stream);
    fill_csr<<<(NE + 255) / 256, 256, 0, stream>>>(adj, adj + NE, adj_v, cursor, csr_col, csr_val);

    // ---- pack weights (bf16) ----
    pack_ffn_weights<<<(NL * FFN * CC + 255) / 256, 256, 0, stream>>>(Wff1, Wff2, W1p, W2p);
    pack_logits_weights<<<(NL * SS * 256 + 255) / 256, 256, 0, stream>>>(Wslice, bslice, Wfront,
                                                                         bfront, Wcombp, bcomb);

    // ---- embed + LN1(layer 0) ----
    embed_ln1_kernel<<<NTOT, 128, 0, stream>>>(inputs, coords, t_norm, freq, embed_W, embed_b,
                                               ln1_g, ln1_b, x, hbf);

    for (int l = 0; l < NL; l++) {
        float* wl = wout_base + (size_t)l * NTOT * SS;
        agg_kernel<<<NTOT, 128, 0, stream>>>(hbf, rowptr, csr_col, csr_val, hlbf);
        hipMemsetAsync(slices_acc, 0, (BATCH * SS * CC + BATCH * SS) * sizeof(float), stream);
        dim3 glp(NBLK, BATCH);
        logits_pool<<<glp, 256, 0, stream>>>(hbf, hlbf, Wcombp + (size_t)l * SS * 256,
                                             bcomb + l * SS, wl, whi, wlo, slices_acc, wsum);
        // MHA (parallel 3-stage)
        qkv_kernel<<<BATCH * SS, 128, 0, stream>>>(slices_acc, wsum,
                                                   Win + (size_t)l * CC * 3 * CC,
                                                   b_in + l * 3 * CC, qkv_ws);
        attn_kernel<<<BATCH * NH, 64, 0, stream>>>(qkv_ws, ovals_ws);
        mha_out_kernel<<<BATCH * SS, 128, 0, stream>>>(ovals_ws, Wout + (size_t)l * CC * CC,
                                                       bout + l * CC, soThi, soTlo);
        // fused broadcast + LN2 + FFN + next-layer LN1
        const float* g1n = (l + 1 < NL) ? (ln1_g + (size_t)(l + 1) * CC) : nullptr;
        const float* b1n = (l + 1 < NL) ? (ln1_b + (size_t)(l + 1) * CC) : nullptr;
        dim3 g3(NBLK, BATCH);
        ffn_mega<<<g3, 256, 0, stream>>>(x, whi, wlo, soThi, soTlo,
                                         ln2_g + l * CC, ln2_b + l * CC,
                                         W1p + (size_t)l * FFN * CC, bff1 + l * FFN,
                                         W2p + (size_t)l * CC * FFN, bff2 + l * CC,
                                         g1n, b1n, hbf);
    }

    proj_kernel<<<NTOT, 128, 0, stream>>>(x, proj_W, proj_b, out);
}